// Round 2
// baseline (18394.699 us; speedup 1.0000x reference)
//
// KalmanNetNN persistent-kernel implementation for MI355X (gfx950).
// R2: identical to R1 design, fence spelling fixed (__builtin_amdgcn_fence).
//  - ONE persistent kernel, 240 blocks x 512 thr (1 block/CU via LDS cap ->
//    all blocks co-resident; custom device-scope 2-level barriers, 3/step).
//  - W_ih/W_hh quantized to fp8-e4m3 (x128 scale) once per launch into d_ws;
//    per-block row-slice LDS-resident (~125KB) + remainder streamed from L2.
//  - Everything else fp32. Kalman x-chain exact fp32, replicated per block.
//  - kg reduction folded: T[i,r] = sum_j W3[i*48+j,r]*inn[j] (block-local),
//    cross-block sum = 4 atomicAdd floats per block per step.
// Predicted: ~3ms, barrier+VALU bound, MfmaUtil 0.

#include <hip/hip_runtime.h>
#include <stdint.h>
#include <stddef.h>

typedef float v2f __attribute__((ext_vector_type(2)));

#define HID   2320
#define G3    6960
#define KIH   4160
#define KHH   2320
#define NBLK  240
#define NTHR  512
#define NGATE 232
#define UPB   10
#define TSEQ  512
#define INVWS (1.0f/128.0f)

// ---------------- workspace layout (bytes) ----------------
#define WS_WIH 0L
#define WS_WHH 28953600L            // 6960*4160 fp8
#define WS_L1G 45100800L            // + 6960*2320 fp8
#define WS_HB  45117440L            // l1 4160 f32
#define WS_CB  45126720L            // h  2320 f32
#define WS_BAR 45126784L            // cb 2x4 f32 (+pad)
#define WS_END 45127424L            // bar u32[160]

struct Offs {
  int l1s, hs, wih, whh, w1s, b1s, w3s, cs, as_, b3s, bih, bhh, gpi, gph,
      l2r, ts, inn, knet, dxs, xpri, xpo, b4, nrm;
  int total;
};

__host__ __device__ inline Offs mkoffs(int KRI, int KRH) {
  Offs o; int p = 0;
#define ALLOC(name, bytes) { p = (p + 15) & ~15; o.name = p; p += (bytes); }
  ALLOC(l1s, KIH*4) ALLOC(hs, HID*4)
  ALLOC(wih, 30*KRI) ALLOC(whh, 30*KRH)
  ALLOC(w1s, 18*52*4) ALLOC(b1s, 18*4)
  ALLOC(w3s, 4*4*48*4) ALLOC(cs, 48*5*4) ALLOC(as_, 16*4) ALLOC(b3s, 192*4)
  ALLOC(bih, 30*4) ALLOC(bhh, 30*4)
  ALLOC(gpi, 30*4) ALLOC(gph, 30*4)
  ALLOC(l2r, 4*4) ALLOC(ts, 16*4) ALLOC(inn, 48*4) ALLOC(knet, 52*4)
  ALLOC(dxs, 16) ALLOC(xpri, 16) ALLOC(xpo, 16) ALLOC(b4, 16) ALLOC(nrm, 16)
#undef ALLOC
  o.total = (p + 63) & ~63;
  return o;
}

struct Params {
  const float *A, *C, *x0, *h0, *y, *W1, *b1, *bih, *bhh, *W2, *b2, *W3, *b3;
  const uint8_t *wih8, *whh8;
  float *l1g, *hb, *cb, *out;
  uint32_t *bar;
  int KRI, KRH;
};

// Two-level grid barrier: 8 group counters (bid&7 ~ XCD) -> root -> epoch.
// Monotonic epochs; RELAXED spin (agent-scope load bypasses stale caches),
// single ACQUIRE fence on exit.
__device__ __forceinline__ void gbar(uint32_t* bar, int tid, int bid,
                                     uint32_t target, bool& dead) {
  __syncthreads();
  if (tid == 0 && !dead) {
    __builtin_amdgcn_fence(__ATOMIC_RELEASE, "agent");
    uint32_t g = (uint32_t)(bid & 7);
    uint32_t old = __hip_atomic_fetch_add(&bar[g*16], 1u, __ATOMIC_RELAXED,
                                          __HIP_MEMORY_SCOPE_AGENT);
    if ((old % 30u) == 29u) {   // 240 blocks / 8 groups = 30 per group
      uint32_t r = __hip_atomic_fetch_add(&bar[128], 1u, __ATOMIC_RELAXED,
                                          __HIP_MEMORY_SCOPE_AGENT);
      if ((r & 7u) == 7u)
        __hip_atomic_fetch_add(&bar[136], 1u, __ATOMIC_RELEASE,
                               __HIP_MEMORY_SCOPE_AGENT);
    }
    uint32_t spins = 0;
    while (__hip_atomic_load(&bar[136], __ATOMIC_RELAXED,
                             __HIP_MEMORY_SCOPE_AGENT) < target) {
      __builtin_amdgcn_s_sleep(2);
      if (++spins > (1u << 19)) { dead = true; break; }  // fail fast, no hang
    }
    __builtin_amdgcn_fence(__ATOMIC_ACQUIRE, "agent");
  }
  __syncthreads();
}

// <=4 rows per wave, full K per row; lanes split K. fp8 weights: LDS-resident
// [0,KRES) + streamed-from-global [KRES,K). acts reused across rows (f32 LDS).
__device__ __forceinline__ void dot_fp8(
    const float* __restrict__ acts, const uint8_t* __restrict__ ldsw,
    int KRES, int K, const uint8_t* __restrict__ gw, int gstride,
    const int* grows, const int* lrows, int nr, int lane, float acc[4])
{
  for (int kb = 0; kb + 256 <= KRES; kb += 256) {
    const float4 a = *((const float4*)(acts + kb) + lane);
#pragma unroll
    for (int j = 0; j < 4; ++j) if (j < nr) {
      uint32_t wb = *(const uint32_t*)(ldsw + (size_t)lrows[j]*KRES + kb + (lane<<2));
      v2f lo = __builtin_amdgcn_cvt_pk_f32_fp8((int)wb, false);
      v2f hi = __builtin_amdgcn_cvt_pk_f32_fp8((int)wb, true);
      acc[j] = fmaf(lo.x, a.x, acc[j]); acc[j] = fmaf(lo.y, a.y, acc[j]);
      acc[j] = fmaf(hi.x, a.z, acc[j]); acc[j] = fmaf(hi.y, a.w, acc[j]);
    }
  }
  for (int e = (KRES & ~255) + lane; e < KRES; e += 64) {
    float a = acts[e];
#pragma unroll
    for (int j = 0; j < 4; ++j) if (j < nr) {
      v2f lo = __builtin_amdgcn_cvt_pk_f32_fp8((int)(uint32_t)ldsw[(size_t)lrows[j]*KRES + e], false);
      acc[j] = fmaf(lo.x, a, acc[j]);
    }
  }
  for (int kb = KRES; kb + 256 <= K; kb += 256) {
    const float4 a = *((const float4*)(acts + kb) + lane);
#pragma unroll
    for (int j = 0; j < 4; ++j) if (j < nr) {
      uint32_t wb = *(const uint32_t*)(gw + (size_t)grows[j]*gstride + kb + (lane<<2));
      v2f lo = __builtin_amdgcn_cvt_pk_f32_fp8((int)wb, false);
      v2f hi = __builtin_amdgcn_cvt_pk_f32_fp8((int)wb, true);
      acc[j] = fmaf(lo.x, a.x, acc[j]); acc[j] = fmaf(lo.y, a.y, acc[j]);
      acc[j] = fmaf(hi.x, a.z, acc[j]); acc[j] = fmaf(hi.y, a.w, acc[j]);
    }
  }
  int kf2 = KRES + ((K - KRES) & ~255);
  for (int e = kf2 + lane; e < K; e += 64) {
    float a = acts[e];
#pragma unroll
    for (int j = 0; j < 4; ++j) if (j < nr) {
      v2f lo = __builtin_amdgcn_cvt_pk_f32_fp8((int)(uint32_t)gw[(size_t)grows[j]*gstride + e], false);
      acc[j] = fmaf(lo.x, a, acc[j]);
    }
  }
}

extern "C" __global__ void __launch_bounds__(NTHR, 2) knet_main(Params p)
{
  extern __shared__ char smem[];
  const Offs o = mkoffs(p.KRI, p.KRH);
  float*   L1S  = (float*)(smem + o.l1s);
  float*   HS   = (float*)(smem + o.hs);
  uint8_t* WIHR = (uint8_t*)(smem + o.wih);
  uint8_t* WHHR = (uint8_t*)(smem + o.whh);
  float*   W1S  = (float*)(smem + o.w1s);
  float*   B1S  = (float*)(smem + o.b1s);
  float*   W3S  = (float*)(smem + o.w3s);
  float*   CS   = (float*)(smem + o.cs);
  float*   AS   = (float*)(smem + o.as_);
  float*   B3S  = (float*)(smem + o.b3s);
  float*   BIH  = (float*)(smem + o.bih);
  float*   BHH  = (float*)(smem + o.bhh);
  float*   GPI  = (float*)(smem + o.gpi);
  float*   GPH  = (float*)(smem + o.gph);
  float*   L2R  = (float*)(smem + o.l2r);
  float*   TS   = (float*)(smem + o.ts);
  float*   INNS = (float*)(smem + o.inn);
  float*   KNET = (float*)(smem + o.knet);
  float*   DXS  = (float*)(smem + o.dxs);
  float*   XPRI = (float*)(smem + o.xpri);
  float*   XPO  = (float*)(smem + o.xpo);
  float*   B4   = (float*)(smem + o.b4);
  float*   NRM  = (float*)(smem + o.nrm);

  const int tid  = (int)threadIdx.x;
  const int bid  = (int)blockIdx.x;
  const int lane = tid & 63;
  const int wv   = tid >> 6;
  const int rows1 = (bid < 80) ? 18 : 17;                    // l1 slice
  const int r1s   = (bid < 80) ? bid*18 : 1440 + (bid-80)*17;
  const int rows2 = (bid < 48) ? 4 : 3;                      // l2 slice
  const int r2s   = (bid < 48) ? bid*4 : 192 + (bid-48)*3;
  bool dead = false;
  uint32_t et = 0;

  // ---------------- one-time staging ----------------
  for (int i = tid; i < rows1*52; i += NTHR) { int r = i/52, k = i - r*52;
    W1S[i] = p.W1[(size_t)(r1s+r)*52 + k]; }
  for (int i = tid; i < rows1; i += NTHR) B1S[i] = p.b1[r1s + i];
  for (int i = tid; i < rows2*192; i += NTHR) { int rl = i/192, rem = i - rl*192;
    W3S[i] = p.W3[(size_t)rem*768 + (r2s + rl)]; }   // W3S[rl*192 + i*48 + j]
  for (int i = tid; i < 240; i += NTHR) CS[i] = p.C[i];
  if (tid < 16) AS[tid] = p.A[tid];
  for (int i = tid; i < 192; i += NTHR) B3S[i] = p.b3[i];
  if (bid < NGATE && tid < 30) {
    int u = tid/3, g = tid - 3*u, ug = bid*UPB + u;
    BIH[tid] = p.bih[g*HID + ug];
    BHH[tid] = p.bhh[g*HID + ug];
  }
  for (int i = tid; i < HID; i += NTHR) HS[i] = p.h0[i];     // h(-1) = h0
  if (bid < NGATE) {
    const int kdI = p.KRI >> 2;
    uint32_t* W32 = (uint32_t*)WIHR;
    for (int i = tid; i < 30*kdI; i += NTHR) {
      int row = i / kdI, kd = i - row*kdI;
      int u = row/3, g = row - 3*u, gr = g*HID + bid*UPB + u;
      W32[i] = ((const uint32_t*)p.wih8)[(size_t)gr*(KIH/4) + kd];
    }
    const int kdH = p.KRH >> 2;
    uint32_t* W32h = (uint32_t*)WHHR;
    for (int i = tid; i < 30*kdH; i += NTHR) {
      int row = i / kdH, kd = i - row*kdH;
      int u = row/3, g = row - 3*u, gr = g*HID + bid*UPB + u;
      W32h[i] = ((const uint32_t*)p.whh8)[(size_t)gr*(KHH/4) + kd];
    }
  }

  // small chain for step t_next: inn, norms, knet, B4, l1 slice, T slice.
  auto tail_chain = [&](int ycol) {
    if (tid < 48) {
      float s = CS[tid*5 + 4];
#pragma unroll
      for (int k = 0; k < 4; ++k) s += CS[tid*5 + k] * XPRI[k];
      INNS[tid] = p.y[(size_t)tid*TSEQ + ycol] - s;
    }
    __syncthreads();
    if (tid == 0) {
      float s = 0;
      for (int j = 0; j < 48; ++j) s += INNS[j]*INNS[j];
      NRM[0] = fmaxf(sqrtf(s), 1e-12f);
      float s2 = 0;
      for (int j = 0; j < 4; ++j) s2 += DXS[j]*DXS[j];
      NRM[1] = fmaxf(sqrtf(s2), 1e-12f);
    }
    __syncthreads();
    if (tid < 48) KNET[tid] = INNS[tid] / NRM[0];
    else if (tid < 52) KNET[tid] = DXS[tid-48] / NRM[1];
    else if (tid >= 64 && tid < 68) {
      int i = tid - 64; float s = 0;
      for (int j = 0; j < 48; ++j) s += B3S[i*48 + j] * INNS[j];
      B4[i] = s;
    }
    __syncthreads();
    if (tid < rows1) {
      float s = B1S[tid];
#pragma unroll 4
      for (int k = 0; k < 52; ++k) s += W1S[tid*52 + k] * KNET[k];
      p.l1g[r1s + tid] = fmaxf(s, 0.f);
    }
    if (tid >= 128 && tid < 128 + rows2*4) {
      int idx = tid - 128, rl = idx >> 2, i = idx & 3;
      float s = 0;
      for (int j = 0; j < 48; ++j) s += W3S[rl*192 + i*48 + j] * INNS[j];
      TS[i*4 + rl] = s;
    }
  };

  // ---------------- pre-loop (produce step-0 inputs) ----------------
  if (tid < 4) { XPO[tid] = p.x0[tid]; DXS[tid] = 0.f; }
  __syncthreads();
  if (tid < 4) {
    float s = 0;
#pragma unroll
    for (int j = 0; j < 4; ++j) s += AS[tid*4 + j] * XPO[j];
    XPRI[tid] = s;
  }
  __syncthreads();
  tail_chain(0);
  gbar(p.bar, tid, bid, ++et, dead);

  // ---------------- main sequence ----------------
  for (int t = 0; t < TSEQ; ++t) {
    // ---- stage 1: GRU gates + h update ----
    if (bid < NGATE) {
      for (int i = tid; i < KIH/4; i += NTHR)
        ((float4*)L1S)[i] = ((const float4*)p.l1g)[i];
      __syncthreads();
      int lrows[4] = {0,0,0,0}, grows[4] = {0,0,0,0};
      int nr = 0;
#pragma unroll
      for (int j = 0; j < 4; ++j) {
        int row = wv + 8*j;
        if (row < 30) { int u = row/3, g = row - 3*u;
          lrows[nr] = row; grows[nr] = g*HID + bid*UPB + u; ++nr; }
      }
      float accI[4] = {0,0,0,0}, accH[4] = {0,0,0,0};
      dot_fp8(L1S, WIHR, p.KRI, KIH, p.wih8, KIH, grows, lrows, nr, lane, accI);
      dot_fp8(HS,  WHHR, p.KRH, KHH, p.whh8, KHH, grows, lrows, nr, lane, accH);
#pragma unroll
      for (int m = 32; m >= 1; m >>= 1) {
#pragma unroll
        for (int j = 0; j < 4; ++j) {
          accI[j] += __shfl_xor(accI[j], m, 64);
          accH[j] += __shfl_xor(accH[j], m, 64);
        }
      }
      if (lane == 0) {
#pragma unroll
        for (int j = 0; j < 4; ++j) if (j < nr) {
          GPI[lrows[j]] = accI[j]; GPH[lrows[j]] = accH[j];
        }
      }
      __syncthreads();
      if (tid < UPB) {
        int ug = bid*UPB + tid, r0 = tid*3;
        float gi0 = GPI[r0+0]*INVWS + BIH[r0+0], gh0 = GPH[r0+0]*INVWS + BHH[r0+0];
        float gi1 = GPI[r0+1]*INVWS + BIH[r0+1], gh1 = GPH[r0+1]*INVWS + BHH[r0+1];
        float gi2 = GPI[r0+2]*INVWS + BIH[r0+2], gh2 = GPH[r0+2]*INVWS + BHH[r0+2];
        float rg = 1.f/(1.f + expf(-(gi0+gh0)));
        float zg = 1.f/(1.f + expf(-(gi1+gh1)));
        float ng = tanhf(gi2 + rg*gh2);
        p.hb[ug] = (1.f - zg)*ng + zg*HS[ug];
      }
    }
    gbar(p.bar, tid, bid, ++et, dead);

    // ---- stage 2: l2 slice + kg contribution (via T) ----
    for (int i = tid; i < HID/4; i += NTHR)
      ((float4*)HS)[i] = ((const float4*)p.hb)[i];   // HS <- h(t)
    __syncthreads();
    if (wv < rows2) {
      int r = r2s + wv;
      float acc = 0;
#pragma unroll 4
      for (int k = lane; k < HID; k += 64)
        acc = fmaf(p.W2[(size_t)r*HID + k], HS[k], acc);
#pragma unroll
      for (int m = 32; m >= 1; m >>= 1) acc += __shfl_xor(acc, m, 64);
      if (lane == 0) L2R[wv] = fmaxf(acc + p.b2[r], 0.f);
    }
    __syncthreads();
    if (tid < 4) {
      float cp = 0;
      for (int rl = 0; rl < rows2; ++rl) cp += L2R[rl] * TS[tid*4 + rl];
      atomicAdd(&p.cb[(t & 1)*4 + tid], cp);
    }
    gbar(p.bar, tid, bid, ++et, dead);

    // ---- stage 3: posterior update + next-step small chain ----
    if (tid < 4) {
      float c = p.cb[(t & 1)*4 + tid];
      float xp = XPRI[tid] + (c + B4[tid]) * 1e-4f;
      XPO[tid] = xp;
      if (bid == 0) {
        p.out[(size_t)tid*TSEQ + t] = xp;
        p.cb[((t+1) & 1)*4 + tid] = 0.f;   // re-zero other buffer
      }
    }
    __syncthreads();
    if (t + 1 < TSEQ) {
      if (tid < 4) DXS[tid] = XPO[tid] - XPRI[tid];
      __syncthreads();
      if (tid < 4) {
        float s = 0;
#pragma unroll
        for (int j = 0; j < 4; ++j) s += AS[tid*4 + j] * XPO[j];
        XPRI[tid] = s;
      }
      __syncthreads();
      tail_chain(t + 1);
      gbar(p.bar, tid, bid, ++et, dead);
    }
  }
}

// f32 -> fp8 e4m3 (x128) conversion, 4 elements per thread.
extern "C" __global__ void knet_cvt_fp8(const float* __restrict__ src,
                                        uint8_t* __restrict__ dst, long n4) {
  long stride = (long)gridDim.x * blockDim.x;
  for (long i = (long)blockIdx.x*blockDim.x + threadIdx.x; i < n4; i += stride) {
    float4 v = ((const float4*)src)[i];
    float a0 = fminf(fmaxf(v.x * 128.f, -448.f), 448.f);
    float a1 = fminf(fmaxf(v.y * 128.f, -448.f), 448.f);
    float a2 = fminf(fmaxf(v.z * 128.f, -448.f), 448.f);
    float a3 = fminf(fmaxf(v.w * 128.f, -448.f), 448.f);
    int pk = __builtin_amdgcn_cvt_pk_fp8_f32(a0, a1, 0, false);
    pk = __builtin_amdgcn_cvt_pk_fp8_f32(a2, a3, pk, true);
    ((uint32_t*)dst)[i] = (uint32_t)pk;
  }
}

extern "C" void kernel_launch(void* const* d_in, const int* in_sizes, int n_in,
                              void* d_out, int out_size, void* d_ws, size_t ws_size,
                              hipStream_t stream)
{
  if (ws_size < (size_t)WS_END) return;   // need ~45.2 MB scratch
  uint8_t* ws = (uint8_t*)d_ws;

  knet_cvt_fp8<<<2048, 256, 0, stream>>>((const float*)d_in[7], ws + WS_WIH,
                                         (long)G3*KIH/4);
  knet_cvt_fp8<<<2048, 256, 0, stream>>>((const float*)d_in[8], ws + WS_WHH,
                                         (long)G3*KHH/4);
  (void)hipMemsetAsync(ws + WS_CB, 0, (size_t)(WS_END - WS_CB), stream); // cb + barriers

  int dev = 0; (void)hipGetDevice(&dev);
  int maxsm = 65536;
  (void)hipDeviceGetAttribute(&maxsm, hipDeviceAttributeMaxSharedMemoryPerBlock, dev);
  int KRI = 1856, KRH = 2320;              // 160KB-LDS variant (~161KB total)
  Offs o = mkoffs(KRI, KRH);
  if (o.total > maxsm) { KRI = 768; KRH = 0; o = mkoffs(KRI, KRH); }  // 64KB variant
  if (o.total > maxsm) { KRI = 0;   KRH = 0; o = mkoffs(KRI, KRH); }  // stream-all
  (void)hipFuncSetAttribute((const void*)knet_main,
                            hipFuncAttributeMaxDynamicSharedMemorySize, o.total);

  Params p;
  p.A  = (const float*)d_in[0];  p.C   = (const float*)d_in[1];
  p.x0 = (const float*)d_in[2];  p.h0  = (const float*)d_in[3];
  p.y  = (const float*)d_in[4];
  p.W1 = (const float*)d_in[5];  p.b1  = (const float*)d_in[6];
  p.bih = (const float*)d_in[9]; p.bhh = (const float*)d_in[10];
  p.W2 = (const float*)d_in[11]; p.b2  = (const float*)d_in[12];
  p.W3 = (const float*)d_in[13]; p.b3  = (const float*)d_in[14];
  p.wih8 = ws + WS_WIH;  p.whh8 = ws + WS_WHH;
  p.l1g = (float*)(ws + WS_L1G); p.hb = (float*)(ws + WS_HB);
  p.cb  = (float*)(ws + WS_CB);  p.bar = (uint32_t*)(ws + WS_BAR);
  p.out = (float*)d_out;
  p.KRI = KRI; p.KRH = KRH;

  knet_main<<<NBLK, NTHR, (size_t)o.total, stream>>>(p);
}

// Round 3
// 18141.348 us; speedup vs baseline: 1.0140x; 1.0140x over previous
//
// KalmanNetNN persistent-kernel implementation for MI355X (gfx950).
// R3: kg reduction via per-block slots + redundant gather (NO same-line
//     atomics), epoch on private cacheline, setattr-gated 160KB LDS config.
//  - ONE persistent kernel, 240 blocks x 512 thr, custom 2-level grid
//    barriers, 3/step.
//  - W_ih/W_hh fp8-e4m3 (x128) in d_ws; per-block slice LDS-resident,
//    remainder streamed from L2.
//  - Kalman x-chain exact fp32, replicated per block.
// Predicted: 7-10.5 ms (cb-atomic serialization removed).

#include <hip/hip_runtime.h>
#include <stdint.h>
#include <stddef.h>

typedef float v2f __attribute__((ext_vector_type(2)));

#define HID   2320
#define G3    6960
#define KIH   4160
#define KHH   2320
#define NBLK  240
#define NTHR  512
#define NGATE 232
#define UPB   10
#define TSEQ  512
#define INVWS (1.0f/128.0f)

// ---------------- workspace layout (bytes) ----------------
#define WS_WIH  0L
#define WS_WHH  28953600L            // 6960*4160 fp8
#define WS_L1G  45100800L            // + 6960*2320 fp8
#define WS_HB   45117440L            // l1 4160 f32
#define WS_SLOT 45126720L            // h  2320 f32
#define WS_BAR  45130816L            // slots 256 x float4
#define WS_END  45131584L            // bar u32[192]

struct Offs {
  int l1s, hs, wih, whh, w1s, b1s, w3s, cs, as_, b3s, bih, bhh, gpi, gph,
      l2r, ts, inn, knet, dxs, xpri, xpo, b4, nrm, cbp, slp;
  int total;
};

__host__ __device__ inline Offs mkoffs(int KRI, int KRH) {
  Offs o; int p = 0;
#define ALLOC(name, bytes) { p = (p + 15) & ~15; o.name = p; p += (bytes); }
  ALLOC(l1s, KIH*4) ALLOC(hs, HID*4)
  ALLOC(wih, 30*KRI) ALLOC(whh, 30*KRH)
  ALLOC(w1s, 18*52*4) ALLOC(b1s, 18*4)
  ALLOC(w3s, 4*4*48*4) ALLOC(cs, 48*5*4) ALLOC(as_, 16*4) ALLOC(b3s, 192*4)
  ALLOC(bih, 30*4) ALLOC(bhh, 30*4)
  ALLOC(gpi, 30*4) ALLOC(gph, 30*4)
  ALLOC(l2r, 4*4) ALLOC(ts, 16*4) ALLOC(inn, 48*4) ALLOC(knet, 52*4)
  ALLOC(dxs, 16) ALLOC(xpri, 16) ALLOC(xpo, 16) ALLOC(b4, 16) ALLOC(nrm, 16)
  ALLOC(cbp, 16) ALLOC(slp, 64)
#undef ALLOC
  o.total = (p + 63) & ~63;
  return o;
}

struct Params {
  const float *A, *C, *x0, *h0, *y, *W1, *b1, *bih, *bhh, *W2, *b2, *W3, *b3;
  const uint8_t *wih8, *whh8;
  float *l1g, *hb, *slots, *out;
  uint32_t *bar;
  int KRI, KRH;
};

// Two-level grid barrier: 8 group counters (one line each) -> root (own line)
// -> epoch (own line). Monotonic epochs; RELAXED agent-scope spin.
__device__ __forceinline__ void gbar(uint32_t* bar, int tid, int bid,
                                     uint32_t target, bool& dead) {
  __syncthreads();
  if (tid == 0 && !dead) {
    __builtin_amdgcn_fence(__ATOMIC_RELEASE, "agent");
    uint32_t g = (uint32_t)(bid & 7);
    uint32_t old = __hip_atomic_fetch_add(&bar[g*16], 1u, __ATOMIC_RELAXED,
                                          __HIP_MEMORY_SCOPE_AGENT);
    if ((old % 30u) == 29u) {   // 240 blocks / 8 groups = 30 per group
      uint32_t r = __hip_atomic_fetch_add(&bar[128], 1u, __ATOMIC_RELAXED,
                                          __HIP_MEMORY_SCOPE_AGENT);
      if ((r & 7u) == 7u)
        __hip_atomic_fetch_add(&bar[160], 1u, __ATOMIC_RELEASE,
                               __HIP_MEMORY_SCOPE_AGENT);
    }
    uint32_t spins = 0;
    while (__hip_atomic_load(&bar[160], __ATOMIC_RELAXED,
                             __HIP_MEMORY_SCOPE_AGENT) < target) {
      __builtin_amdgcn_s_sleep(2);
      if (++spins > (1u << 19)) { dead = true; break; }  // fail fast, no hang
    }
    __builtin_amdgcn_fence(__ATOMIC_ACQUIRE, "agent");
  }
  __syncthreads();
}

// <=4 rows per wave, full K per row; lanes split K. fp8 weights: LDS-resident
// [0,KRES) + streamed-from-global [KRES,K). acts reused across rows (f32 LDS).
__device__ __forceinline__ void dot_fp8(
    const float* __restrict__ acts, const uint8_t* __restrict__ ldsw,
    int KRES, int K, const uint8_t* __restrict__ gw, int gstride,
    const int* grows, const int* lrows, int nr, int lane, float acc[4])
{
  for (int kb = 0; kb + 256 <= KRES; kb += 256) {
    const float4 a = *((const float4*)(acts + kb) + lane);
#pragma unroll
    for (int j = 0; j < 4; ++j) if (j < nr) {
      uint32_t wb = *(const uint32_t*)(ldsw + (size_t)lrows[j]*KRES + kb + (lane<<2));
      v2f lo = __builtin_amdgcn_cvt_pk_f32_fp8((int)wb, false);
      v2f hi = __builtin_amdgcn_cvt_pk_f32_fp8((int)wb, true);
      acc[j] = fmaf(lo.x, a.x, acc[j]); acc[j] = fmaf(lo.y, a.y, acc[j]);
      acc[j] = fmaf(hi.x, a.z, acc[j]); acc[j] = fmaf(hi.y, a.w, acc[j]);
    }
  }
  for (int e = (KRES & ~255) + lane; e < KRES; e += 64) {
    float a = acts[e];
#pragma unroll
    for (int j = 0; j < 4; ++j) if (j < nr) {
      v2f lo = __builtin_amdgcn_cvt_pk_f32_fp8((int)(uint32_t)ldsw[(size_t)lrows[j]*KRES + e], false);
      acc[j] = fmaf(lo.x, a, acc[j]);
    }
  }
  for (int kb = KRES; kb + 256 <= K; kb += 256) {
    const float4 a = *((const float4*)(acts + kb) + lane);
#pragma unroll
    for (int j = 0; j < 4; ++j) if (j < nr) {
      uint32_t wb = *(const uint32_t*)(gw + (size_t)grows[j]*gstride + kb + (lane<<2));
      v2f lo = __builtin_amdgcn_cvt_pk_f32_fp8((int)wb, false);
      v2f hi = __builtin_amdgcn_cvt_pk_f32_fp8((int)wb, true);
      acc[j] = fmaf(lo.x, a.x, acc[j]); acc[j] = fmaf(lo.y, a.y, acc[j]);
      acc[j] = fmaf(hi.x, a.z, acc[j]); acc[j] = fmaf(hi.y, a.w, acc[j]);
    }
  }
  int kf2 = KRES + ((K - KRES) & ~255);
  for (int e = kf2 + lane; e < K; e += 64) {
    float a = acts[e];
#pragma unroll
    for (int j = 0; j < 4; ++j) if (j < nr) {
      v2f lo = __builtin_amdgcn_cvt_pk_f32_fp8((int)(uint32_t)gw[(size_t)grows[j]*gstride + e], false);
      acc[j] = fmaf(lo.x, a, acc[j]);
    }
  }
}

extern "C" __global__ void __launch_bounds__(NTHR, 2) knet_main(Params p)
{
  extern __shared__ char smem[];
  const Offs o = mkoffs(p.KRI, p.KRH);
  float*   L1S  = (float*)(smem + o.l1s);
  float*   HS   = (float*)(smem + o.hs);
  uint8_t* WIHR = (uint8_t*)(smem + o.wih);
  uint8_t* WHHR = (uint8_t*)(smem + o.whh);
  float*   W1S  = (float*)(smem + o.w1s);
  float*   B1S  = (float*)(smem + o.b1s);
  float*   W3S  = (float*)(smem + o.w3s);
  float*   CS   = (float*)(smem + o.cs);
  float*   AS   = (float*)(smem + o.as_);
  float*   B3S  = (float*)(smem + o.b3s);
  float*   BIH  = (float*)(smem + o.bih);
  float*   BHH  = (float*)(smem + o.bhh);
  float*   GPI  = (float*)(smem + o.gpi);
  float*   GPH  = (float*)(smem + o.gph);
  float*   L2R  = (float*)(smem + o.l2r);
  float*   TS   = (float*)(smem + o.ts);
  float*   INNS = (float*)(smem + o.inn);
  float*   KNET = (float*)(smem + o.knet);
  float*   DXS  = (float*)(smem + o.dxs);
  float*   XPRI = (float*)(smem + o.xpri);
  float*   XPO  = (float*)(smem + o.xpo);
  float*   B4   = (float*)(smem + o.b4);
  float*   NRM  = (float*)(smem + o.nrm);
  float*   CBP  = (float*)(smem + o.cbp);
  float*   SLP  = (float*)(smem + o.slp);   // 4 x float4 wave partials

  const int tid  = (int)threadIdx.x;
  const int bid  = (int)blockIdx.x;
  const int lane = tid & 63;
  const int wv   = tid >> 6;
  const int rows1 = (bid < 80) ? 18 : 17;                    // l1 slice
  const int r1s   = (bid < 80) ? bid*18 : 1440 + (bid-80)*17;
  const int rows2 = (bid < 48) ? 4 : 3;                      // l2 slice
  const int r2s   = (bid < 48) ? bid*4 : 192 + (bid-48)*3;
  bool dead = false;
  uint32_t et = 0;

  // ---------------- one-time staging ----------------
  for (int i = tid; i < rows1*52; i += NTHR) { int r = i/52, k = i - r*52;
    W1S[i] = p.W1[(size_t)(r1s+r)*52 + k]; }
  for (int i = tid; i < rows1; i += NTHR) B1S[i] = p.b1[r1s + i];
  for (int i = tid; i < rows2*192; i += NTHR) { int rl = i/192, rem = i - rl*192;
    W3S[i] = p.W3[(size_t)rem*768 + (r2s + rl)]; }   // W3S[rl*192 + i*48 + j]
  for (int i = tid; i < 240; i += NTHR) CS[i] = p.C[i];
  if (tid < 16) AS[tid] = p.A[tid];
  for (int i = tid; i < 192; i += NTHR) B3S[i] = p.b3[i];
  if (bid < NGATE && tid < 30) {
    int u = tid/3, g = tid - 3*u, ug = bid*UPB + u;
    BIH[tid] = p.bih[g*HID + ug];
    BHH[tid] = p.bhh[g*HID + ug];
  }
  for (int i = tid; i < HID; i += NTHR) HS[i] = p.h0[i];     // h(-1) = h0
  if (bid < NGATE) {
    const int kdI = p.KRI >> 2;
    uint32_t* W32 = (uint32_t*)WIHR;
    for (int i = tid; i < 30*kdI; i += NTHR) {
      int row = i / kdI, kd = i - row*kdI;
      int u = row/3, g = row - 3*u, gr = g*HID + bid*UPB + u;
      W32[i] = ((const uint32_t*)p.wih8)[(size_t)gr*(KIH/4) + kd];
    }
    const int kdH = p.KRH >> 2;
    uint32_t* W32h = (uint32_t*)WHHR;
    for (int i = tid; i < 30*kdH; i += NTHR) {
      int row = i / kdH, kd = i - row*kdH;
      int u = row/3, g = row - 3*u, gr = g*HID + bid*UPB + u;
      W32h[i] = ((const uint32_t*)p.whh8)[(size_t)gr*(KHH/4) + kd];
    }
  }

  // small chain for step t_next: inn, norms, knet, B4, l1 slice, T slice.
  auto tail_chain = [&](int ycol) {
    if (tid < 48) {
      float s = CS[tid*5 + 4];
#pragma unroll
      for (int k = 0; k < 4; ++k) s += CS[tid*5 + k] * XPRI[k];
      INNS[tid] = p.y[(size_t)tid*TSEQ + ycol] - s;
    }
    __syncthreads();
    if (tid == 0) {
      float s = 0;
      for (int j = 0; j < 48; ++j) s += INNS[j]*INNS[j];
      NRM[0] = fmaxf(sqrtf(s), 1e-12f);
      float s2 = 0;
      for (int j = 0; j < 4; ++j) s2 += DXS[j]*DXS[j];
      NRM[1] = fmaxf(sqrtf(s2), 1e-12f);
    }
    __syncthreads();
    if (tid < 48) KNET[tid] = INNS[tid] / NRM[0];
    else if (tid < 52) KNET[tid] = DXS[tid-48] / NRM[1];
    else if (tid >= 64 && tid < 68) {
      int i = tid - 64; float s = 0;
      for (int j = 0; j < 48; ++j) s += B3S[i*48 + j] * INNS[j];
      B4[i] = s;
    }
    __syncthreads();
    if (tid < rows1) {
      float s = B1S[tid];
#pragma unroll 4
      for (int k = 0; k < 52; ++k) s += W1S[tid*52 + k] * KNET[k];
      p.l1g[r1s + tid] = fmaxf(s, 0.f);
    }
    if (tid >= 128 && tid < 128 + rows2*4) {
      int idx = tid - 128, rl = idx >> 2, i = idx & 3;
      float s = 0;
      for (int j = 0; j < 48; ++j) s += W3S[rl*192 + i*48 + j] * INNS[j];
      TS[i*4 + rl] = s;
    }
  };

  // ---------------- pre-loop (produce step-0 inputs) ----------------
  if (tid < 4) { XPO[tid] = p.x0[tid]; DXS[tid] = 0.f; }
  __syncthreads();
  if (tid < 4) {
    float s = 0;
#pragma unroll
    for (int j = 0; j < 4; ++j) s += AS[tid*4 + j] * XPO[j];
    XPRI[tid] = s;
  }
  __syncthreads();
  tail_chain(0);
  gbar(p.bar, tid, bid, ++et, dead);

  // ---------------- main sequence ----------------
  for (int t = 0; t < TSEQ; ++t) {
    // ---- stage 1: GRU gates + h update ----
    if (bid < NGATE) {
      for (int i = tid; i < KIH/4; i += NTHR)
        ((float4*)L1S)[i] = ((const float4*)p.l1g)[i];
      __syncthreads();
      int lrows[4] = {0,0,0,0}, grows[4] = {0,0,0,0};
      int nr = 0;
#pragma unroll
      for (int j = 0; j < 4; ++j) {
        int row = wv + 8*j;
        if (row < 30) { int u = row/3, g = row - 3*u;
          lrows[nr] = row; grows[nr] = g*HID + bid*UPB + u; ++nr; }
      }
      float accI[4] = {0,0,0,0}, accH[4] = {0,0,0,0};
      dot_fp8(L1S, WIHR, p.KRI, KIH, p.wih8, KIH, grows, lrows, nr, lane, accI);
      dot_fp8(HS,  WHHR, p.KRH, KHH, p.whh8, KHH, grows, lrows, nr, lane, accH);
#pragma unroll
      for (int m = 32; m >= 1; m >>= 1) {
#pragma unroll
        for (int j = 0; j < 4; ++j) {
          accI[j] += __shfl_xor(accI[j], m, 64);
          accH[j] += __shfl_xor(accH[j], m, 64);
        }
      }
      if (lane == 0) {
#pragma unroll
        for (int j = 0; j < 4; ++j) if (j < nr) {
          GPI[lrows[j]] = accI[j]; GPH[lrows[j]] = accH[j];
        }
      }
      __syncthreads();
      if (tid < UPB) {
        int ug = bid*UPB + tid, r0 = tid*3;
        float gi0 = GPI[r0+0]*INVWS + BIH[r0+0], gh0 = GPH[r0+0]*INVWS + BHH[r0+0];
        float gi1 = GPI[r0+1]*INVWS + BIH[r0+1], gh1 = GPH[r0+1]*INVWS + BHH[r0+1];
        float gi2 = GPI[r0+2]*INVWS + BIH[r0+2], gh2 = GPH[r0+2]*INVWS + BHH[r0+2];
        float rg = 1.f/(1.f + expf(-(gi0+gh0)));
        float zg = 1.f/(1.f + expf(-(gi1+gh1)));
        float ng = tanhf(gi2 + rg*gh2);
        p.hb[ug] = (1.f - zg)*ng + zg*HS[ug];
      }
    }
    gbar(p.bar, tid, bid, ++et, dead);

    // ---- stage 2: l2 slice + kg contribution (via T) -> private slot ----
    for (int i = tid; i < HID/4; i += NTHR)
      ((float4*)HS)[i] = ((const float4*)p.hb)[i];   // HS <- h(t)
    __syncthreads();
    if (wv < rows2) {
      int r = r2s + wv;
      float acc = 0;
#pragma unroll 4
      for (int k = lane; k < HID; k += 64)
        acc = fmaf(p.W2[(size_t)r*HID + k], HS[k], acc);
#pragma unroll
      for (int m = 32; m >= 1; m >>= 1) acc += __shfl_xor(acc, m, 64);
      if (lane == 0) L2R[wv] = fmaxf(acc + p.b2[r], 0.f);
    }
    __syncthreads();
    if (tid < 4) {
      float cp = 0;
      for (int rl = 0; rl < rows2; ++rl) cp += L2R[rl] * TS[tid*4 + rl];
      CBP[tid] = cp;
    }
    __syncthreads();
    if (tid == 0)
      ((float4*)p.slots)[bid] = make_float4(CBP[0], CBP[1], CBP[2], CBP[3]);
    gbar(p.bar, tid, bid, ++et, dead);

    // ---- stage 3: redundant slot gather + posterior + next small chain ----
    if (wv < 4) {
      int s = (wv << 6) | lane;
      float4 v = make_float4(0.f, 0.f, 0.f, 0.f);
      if (s < NBLK) v = ((const float4*)p.slots)[s];
#pragma unroll
      for (int m = 32; m >= 1; m >>= 1) {
        v.x += __shfl_xor(v.x, m, 64);
        v.y += __shfl_xor(v.y, m, 64);
        v.z += __shfl_xor(v.z, m, 64);
        v.w += __shfl_xor(v.w, m, 64);
      }
      if (lane == 0) ((float4*)SLP)[wv] = v;
    }
    __syncthreads();
    if (tid < 4) {
      float c = SLP[tid] + SLP[4 + tid] + SLP[8 + tid] + SLP[12 + tid];
      float xp = XPRI[tid] + (c + B4[tid]) * 1e-4f;
      XPO[tid] = xp;
      if (bid == 0) p.out[(size_t)tid*TSEQ + t] = xp;
    }
    __syncthreads();
    if (t + 1 < TSEQ) {
      if (tid < 4) DXS[tid] = XPO[tid] - XPRI[tid];
      __syncthreads();
      if (tid < 4) {
        float s = 0;
#pragma unroll
        for (int j = 0; j < 4; ++j) s += AS[tid*4 + j] * XPO[j];
        XPRI[tid] = s;
      }
      __syncthreads();
      tail_chain(t + 1);
      gbar(p.bar, tid, bid, ++et, dead);
    }
  }
}

// f32 -> fp8 e4m3 (x128) conversion, 4 elements per thread.
extern "C" __global__ void knet_cvt_fp8(const float* __restrict__ src,
                                        uint8_t* __restrict__ dst, long n4) {
  long stride = (long)gridDim.x * blockDim.x;
  for (long i = (long)blockIdx.x*blockDim.x + threadIdx.x; i < n4; i += stride) {
    float4 v = ((const float4*)src)[i];
    float a0 = fminf(fmaxf(v.x * 128.f, -448.f), 448.f);
    float a1 = fminf(fmaxf(v.y * 128.f, -448.f), 448.f);
    float a2 = fminf(fmaxf(v.z * 128.f, -448.f), 448.f);
    float a3 = fminf(fmaxf(v.w * 128.f, -448.f), 448.f);
    int pk = __builtin_amdgcn_cvt_pk_fp8_f32(a0, a1, 0, false);
    pk = __builtin_amdgcn_cvt_pk_fp8_f32(a2, a3, pk, true);
    ((uint32_t*)dst)[i] = (uint32_t)pk;
  }
}

extern "C" void kernel_launch(void* const* d_in, const int* in_sizes, int n_in,
                              void* d_out, int out_size, void* d_ws, size_t ws_size,
                              hipStream_t stream)
{
  if (ws_size < (size_t)WS_END) return;   // need ~45.2 MB scratch
  uint8_t* ws = (uint8_t*)d_ws;

  knet_cvt_fp8<<<2048, 256, 0, stream>>>((const float*)d_in[7], ws + WS_WIH,
                                         (long)G3*KIH/4);
  knet_cvt_fp8<<<2048, 256, 0, stream>>>((const float*)d_in[8], ws + WS_WHH,
                                         (long)G3*KHH/4);
  (void)hipMemsetAsync(ws + WS_BAR, 0, (size_t)(WS_END - WS_BAR), stream); // barriers

  // Prefer the 160KB-LDS config; trust the setattr return code, not the
  // (possibly 64KB-reporting) device attribute.
  int KRI = 1856, KRH = 2320;              // ~157KB variant
  Offs o = mkoffs(KRI, KRH);
  hipError_t e = hipFuncSetAttribute((const void*)knet_main,
                                     hipFuncAttributeMaxDynamicSharedMemorySize,
                                     o.total);
  if (e != hipSuccess) {
    KRI = 768; KRH = 0; o = mkoffs(KRI, KRH);   // <64KB fallback
    (void)hipFuncSetAttribute((const void*)knet_main,
                              hipFuncAttributeMaxDynamicSharedMemorySize, o.total);
  }

  Params p;
  p.A  = (const float*)d_in[0];  p.C   = (const float*)d_in[1];
  p.x0 = (const float*)d_in[2];  p.h0  = (const float*)d_in[3];
  p.y  = (const float*)d_in[4];
  p.W1 = (const float*)d_in[5];  p.b1  = (const float*)d_in[6];
  p.bih = (const float*)d_in[9]; p.bhh = (const float*)d_in[10];
  p.W2 = (const float*)d_in[11]; p.b2  = (const float*)d_in[12];
  p.W3 = (const float*)d_in[13]; p.b3  = (const float*)d_in[14];
  p.wih8 = ws + WS_WIH;  p.whh8 = ws + WS_WHH;
  p.l1g = (float*)(ws + WS_L1G); p.hb = (float*)(ws + WS_HB);
  p.slots = (float*)(ws + WS_SLOT); p.bar = (uint32_t*)(ws + WS_BAR);
  p.out = (float*)d_out;
  p.KRI = KRI; p.KRH = KRH;

  knet_main<<<NBLK, NTHR, (size_t)o.total, stream>>>(p);
}

// Round 4
// 15433.591 us; speedup vs baseline: 1.1919x; 1.1754x over previous
//
// KalmanNetNN persistent kernel, MI355X (gfx950).
// R4: TWO grid barriers/step (was 3) + no l1 global round-trip.
//   step t: P_gate[W_ih@l1(t)+ghh(t-1)->h(t)] B1 P_h[ghh(t)=W_hh@h, l2=W2@h,
//   slots] B2 P_x[gather slots->XPO->redundant small chain-> full l1(t+1)].
//   l1 computed REDUNDANTLY per block from fp8 W1ext (bias folded, 64B rows,
//   L2-resident). W_hh + W2 slices fully LDS-resident fp8 (in-kernel cvt).
//   W_ih: 1600 cols LDS-resident fp8 + 2560 cols streamed fp8 from d_ws.
// d_ws use: 29.2 MB (under proven 45.1 MB).

#include <hip/hip_runtime.h>
#include <stdint.h>
#include <stddef.h>

typedef float v2f __attribute__((ext_vector_type(2)));

#define HID   2320
#define G3    6960
#define KIH   4160
#define KHH   2320
#define NBLK  240
#define NTHR  512
#define NGATE 232
#define UPB   10
#define TSEQ  512
#define KRIRES 1600
#define INVWS (1.0f/128.0f)

// ---------------- workspace layout (bytes) ----------------
#define WS_WIH8 0L
#define WS_W1E  28953600L   // 6960*4160 fp8
#define WS_HB   29219840L   // 4160*64 fp8 (W1ext: 52 w + b1 + 11 zero pad)
#define WS_SLOT 29229120L   // hb 2320 f32 (pad)
#define WS_BAR  29232960L   // slots 240*16
#define WS_END  29233728L   // bar u32[192]

struct Offs {
  int l1s, hs, wih, whh, w2s, w3s, cs, as_, b3s, bih, bhh, b2s, gis, ghs,
      l2r, ts, inn, kn, dxs, xpri, xpo, b4, nrm, cb, slp;
  int total;
};

__host__ __device__ inline Offs mkoffs(int kri, int whhres, int w2res) {
  Offs o; int p = 0;
#define ALLOC(name, bytes) { p = (p + 15) & ~15; o.name = p; p += (bytes); }
  ALLOC(l1s, KIH*4) ALLOC(hs, HID*4)
  ALLOC(wih, 30*kri) ALLOC(whh, whhres ? 30*KHH : 16) ALLOC(w2s, w2res ? 4*HID : 16)
  ALLOC(w3s, 16*48*4) ALLOC(cs, 240*4) ALLOC(as_, 64) ALLOC(b3s, 192*4)
  ALLOC(bih, 120) ALLOC(bhh, 120) ALLOC(b2s, 16)
  ALLOC(gis, 120) ALLOC(ghs, 120)
  ALLOC(l2r, 16) ALLOC(ts, 64) ALLOC(inn, 192) ALLOC(kn, 256)
  ALLOC(dxs, 16) ALLOC(xpri, 16) ALLOC(xpo, 16) ALLOC(b4, 16) ALLOC(nrm, 16)
  ALLOC(cb, 16) ALLOC(slp, 64)
#undef ALLOC
  o.total = (p + 63) & ~63;
  return o;
}

struct Params {
  const float *A, *C, *x0, *h0, *y, *W1, *b1, *Wih, *Whh, *bih, *bhh, *W2, *b2, *W3, *b3;
  const uint8_t *wih8;
  const uint8_t *w1e;   // may be null (f32-W1 fallback)
  float *hb, *slots, *out;
  uint32_t *bar;
  int kri, whhres, w2res;
};

__device__ __forceinline__ uint8_t f2fp8(float v) {
  v = fminf(fmaxf(v * 128.f, -448.f), 448.f);
  int pk = __builtin_amdgcn_cvt_pk_fp8_f32(v, v, 0, false);
  return (uint8_t)(pk & 0xff);
}

// Two-level grid barrier: 8 group lines -> root line -> epoch line.
__device__ __forceinline__ void gbar(uint32_t* bar, int tid, int bid,
                                     uint32_t target, bool& dead) {
  __syncthreads();
  if (tid == 0 && !dead) {
    __builtin_amdgcn_fence(__ATOMIC_RELEASE, "agent");
    uint32_t g = (uint32_t)(bid & 7);
    uint32_t old = __hip_atomic_fetch_add(&bar[g*16], 1u, __ATOMIC_RELAXED,
                                          __HIP_MEMORY_SCOPE_AGENT);
    if ((old % 30u) == 29u) {
      uint32_t r = __hip_atomic_fetch_add(&bar[128], 1u, __ATOMIC_RELAXED,
                                          __HIP_MEMORY_SCOPE_AGENT);
      if ((r & 7u) == 7u)
        __hip_atomic_fetch_add(&bar[160], 1u, __ATOMIC_RELEASE,
                               __HIP_MEMORY_SCOPE_AGENT);
    }
    uint32_t spins = 0;
    while (__hip_atomic_load(&bar[160], __ATOMIC_RELAXED,
                             __HIP_MEMORY_SCOPE_AGENT) < target) {
      __builtin_amdgcn_s_sleep(2);
      if (++spins > (1u << 20)) { dead = true; break; }
    }
    __builtin_amdgcn_fence(__ATOMIC_ACQUIRE, "agent");
  }
  __syncthreads();
}

// fp8 row-dot, weights LDS-resident, row-major stride; <=4 rows per wave.
__device__ __forceinline__ void dot8_lds(
    const float* __restrict__ acts, const uint8_t* __restrict__ w, int stride,
    int K, const int* lrows, int nr, int lane, float acc[4])
{
  int kb = 0;
  for (; kb + 256 <= K; kb += 256) {
    const float4 a = ((const float4*)(acts + kb))[lane];
#pragma unroll
    for (int j = 0; j < 4; ++j) if (j < nr) {
      uint32_t wb = *(const uint32_t*)(w + (size_t)lrows[j]*stride + kb + (lane<<2));
      v2f lo = __builtin_amdgcn_cvt_pk_f32_fp8((int)wb, false);
      v2f hi = __builtin_amdgcn_cvt_pk_f32_fp8((int)wb, true);
      acc[j] = fmaf(lo.x, a.x, acc[j]); acc[j] = fmaf(lo.y, a.y, acc[j]);
      acc[j] = fmaf(hi.x, a.z, acc[j]); acc[j] = fmaf(hi.y, a.w, acc[j]);
    }
  }
  int rem = K - kb;
  if ((lane << 2) < rem) {
    const float4 a = ((const float4*)(acts + kb))[lane];
#pragma unroll
    for (int j = 0; j < 4; ++j) if (j < nr) {
      uint32_t wb = *(const uint32_t*)(w + (size_t)lrows[j]*stride + kb + (lane<<2));
      v2f lo = __builtin_amdgcn_cvt_pk_f32_fp8((int)wb, false);
      v2f hi = __builtin_amdgcn_cvt_pk_f32_fp8((int)wb, true);
      acc[j] = fmaf(lo.x, a.x, acc[j]); acc[j] = fmaf(lo.y, a.y, acc[j]);
      acc[j] = fmaf(hi.x, a.z, acc[j]); acc[j] = fmaf(hi.y, a.w, acc[j]);
    }
  }
}

// fp8 row-dot, weights streamed from global, cols [K0,K), 8B loads.
__device__ __forceinline__ void dot8_glb(
    const float* __restrict__ acts, const uint8_t* __restrict__ gw, int gstride,
    int K0, int K, const int* grows, int nr, int lane, float acc[4])
{
  int kb = K0;
  for (; kb + 512 <= K; kb += 512) {
    const float4 a0 = ((const float4*)(acts + kb))[lane*2];
    const float4 a1 = ((const float4*)(acts + kb))[lane*2 + 1];
#pragma unroll
    for (int j = 0; j < 4; ++j) if (j < nr) {
      uint2 wb = *(const uint2*)(gw + (size_t)grows[j]*gstride + kb + (lane<<3));
      v2f l0 = __builtin_amdgcn_cvt_pk_f32_fp8((int)wb.x, false);
      v2f h0 = __builtin_amdgcn_cvt_pk_f32_fp8((int)wb.x, true);
      v2f l1 = __builtin_amdgcn_cvt_pk_f32_fp8((int)wb.y, false);
      v2f h1 = __builtin_amdgcn_cvt_pk_f32_fp8((int)wb.y, true);
      acc[j] = fmaf(l0.x, a0.x, acc[j]); acc[j] = fmaf(l0.y, a0.y, acc[j]);
      acc[j] = fmaf(h0.x, a0.z, acc[j]); acc[j] = fmaf(h0.y, a0.w, acc[j]);
      acc[j] = fmaf(l1.x, a1.x, acc[j]); acc[j] = fmaf(l1.y, a1.y, acc[j]);
      acc[j] = fmaf(h1.x, a1.z, acc[j]); acc[j] = fmaf(h1.y, a1.w, acc[j]);
    }
  }
  for (int e = kb + lane; e < K; e += 64) {
    float a = acts[e];
#pragma unroll
    for (int j = 0; j < 4; ++j) if (j < nr) {
      v2f lo = __builtin_amdgcn_cvt_pk_f32_fp8(
          (int)(uint32_t)gw[(size_t)grows[j]*gstride + e], false);
      acc[j] = fmaf(lo.x, a, acc[j]);
    }
  }
}

// f32 row-dot fallback (insurance path only).
__device__ __forceinline__ void dotf_glb(
    const float* __restrict__ acts, const float* __restrict__ gw, int gstride,
    int K, const int* grows, int nr, int lane, float acc[4])
{
  for (int k = lane; k < K; k += 64) {
    float a = acts[k];
#pragma unroll
    for (int j = 0; j < 4; ++j) if (j < nr)
      acc[j] = fmaf(gw[(size_t)grows[j]*gstride + k], a, acc[j]);
  }
}

extern "C" __global__ void __launch_bounds__(NTHR, 2) knet_main(Params p)
{
  extern __shared__ char smem[];
  const Offs o = mkoffs(p.kri, p.whhres, p.w2res);
  float*   L1S  = (float*)(smem + o.l1s);
  float*   HS   = (float*)(smem + o.hs);
  uint8_t* WIHR = (uint8_t*)(smem + o.wih);
  uint8_t* WHHR = (uint8_t*)(smem + o.whh);
  uint8_t* W2S  = (uint8_t*)(smem + o.w2s);
  float*   W3S  = (float*)(smem + o.w3s);
  float*   CS   = (float*)(smem + o.cs);
  float*   AS   = (float*)(smem + o.as_);
  float*   B3S  = (float*)(smem + o.b3s);
  float*   BIH  = (float*)(smem + o.bih);
  float*   BHH  = (float*)(smem + o.bhh);
  float*   B2S  = (float*)(smem + o.b2s);
  float*   GIS  = (float*)(smem + o.gis);
  float*   GHS  = (float*)(smem + o.ghs);
  float*   L2R  = (float*)(smem + o.l2r);
  float*   TS   = (float*)(smem + o.ts);
  float*   INNS = (float*)(smem + o.inn);
  float*   KN   = (float*)(smem + o.kn);
  float*   DXS  = (float*)(smem + o.dxs);
  float*   XPRI = (float*)(smem + o.xpri);
  float*   XPO  = (float*)(smem + o.xpo);
  float*   B4   = (float*)(smem + o.b4);
  float*   NRM  = (float*)(smem + o.nrm);
  float*   CB   = (float*)(smem + o.cb);
  float*   SLP  = (float*)(smem + o.slp);

  const int tid  = (int)threadIdx.x;
  const int bid  = (int)blockIdx.x;
  const int lane = tid & 63;
  const int wv   = tid >> 6;
  const bool gate = (bid < NGATE);
  const int rows2 = (bid < 48) ? 4 : 3;
  const int r2s   = (bid < 48) ? bid*4 : 192 + (bid-48)*3;
  bool dead = false;
  uint32_t et = 0;

  // per-wave gate row assignment: rows wv, wv+8, wv+16, wv+24 of the 30.
  int lrows[4] = {0,0,0,0}, grows[4] = {0,0,0,0};
  int nr = 0;
  if (gate) {
#pragma unroll
    for (int j = 0; j < 4; ++j) {
      int row = wv + 8*j;
      if (row < 30) { int u = row/3, g = row - 3*u;
        lrows[nr] = row; grows[nr] = g*HID + bid*UPB + u; ++nr; }
    }
  }

  // ---------------- one-time staging ----------------
  for (int i = tid; i < rows2*192; i += NTHR) { int rl = i/192, rem = i - rl*192;
    W3S[i] = p.W3[(size_t)rem*768 + (r2s + rl)]; }     // W3S[rl*192 + i*48 + j]
  for (int i = tid; i < 240; i += NTHR) CS[i] = p.C[i];
  if (tid < 16) AS[tid] = p.A[tid];
  for (int i = tid; i < 192; i += NTHR) B3S[i] = p.b3[i];
  if (tid < rows2) B2S[tid] = p.b2[r2s + tid];
  if (gate && tid < 30) {
    int u = tid/3, g = tid - 3*u, ug = bid*UPB + u;
    BIH[tid] = p.bih[g*HID + ug];
    BHH[tid] = p.bhh[g*HID + ug];
  }
  for (int i = tid; i < HID; i += NTHR) HS[i] = p.h0[i];
  if (gate && p.kri > 0) {                    // resident W_ih cols from fp8 ws
    const int kd = p.kri >> 2;
    uint32_t* W32 = (uint32_t*)WIHR;
    for (int i = tid; i < 30*kd; i += NTHR) {
      int row = i / kd, c = i - row*kd;
      int u = row/3, g = row - 3*u, gr = g*HID + bid*UPB + u;
      W32[i] = ((const uint32_t*)p.wih8)[(size_t)gr*(KIH/4) + c];
    }
  }
  if (gate && p.whhres) {                     // W_hh rows: in-kernel f32->fp8
    for (int i = tid; i < 30*KHH; i += NTHR) {
      int row = i / KHH, k = i - row*KHH;
      int u = row/3, g = row - 3*u, gr = g*HID + bid*UPB + u;
      WHHR[i] = f2fp8(p.Whh[(size_t)gr*KHH + k]);
    }
  }
  if (p.w2res) {                              // W2 slice: in-kernel f32->fp8
    for (int i = tid; i < rows2*HID; i += NTHR) {
      int rl = i / HID, k = i - rl*HID;
      W2S[i] = f2fp8(p.W2[(size_t)(r2s+rl)*HID + k]);
    }
  }
  __syncthreads();

  // small chain producing step-`ycol` inputs: inn, norms, KN, B4, TS, full l1.
  auto small_chain = [&](int ycol) {
    if (tid < 48) {
      float s = CS[tid*5 + 4];
#pragma unroll
      for (int k = 0; k < 4; ++k) s += CS[tid*5 + k] * XPRI[k];
      INNS[tid] = p.y[(size_t)tid*TSEQ + ycol] - s;
    }
    __syncthreads();
    if (tid == 0) {
      float s = 0;
      for (int j = 0; j < 48; ++j) s += INNS[j]*INNS[j];
      NRM[0] = fmaxf(sqrtf(s), 1e-12f);
      float s2 = 0;
      for (int j = 0; j < 4; ++j) s2 += DXS[j]*DXS[j];
      NRM[1] = fmaxf(sqrtf(s2), 1e-12f);
    }
    __syncthreads();
    if (tid < 48) KN[tid] = INNS[tid] / NRM[0];
    else if (tid < 52) KN[tid] = DXS[tid-48] / NRM[1];
    else if (tid == 52) KN[tid] = 1.0f;       // bias column of W1ext
    else if (tid < 64) KN[tid] = 0.0f;        // zero pad
    else if (tid < 68) {
      int i = tid - 64; float s = 0;
      for (int j = 0; j < 48; ++j) s += B3S[i*48 + j] * INNS[j];
      B4[i] = s;
    }
    if (tid >= 128 && tid < 128 + rows2*4) {
      int idx = tid - 128, rl = idx >> 2, i = idx & 3;
      float s = 0;
      for (int j = 0; j < 48; ++j) s += W3S[rl*192 + i*48 + j] * INNS[j];
      TS[i*4 + rl] = s;
    }
    __syncthreads();
    if (gate) {
      if (p.w1e) {
        float4 kn[16];
#pragma unroll
        for (int c = 0; c < 16; ++c) kn[c] = ((const float4*)KN)[c];
        for (int r = tid; r < KIH; r += NTHR) {
          const uint4* wp = (const uint4*)(p.w1e + (size_t)r*64);
          float acc = 0.f;
#pragma unroll
          for (int q = 0; q < 4; ++q) {
            uint4 w = wp[q];
            v2f l0 = __builtin_amdgcn_cvt_pk_f32_fp8((int)w.x, false);
            v2f h0 = __builtin_amdgcn_cvt_pk_f32_fp8((int)w.x, true);
            v2f l1 = __builtin_amdgcn_cvt_pk_f32_fp8((int)w.y, false);
            v2f h1 = __builtin_amdgcn_cvt_pk_f32_fp8((int)w.y, true);
            v2f l2 = __builtin_amdgcn_cvt_pk_f32_fp8((int)w.z, false);
            v2f h2 = __builtin_amdgcn_cvt_pk_f32_fp8((int)w.z, true);
            v2f l3 = __builtin_amdgcn_cvt_pk_f32_fp8((int)w.w, false);
            v2f h3 = __builtin_amdgcn_cvt_pk_f32_fp8((int)w.w, true);
            float4 a0 = kn[q*4+0], a1 = kn[q*4+1], a2 = kn[q*4+2], a3 = kn[q*4+3];
            acc = fmaf(l0.x,a0.x,acc); acc = fmaf(l0.y,a0.y,acc);
            acc = fmaf(h0.x,a0.z,acc); acc = fmaf(h0.y,a0.w,acc);
            acc = fmaf(l1.x,a1.x,acc); acc = fmaf(l1.y,a1.y,acc);
            acc = fmaf(h1.x,a1.z,acc); acc = fmaf(h1.y,a1.w,acc);
            acc = fmaf(l2.x,a2.x,acc); acc = fmaf(l2.y,a2.y,acc);
            acc = fmaf(h2.x,a2.z,acc); acc = fmaf(h2.y,a2.w,acc);
            acc = fmaf(l3.x,a3.x,acc); acc = fmaf(l3.y,a3.y,acc);
            acc = fmaf(h3.x,a3.z,acc); acc = fmaf(h3.y,a3.w,acc);
          }
          L1S[r] = fmaxf(acc * INVWS, 0.f);
        }
      } else {                                 // f32 W1 fallback
        for (int r = tid; r < KIH; r += NTHR) {
          const float4* wp = (const float4*)(p.W1 + (size_t)r*52);
          float acc = p.b1[r];
#pragma unroll 13
          for (int q = 0; q < 13; ++q) {
            float4 w = wp[q]; float4 a = ((const float4*)KN)[q];
            acc = fmaf(w.x,a.x,acc); acc = fmaf(w.y,a.y,acc);
            acc = fmaf(w.z,a.z,acc); acc = fmaf(w.w,a.w,acc);
          }
          L1S[r] = fmaxf(acc, 0.f);
        }
      }
    }
    __syncthreads();
  };

  auto compute_ghh = [&]() {                   // W_hh @ HS partials -> GHS
    if (!gate) return;
    float acc[4] = {0,0,0,0};
    if (p.whhres) dot8_lds(HS, WHHR, KHH, KHH, lrows, nr, lane, acc);
    else          dotf_glb(HS, p.Whh, KHH, KHH, grows, nr, lane, acc);
#pragma unroll
    for (int m = 32; m >= 1; m >>= 1)
#pragma unroll
      for (int j = 0; j < 4; ++j) acc[j] += __shfl_xor(acc[j], m, 64);
    if (lane == 0)
#pragma unroll
      for (int j = 0; j < 4; ++j) if (j < nr) GHS[lrows[j]] = acc[j];
  };

  // ---------------- pre-loop ----------------
  if (tid < 4) { XPO[tid] = p.x0[tid]; DXS[tid] = 0.f; }
  __syncthreads();
  if (tid < 4) {
    float s = 0;
#pragma unroll
    for (int j = 0; j < 4; ++j) s += AS[tid*4 + j] * XPO[j];
    XPRI[tid] = s;
  }
  __syncthreads();
  small_chain(0);            // inn/KN/B4/TS/l1 for t=0
  compute_ghh();             // W_hh @ h0
  __syncthreads();

  // ---------------- main sequence ----------------
  for (int t = 0; t < TSEQ; ++t) {
    // ---- P_gate: gi = W_ih @ l1(t); h(t) = GRU(gi+ghh) ----
    if (gate) {
      float acc[4] = {0,0,0,0};
      if (p.kri > 0) dot8_lds(L1S, WIHR, p.kri, p.kri, lrows, nr, lane, acc);
      dot8_glb(L1S, p.wih8, KIH, p.kri, KIH, grows, nr, lane, acc);
#pragma unroll
      for (int m = 32; m >= 1; m >>= 1)
#pragma unroll
        for (int j = 0; j < 4; ++j) acc[j] += __shfl_xor(acc[j], m, 64);
      if (lane == 0)
#pragma unroll
        for (int j = 0; j < 4; ++j) if (j < nr) GIS[lrows[j]] = acc[j];
    }
    __syncthreads();
    if (gate && tid < UPB) {
      int ug = bid*UPB + tid, r0 = tid*3;
      float gi0 = GIS[r0+0]*INVWS + BIH[r0+0], gh0 = GHS[r0+0]*INVWS + BHH[r0+0];
      float gi1 = GIS[r0+1]*INVWS + BIH[r0+1], gh1 = GHS[r0+1]*INVWS + BHH[r0+1];
      float gi2 = GIS[r0+2]*INVWS + BIH[r0+2], gh2 = GHS[r0+2]*INVWS + BHH[r0+2];
      float rg = 1.f/(1.f + expf(-(gi0+gh0)));
      float zg = 1.f/(1.f + expf(-(gi1+gh1)));
      float ng = tanhf(gi2 + rg*gh2);
      p.hb[ug] = (1.f - zg)*ng + zg*HS[ug];
    }
    gbar(p.bar, tid, bid, ++et, dead);

    // ---- P_h: HS<-h(t); ghh(t) for t+1; l2 = W2@h; slot write ----
    for (int i = tid; i < HID/4; i += NTHR)
      ((float4*)HS)[i] = ((const float4*)p.hb)[i];
    __syncthreads();
    compute_ghh();
    if (wv < rows2) {                          // l2 row per wave
      float acc = 0.f;
      if (p.w2res) {
        const uint8_t* wr = W2S + (size_t)wv*HID;
#pragma unroll 3
        for (int i = 0; i < 9; ++i) {
          int k = (lane + (i<<6)) << 2;        // dword index *4 = byte/elem
          uint32_t wb = *(const uint32_t*)(wr + k);
          const float4 a = ((const float4*)HS)[lane + (i<<6)];
          v2f lo = __builtin_amdgcn_cvt_pk_f32_fp8((int)wb, false);
          v2f hi = __builtin_amdgcn_cvt_pk_f32_fp8((int)wb, true);
          acc = fmaf(lo.x, a.x, acc); acc = fmaf(lo.y, a.y, acc);
          acc = fmaf(hi.x, a.z, acc); acc = fmaf(hi.y, a.w, acc);
        }
        if (lane < 4) {                        // tail: dwords 576..579
          int k = (576 + lane) << 2;
          uint32_t wb = *(const uint32_t*)(wr + k);
          const float4 a = ((const float4*)HS)[576 + lane];
          v2f lo = __builtin_amdgcn_cvt_pk_f32_fp8((int)wb, false);
          v2f hi = __builtin_amdgcn_cvt_pk_f32_fp8((int)wb, true);
          acc = fmaf(lo.x, a.x, acc); acc = fmaf(lo.y, a.y, acc);
          acc = fmaf(hi.x, a.z, acc); acc = fmaf(hi.y, a.w, acc);
        }
        acc *= INVWS;
      } else {
        const float* wr = p.W2 + (size_t)(r2s+wv)*HID;
        for (int k = lane; k < HID; k += 64) acc = fmaf(wr[k], HS[k], acc);
      }
#pragma unroll
      for (int m = 32; m >= 1; m >>= 1) acc += __shfl_xor(acc, m, 64);
      if (lane == 0) L2R[wv] = fmaxf(acc + B2S[wv], 0.f);
    }
    __syncthreads();
    if (tid < 4) {
      float cp = 0;
      for (int rl = 0; rl < rows2; ++rl) cp += L2R[rl] * TS[tid*4 + rl];
      CB[tid] = cp;
    }
    __syncthreads();
    if (tid == 0)
      ((float4*)p.slots)[bid] = make_float4(CB[0], CB[1], CB[2], CB[3]);
    gbar(p.bar, tid, bid, ++et, dead);

    // ---- P_x: gather slots -> XPO(t) -> next-step chain (all local) ----
    if (wv < 4) {
      int s = (wv << 6) | lane;
      float4 v = make_float4(0.f, 0.f, 0.f, 0.f);
      if (s < NBLK) v = ((const float4*)p.slots)[s];
#pragma unroll
      for (int m = 32; m >= 1; m >>= 1) {
        v.x += __shfl_xor(v.x, m, 64); v.y += __shfl_xor(v.y, m, 64);
        v.z += __shfl_xor(v.z, m, 64); v.w += __shfl_xor(v.w, m, 64);
      }
      if (lane == 0) ((float4*)SLP)[wv] = v;
    }
    __syncthreads();
    if (tid < 4) {
      float c = SLP[tid] + SLP[4 + tid] + SLP[8 + tid] + SLP[12 + tid];
      float xp = XPRI[tid] + (c + B4[tid]) * 1e-4f;
      XPO[tid] = xp;
      if (bid == 0) p.out[(size_t)tid*TSEQ + t] = xp;
    }
    __syncthreads();
    if (t + 1 < TSEQ) {
      if (tid < 4) {
        float xo = XPO[tid];
        DXS[tid] = xo - XPRI[tid];             // dx uses OLD prior
        float s = 0;
#pragma unroll
        for (int j = 0; j < 4; ++j) s += AS[tid*4 + j] * XPO[j];
        XPRI[tid] = s;                          // new prior A@x_post
      }
      __syncthreads();
      small_chain(t + 1);                       // ends with syncthreads
    }
  }
}

// f32 -> fp8 e4m3 (x128), 4 elements per thread (W_ih full).
extern "C" __global__ void knet_cvt_fp8(const float* __restrict__ src,
                                        uint8_t* __restrict__ dst, long n4) {
  long stride = (long)gridDim.x * blockDim.x;
  for (long i = (long)blockIdx.x*blockDim.x + threadIdx.x; i < n4; i += stride) {
    float4 v = ((const float4*)src)[i];
    float a0 = fminf(fmaxf(v.x * 128.f, -448.f), 448.f);
    float a1 = fminf(fmaxf(v.y * 128.f, -448.f), 448.f);
    float a2 = fminf(fmaxf(v.z * 128.f, -448.f), 448.f);
    float a3 = fminf(fmaxf(v.w * 128.f, -448.f), 448.f);
    int pk = __builtin_amdgcn_cvt_pk_fp8_f32(a0, a1, 0, false);
    pk = __builtin_amdgcn_cvt_pk_fp8_f32(a2, a3, pk, true);
    ((uint32_t*)dst)[i] = (uint32_t)pk;
  }
}

// Build W1ext fp8: row r = [W1[r,0:52], b1[r], 0 x11] * 128, 64 B/row.
extern "C" __global__ void knet_build_w1e(const float* __restrict__ W1,
                                          const float* __restrict__ b1,
                                          uint8_t* __restrict__ dst) {
  int r = blockIdx.x * blockDim.x + threadIdx.x;
  if (r >= KIH) return;
  float v[64];
#pragma unroll 13
  for (int q = 0; q < 13; ++q) {
    float4 w = ((const float4*)(W1 + (size_t)r*52))[q];
    v[q*4+0] = w.x; v[q*4+1] = w.y; v[q*4+2] = w.z; v[q*4+3] = w.w;
  }
  v[52] = b1[r];
  for (int i = 53; i < 64; ++i) v[i] = 0.f;
  uint32_t out[16];
#pragma unroll 16
  for (int d = 0; d < 16; ++d) {
    float a0 = fminf(fmaxf(v[d*4+0] * 128.f, -448.f), 448.f);
    float a1 = fminf(fmaxf(v[d*4+1] * 128.f, -448.f), 448.f);
    float a2 = fminf(fmaxf(v[d*4+2] * 128.f, -448.f), 448.f);
    float a3 = fminf(fmaxf(v[d*4+3] * 128.f, -448.f), 448.f);
    int pk = __builtin_amdgcn_cvt_pk_fp8_f32(a0, a1, 0, false);
    pk = __builtin_amdgcn_cvt_pk_fp8_f32(a2, a3, pk, true);
    out[d] = (uint32_t)pk;
  }
  uint4* dp = (uint4*)(dst + (size_t)r*64);
#pragma unroll 4
  for (int q = 0; q < 4; ++q)
    dp[q] = make_uint4(out[q*4+0], out[q*4+1], out[q*4+2], out[q*4+3]);
}

extern "C" void kernel_launch(void* const* d_in, const int* in_sizes, int n_in,
                              void* d_out, int out_size, void* d_ws, size_t ws_size,
                              hipStream_t stream)
{
  if (ws_size < (size_t)WS_END) return;   // needs 29.3 MB (proven >=45 MB avail)
  uint8_t* ws = (uint8_t*)d_ws;

  knet_cvt_fp8<<<2048, 256, 0, stream>>>((const float*)d_in[7], ws + WS_WIH8,
                                         (long)G3*KIH/4);
  knet_build_w1e<<<(KIH + 255)/256, 256, 0, stream>>>(
      (const float*)d_in[5], (const float*)d_in[6], ws + WS_W1E);
  (void)hipMemsetAsync(ws + WS_BAR, 0, (size_t)(WS_END - WS_BAR), stream);

  // Primary: ~159 KB LDS (W_ih 1600-col + full W_hh + W2 slice resident).
  int kri = KRIRES, whhres = 1, w2res = 1;
  Offs o = mkoffs(kri, whhres, w2res);
  hipError_t e = hipFuncSetAttribute((const void*)knet_main,
                                     hipFuncAttributeMaxDynamicSharedMemorySize,
                                     o.total);
  if (e != hipSuccess) {   // insurance: minimal-LDS streamed config
    kri = 0; whhres = 0; w2res = 0;
    o = mkoffs(kri, whhres, w2res);
    (void)hipFuncSetAttribute((const void*)knet_main,
                              hipFuncAttributeMaxDynamicSharedMemorySize, o.total);
  }

  Params p;
  p.A   = (const float*)d_in[0];  p.C   = (const float*)d_in[1];
  p.x0  = (const float*)d_in[2];  p.h0  = (const float*)d_in[3];
  p.y   = (const float*)d_in[4];
  p.W1  = (const float*)d_in[5];  p.b1  = (const float*)d_in[6];
  p.Wih = (const float*)d_in[7];  p.Whh = (const float*)d_in[8];
  p.bih = (const float*)d_in[9];  p.bhh = (const float*)d_in[10];
  p.W2  = (const float*)d_in[11]; p.b2  = (const float*)d_in[12];
  p.W3  = (const float*)d_in[13]; p.b3  = (const float*)d_in[14];
  p.wih8 = ws + WS_WIH8;
  p.w1e  = ws + WS_W1E;
  p.hb   = (float*)(ws + WS_HB);
  p.slots = (float*)(ws + WS_SLOT);
  p.bar  = (uint32_t*)(ws + WS_BAR);
  p.out  = (float*)d_out;
  p.kri = kri; p.whhres = whhres; p.w2res = w2res;

  knet_main<<<NBLK, NTHR, (size_t)o.total, stream>>>(p);
}

// Round 5
// 10950.216 us; speedup vs baseline: 1.6798x; 1.4094x over previous
//
// KalmanNetNN persistent kernel, MI355X (gfx950).
// R5: ZERO grid barriers — dataflow sync via step-tagged packets.
//   h broadcast: 232 producer packets (10 f32 + tag, 64B, parity x2);
//   slot reduce: 240 packets (4 f32 + tag). Producers: agent atomic data
//   stores + RELEASE tag store (wave vmcnt orders data<tag). Consumers:
//   per-lane tag poll (waves 0-3) + agent atomic data loads.
//   W_ih fully on-chip: 1600 cols LDS + 2560 cols hoisted into VGPRs (const
//   across steps). W_hh/W2 LDS-resident fp8. l1 redundant per gate block
//   from fp8 W1ext (L2). Fallback cfg streams everything (if LDS cap <159KB).
// Predicted: 6-8 us/step -> 3.5-6.5 ms.

#include <hip/hip_runtime.h>
#include <stdint.h>
#include <stddef.h>

typedef float v2f __attribute__((ext_vector_type(2)));

#define HID   2320
#define G3    6960
#define KIH   4160
#define KHH   2320
#define NBLK  240
#define NTHR  512
#define NGATE 232
#define UPB   10
#define TSEQ  512
#define KRES  1600
#define INVWS (1.0f/128.0f)
#define SPINCAP (1u<<17)

// ---------------- workspace layout (bytes) ----------------
#define WS_WIH8 0L
#define WS_W1E  28953600L      // 6960*4160 fp8
#define WS_HBP  29219840L      // 4160*64 fp8 W1ext (52 w + b1 + pad)
#define WS_SLT  29249536L      // 2 x 232 x 64B h packets
#define WS_END  29280256L      // 2 x 240 x 64B slot packets

struct Offs {
  int l1s, hs, wih, whh, w2s, w3s, cs, as_, b3s, bih, bhh, b2s, gis, ghs,
      ts, inn, kn, dxs, xpri, xpo, b4, nrm, slp;
  int total;
};

__host__ __device__ inline Offs mkoffs(int res) {
  Offs o; int p = 0;
#define ALLOC(name, bytes) { p = (p + 15) & ~15; o.name = p; p += (bytes); }
  ALLOC(l1s, KIH*4) ALLOC(hs, HID*4)
  ALLOC(wih, res ? 30*KRES : 16) ALLOC(whh, res ? 30*KHH : 16)
  ALLOC(w2s, res ? 4*HID : 16)
  ALLOC(w3s, 16*48*4) ALLOC(cs, 240*4) ALLOC(as_, 64) ALLOC(b3s, 192*4)
  ALLOC(bih, 120) ALLOC(bhh, 120) ALLOC(b2s, 16)
  ALLOC(gis, 120) ALLOC(ghs, 120)
  ALLOC(ts, 64) ALLOC(inn, 192) ALLOC(kn, 256)
  ALLOC(dxs, 16) ALLOC(xpri, 16) ALLOC(xpo, 16) ALLOC(b4, 16) ALLOC(nrm, 16)
  ALLOC(slp, 64)
#undef ALLOC
  o.total = (p + 63) & ~63;
  return o;
}

struct Params {
  const float *A, *C, *x0, *h0, *y, *W1, *b1, *Wih, *Whh, *bih, *bhh, *W2, *b2, *W3, *b3;
  const uint8_t *wih8, *w1e;
  uint8_t *hbp, *slt;
  float *out;
  int resident;
};

__device__ __forceinline__ uint8_t f2fp8(float v) {
  v = fminf(fmaxf(v * 128.f, -448.f), 448.f);
  int pk = __builtin_amdgcn_cvt_pk_fp8_f32(v, v, 0, false);
  return (uint8_t)(pk & 0xff);
}

// fp8 row-dot, LDS weights, <=4 rows/wave, lanes split K.
__device__ __forceinline__ void dot8_lds(
    const float* __restrict__ acts, const uint8_t* __restrict__ w, int stride,
    int K, const int* lrows, int nr, int lane, float acc[4])
{
  int kb = 0;
  for (; kb + 256 <= K; kb += 256) {
    const float4 a = ((const float4*)(acts + kb))[lane];
#pragma unroll
    for (int j = 0; j < 4; ++j) if (j < nr) {
      uint32_t wb = *(const uint32_t*)(w + (size_t)lrows[j]*stride + kb + (lane<<2));
      v2f lo = __builtin_amdgcn_cvt_pk_f32_fp8((int)wb, false);
      v2f hi = __builtin_amdgcn_cvt_pk_f32_fp8((int)wb, true);
      acc[j] = fmaf(lo.x, a.x, acc[j]); acc[j] = fmaf(lo.y, a.y, acc[j]);
      acc[j] = fmaf(hi.x, a.z, acc[j]); acc[j] = fmaf(hi.y, a.w, acc[j]);
    }
  }
  int rem = K - kb;
  if ((lane << 2) < rem) {
    const float4 a = ((const float4*)(acts + kb))[lane];
#pragma unroll
    for (int j = 0; j < 4; ++j) if (j < nr) {
      uint32_t wb = *(const uint32_t*)(w + (size_t)lrows[j]*stride + kb + (lane<<2));
      v2f lo = __builtin_amdgcn_cvt_pk_f32_fp8((int)wb, false);
      v2f hi = __builtin_amdgcn_cvt_pk_f32_fp8((int)wb, true);
      acc[j] = fmaf(lo.x, a.x, acc[j]); acc[j] = fmaf(lo.y, a.y, acc[j]);
      acc[j] = fmaf(hi.x, a.z, acc[j]); acc[j] = fmaf(hi.y, a.w, acc[j]);
    }
  }
}

// fp8 row-dot, global weights, cols [K0,K).
__device__ __forceinline__ void dot8_glb(
    const float* __restrict__ acts, const uint8_t* __restrict__ gw, int gstride,
    int K0, int K, const int* grows, int nr, int lane, float acc[4])
{
  int kb = K0;
  for (; kb + 512 <= K; kb += 512) {
    const float4 a0 = ((const float4*)(acts + kb))[lane*2];
    const float4 a1 = ((const float4*)(acts + kb))[lane*2 + 1];
#pragma unroll
    for (int j = 0; j < 4; ++j) if (j < nr) {
      uint2 wb = *(const uint2*)(gw + (size_t)grows[j]*gstride + kb + (lane<<3));
      v2f l0 = __builtin_amdgcn_cvt_pk_f32_fp8((int)wb.x, false);
      v2f h0 = __builtin_amdgcn_cvt_pk_f32_fp8((int)wb.x, true);
      v2f l1 = __builtin_amdgcn_cvt_pk_f32_fp8((int)wb.y, false);
      v2f h1 = __builtin_amdgcn_cvt_pk_f32_fp8((int)wb.y, true);
      acc[j] = fmaf(l0.x, a0.x, acc[j]); acc[j] = fmaf(l0.y, a0.y, acc[j]);
      acc[j] = fmaf(h0.x, a0.z, acc[j]); acc[j] = fmaf(h0.y, a0.w, acc[j]);
      acc[j] = fmaf(l1.x, a1.x, acc[j]); acc[j] = fmaf(l1.y, a1.y, acc[j]);
      acc[j] = fmaf(h1.x, a1.z, acc[j]); acc[j] = fmaf(h1.y, a1.w, acc[j]);
    }
  }
  for (int e = kb + lane; e < K; e += 64) {
    float a = acts[e];
#pragma unroll
    for (int j = 0; j < 4; ++j) if (j < nr) {
      v2f lo = __builtin_amdgcn_cvt_pk_f32_fp8(
          (int)(uint32_t)gw[(size_t)grows[j]*gstride + e], false);
      acc[j] = fmaf(lo.x, a, acc[j]);
    }
  }
}

// f32 row-dot, global weights (fallback ghh).
__device__ __forceinline__ void dotf_glb(
    const float* __restrict__ acts, const float* __restrict__ gw, int gstride,
    int K, const int* grows, int nr, int lane, float acc[4])
{
  for (int k = lane; k < K; k += 64) {
    float a = acts[k];
#pragma unroll
    for (int j = 0; j < 4; ++j) if (j < nr)
      acc[j] = fmaf(gw[(size_t)grows[j]*gstride + k], a, acc[j]);
  }
}

extern "C" __global__ void __launch_bounds__(NTHR, 2) knet_main(Params p)
{
  extern __shared__ char smem[];
  const Offs o = mkoffs(p.resident);
  float*   L1S  = (float*)(smem + o.l1s);
  float*   HS   = (float*)(smem + o.hs);
  uint8_t* WIHR = (uint8_t*)(smem + o.wih);
  uint8_t* WHHR = (uint8_t*)(smem + o.whh);
  uint8_t* W2S  = (uint8_t*)(smem + o.w2s);
  float*   W3S  = (float*)(smem + o.w3s);
  float*   CS   = (float*)(smem + o.cs);
  float*   AS   = (float*)(smem + o.as_);
  float*   B3S  = (float*)(smem + o.b3s);
  float*   BIH  = (float*)(smem + o.bih);
  float*   BHH  = (float*)(smem + o.bhh);
  float*   B2S  = (float*)(smem + o.b2s);
  float*   GIS  = (float*)(smem + o.gis);
  float*   GHS  = (float*)(smem + o.ghs);
  float*   TS   = (float*)(smem + o.ts);
  float*   INNS = (float*)(smem + o.inn);
  float*   KN   = (float*)(smem + o.kn);
  float*   DXS  = (float*)(smem + o.dxs);
  float*   XPRI = (float*)(smem + o.xpri);
  float*   XPO  = (float*)(smem + o.xpo);
  float*   B4   = (float*)(smem + o.b4);
  float*   NRM  = (float*)(smem + o.nrm);
  float*   SLP  = (float*)(smem + o.slp);

  const int tid  = (int)threadIdx.x;
  const int bid  = (int)blockIdx.x;
  const int lane = tid & 63;
  const int wv   = tid >> 6;
  const bool gate = (bid < NGATE);
  const int rows2 = (bid < 48) ? 4 : 3;
  const int r2s   = (bid < 48) ? bid*4 : 192 + (bid-48)*3;
  bool dead = false;

  int lrows[4] = {0,0,0,0}, grows[4] = {0,0,0,0};
  int nr = 0;
  if (gate) {
#pragma unroll
    for (int j = 0; j < 4; ++j) {
      int row = wv + 8*j;
      if (row < 30) { int u = row/3, g = row - 3*u;
        lrows[nr] = row; grows[nr] = g*HID + bid*UPB + u; ++nr; }
    }
  }

  // ---------------- one-time staging ----------------
  for (int i = tid; i < rows2*192; i += NTHR) { int rl = i/192, rem = i - rl*192;
    W3S[i] = p.W3[(size_t)rem*768 + (r2s + rl)]; }
  for (int i = tid; i < 240; i += NTHR) CS[i] = p.C[i];
  if (tid < 16) AS[tid] = p.A[tid];
  for (int i = tid; i < 192; i += NTHR) B3S[i] = p.b3[i];
  if (tid < rows2) B2S[tid] = p.b2[r2s + tid];
  if (gate && tid < 30) {
    int u = tid/3, g = tid - 3*u, ug = bid*UPB + u;
    BIH[tid] = p.bih[g*HID + ug];
    BHH[tid] = p.bhh[g*HID + ug];
  }
  for (int i = tid; i < HID; i += NTHR) HS[i] = p.h0[i];
  if (p.resident) {
    if (gate) {
      const int kd = KRES >> 2;                 // W_ih resident cols from fp8 ws
      uint32_t* W32 = (uint32_t*)WIHR;
      for (int i = tid; i < 30*kd; i += NTHR) {
        int row = i / kd, c = i - row*kd;
        int u = row/3, g = row - 3*u, gr = g*HID + bid*UPB + u;
        W32[i] = ((const uint32_t*)p.wih8)[(size_t)gr*(KIH/4) + c];
      }
      for (int i = tid; i < 30*KHH; i += NTHR) { // W_hh rows f32->fp8
        int row = i / KHH, k = i - row*KHH;
        int u = row/3, g = row - 3*u, gr = g*HID + bid*UPB + u;
        WHHR[i] = f2fp8(p.Whh[(size_t)gr*KHH + k]);
      }
    }
    for (int i = tid; i < rows2*HID; i += NTHR) { // W2 slice f32->fp8
      int rl = i / HID, k = i - rl*HID;
      W2S[i] = f2fp8(p.W2[(size_t)(r2s+rl)*HID + k]);
    }
  }
  // streamed W_ih cols [KRES,4160) hoisted into VGPRs (constant across steps)
  uint2 pf[4][5];
#pragma unroll
  for (int j = 0; j < 4; ++j)
#pragma unroll
    for (int i = 0; i < 5; ++i) pf[j][i] = make_uint2(0u, 0u);
  if (gate) {
#pragma unroll
    for (int j = 0; j < 4; ++j) if (j < nr)
#pragma unroll
      for (int i = 0; i < 5; ++i)
        pf[j][i] = *(const uint2*)(p.wih8 + (size_t)grows[j]*KIH + KRES + i*512 + (lane<<3));
  }
  __syncthreads();

  // small chain producing step-`ycol` inputs: INNS, KN, B4, TS, full l1.
  auto small_chain = [&](int ycol) {
    if (tid < 48) {
      float s = CS[tid*5 + 4];
#pragma unroll
      for (int k = 0; k < 4; ++k) s += CS[tid*5 + k] * XPRI[k];
      INNS[tid] = p.y[(size_t)tid*TSEQ + ycol] - s;
    }
    __syncthreads();
    if (tid == 0) {
      float s = 0;
      for (int j = 0; j < 48; ++j) s += INNS[j]*INNS[j];
      NRM[0] = fmaxf(sqrtf(s), 1e-12f);
      float s2 = 0;
      for (int j = 0; j < 4; ++j) s2 += DXS[j]*DXS[j];
      NRM[1] = fmaxf(sqrtf(s2), 1e-12f);
    }
    __syncthreads();
    if (tid < 48) KN[tid] = INNS[tid] / NRM[0];
    else if (tid < 52) KN[tid] = DXS[tid-48] / NRM[1];
    else if (tid == 52) KN[tid] = 1.0f;
    else if (tid < 64) KN[tid] = 0.0f;
    else if (tid < 68) {
      int i = tid - 64; float s = 0;
      for (int j = 0; j < 48; ++j) s += B3S[i*48 + j] * INNS[j];
      B4[i] = s;
    }
    if (tid >= 128 && tid < 128 + rows2*4) {
      int idx = tid - 128, rl = idx >> 2, i = idx & 3;
      float s = 0;
      for (int j = 0; j < 48; ++j) s += W3S[rl*192 + i*48 + j] * INNS[j];
      TS[i*4 + rl] = s;
    }
    __syncthreads();
    if (gate) {                                  // redundant full l1
      float4 kn[16];
#pragma unroll
      for (int c = 0; c < 16; ++c) kn[c] = ((const float4*)KN)[c];
      for (int r = tid; r < KIH; r += NTHR) {
        const uint4* wp = (const uint4*)(p.w1e + (size_t)r*64);
        float acc = 0.f;
#pragma unroll
        for (int q = 0; q < 4; ++q) {
          uint4 w = wp[q];
          v2f l0 = __builtin_amdgcn_cvt_pk_f32_fp8((int)w.x, false);
          v2f h0 = __builtin_amdgcn_cvt_pk_f32_fp8((int)w.x, true);
          v2f l1 = __builtin_amdgcn_cvt_pk_f32_fp8((int)w.y, false);
          v2f h1 = __builtin_amdgcn_cvt_pk_f32_fp8((int)w.y, true);
          v2f l2 = __builtin_amdgcn_cvt_pk_f32_fp8((int)w.z, false);
          v2f h2 = __builtin_amdgcn_cvt_pk_f32_fp8((int)w.z, true);
          v2f l3 = __builtin_amdgcn_cvt_pk_f32_fp8((int)w.w, false);
          v2f h3 = __builtin_amdgcn_cvt_pk_f32_fp8((int)w.w, true);
          float4 a0 = kn[q*4+0], a1 = kn[q*4+1], a2 = kn[q*4+2], a3 = kn[q*4+3];
          acc = fmaf(l0.x,a0.x,acc); acc = fmaf(l0.y,a0.y,acc);
          acc = fmaf(h0.x,a0.z,acc); acc = fmaf(h0.y,a0.w,acc);
          acc = fmaf(l1.x,a1.x,acc); acc = fmaf(l1.y,a1.y,acc);
          acc = fmaf(h1.x,a1.z,acc); acc = fmaf(h1.y,a1.w,acc);
          acc = fmaf(l2.x,a2.x,acc); acc = fmaf(l2.y,a2.y,acc);
          acc = fmaf(h2.x,a2.z,acc); acc = fmaf(h2.y,a2.w,acc);
          acc = fmaf(l3.x,a3.x,acc); acc = fmaf(l3.y,a3.y,acc);
          acc = fmaf(h3.x,a3.z,acc); acc = fmaf(h3.y,a3.w,acc);
        }
        L1S[r] = fmaxf(acc * INVWS, 0.f);
      }
    }
    __syncthreads();
  };

  auto ghh = [&]() {                             // W_hh @ HS -> GHS
    if (!gate) return;
    float acc[4] = {0,0,0,0};
    if (p.resident) dot8_lds(HS, WHHR, KHH, KHH, lrows, nr, lane, acc);
    else            dotf_glb(HS, p.Whh, KHH, KHH, grows, nr, lane, acc);
#pragma unroll
    for (int m = 32; m >= 1; m >>= 1)
#pragma unroll
      for (int j = 0; j < 4; ++j) acc[j] += __shfl_xor(acc[j], m, 64);
    if (lane == 0)
#pragma unroll
      for (int j = 0; j < 4; ++j) if (j < nr) GHS[lrows[j]] = acc[j];
  };

  // ---------------- pre-loop ----------------
  if (tid < 4) { XPO[tid] = p.x0[tid]; DXS[tid] = 0.f; }
  __syncthreads();
  if (tid < 4) {
    float s = 0;
#pragma unroll
    for (int j = 0; j < 4; ++j) s += AS[tid*4 + j] * XPO[j];
    XPRI[tid] = s;
  }
  __syncthreads();
  small_chain(0);
  ghh();
  __syncthreads();

  // ---------------- main sequence (no grid barriers) ----------------
  for (int t = 0; t < TSEQ; ++t) {
    const int par = t & 1;
    const uint32_t want = (uint32_t)(t + 1);

    // ---- A: gate-dot gi = W_ih @ l1(t) ----
    if (gate) {
      float acc[4] = {0,0,0,0};
      if (p.resident) dot8_lds(L1S, WIHR, KRES, KRES, lrows, nr, lane, acc);
      else            dot8_glb(L1S, p.wih8, KIH, 0, KRES, grows, nr, lane, acc);
#pragma unroll
      for (int i = 0; i < 5; ++i) {              // VGPR-held streamed cols
        const float4 a0 = ((const float4*)(L1S + KRES + i*512))[lane*2];
        const float4 a1 = ((const float4*)(L1S + KRES + i*512))[lane*2 + 1];
#pragma unroll
        for (int j = 0; j < 4; ++j) if (j < nr) {
          uint2 w = pf[j][i];
          v2f l0 = __builtin_amdgcn_cvt_pk_f32_fp8((int)w.x, false);
          v2f h0 = __builtin_amdgcn_cvt_pk_f32_fp8((int)w.x, true);
          v2f l1v = __builtin_amdgcn_cvt_pk_f32_fp8((int)w.y, false);
          v2f h1 = __builtin_amdgcn_cvt_pk_f32_fp8((int)w.y, true);
          acc[j] = fmaf(l0.x, a0.x, acc[j]); acc[j] = fmaf(l0.y, a0.y, acc[j]);
          acc[j] = fmaf(h0.x, a0.z, acc[j]); acc[j] = fmaf(h0.y, a0.w, acc[j]);
          acc[j] = fmaf(l1v.x, a1.x, acc[j]); acc[j] = fmaf(l1v.y, a1.y, acc[j]);
          acc[j] = fmaf(h1.x, a1.z, acc[j]); acc[j] = fmaf(h1.y, a1.w, acc[j]);
        }
      }
#pragma unroll
      for (int m = 32; m >= 1; m >>= 1)
#pragma unroll
        for (int j = 0; j < 4; ++j) acc[j] += __shfl_xor(acc[j], m, 64);
      if (lane == 0)
#pragma unroll
        for (int j = 0; j < 4; ++j) if (j < nr) GIS[lrows[j]] = acc[j];
    }
    __syncthreads();

    // ---- B: h(t) + packet publish (wave 0 lanes 0..9) ----
    if (gate && tid < UPB) {
      int ug = bid*UPB + tid, r0 = tid*3;
      float gi0 = GIS[r0+0]*INVWS + BIH[r0+0], gh0 = GHS[r0+0]*INVWS + BHH[r0+0];
      float gi1 = GIS[r0+1]*INVWS + BIH[r0+1], gh1 = GHS[r0+1]*INVWS + BHH[r0+1];
      float gi2 = GIS[r0+2]*INVWS + BIH[r0+2], gh2 = GHS[r0+2]*INVWS + BHH[r0+2];
      float rg = 1.f/(1.f + expf(-(gi0+gh0)));
      float zg = 1.f/(1.f + expf(-(gi1+gh1)));
      float ng = tanhf(gi2 + rg*gh2);
      float hnew = (1.f - zg)*ng + zg*HS[ug];
      float* hd = (float*)p.hbp + (((size_t)par*NGATE + bid) << 4);
      __hip_atomic_store(hd + tid, hnew, __ATOMIC_RELAXED, __HIP_MEMORY_SCOPE_AGENT);
    }
    if (gate && tid == 0) {
      uint32_t* ht = (uint32_t*)p.hbp + (((size_t)par*NGATE + bid) << 4) + 15;
      __hip_atomic_store(ht, want, __ATOMIC_RELEASE, __HIP_MEMORY_SCOPE_AGENT);
    }
    __syncthreads();   // protect HS (old h) until B done before C overwrites

    // ---- C: h broadcast consume -> HS ----
    if (wv < 4) {
      int idx = (wv << 6) | lane;
      if (idx < NGATE) {
        const float* hd = (const float*)p.hbp + (((size_t)par*NGATE + idx) << 4);
        const uint32_t* ht = (const uint32_t*)hd + 15;
        uint32_t spins = 0;
        while (!dead && __hip_atomic_load(ht, __ATOMIC_RELAXED,
                                          __HIP_MEMORY_SCOPE_AGENT) != want) {
          __builtin_amdgcn_s_sleep(1);
          if (++spins > SPINCAP) dead = true;
        }
        float v[10];
#pragma unroll
        for (int k = 0; k < 10; ++k)
          v[k] = __hip_atomic_load(hd + k, __ATOMIC_RELAXED, __HIP_MEMORY_SCOPE_AGENT);
#pragma unroll
        for (int k = 0; k < 10; ++k) HS[idx*10 + k] = v[k];
      }
    }
    __syncthreads();

    // ---- D: l2 (wave 0 only) + slot publish ----
    if (wv == 0) {
      float a2[4] = {0,0,0,0};
      if (p.resident) {
        int kb = 0;
        for (; kb + 256 <= HID; kb += 256) {
          const float4 a = ((const float4*)(HS + kb))[lane];
#pragma unroll
          for (int rl = 0; rl < 4; ++rl) if (rl < rows2) {
            uint32_t wb = *(const uint32_t*)(W2S + rl*HID + kb + (lane<<2));
            v2f lo = __builtin_amdgcn_cvt_pk_f32_fp8((int)wb, false);
            v2f hi = __builtin_amdgcn_cvt_pk_f32_fp8((int)wb, true);
            a2[rl] = fmaf(lo.x, a.x, a2[rl]); a2[rl] = fmaf(lo.y, a.y, a2[rl]);
            a2[rl] = fmaf(hi.x, a.z, a2[rl]); a2[rl] = fmaf(hi.y, a.w, a2[rl]);
          }
        }
        if ((lane << 2) < HID - kb) {
          const float4 a = ((const float4*)(HS + kb))[lane];
#pragma unroll
          for (int rl = 0; rl < 4; ++rl) if (rl < rows2) {
            uint32_t wb = *(const uint32_t*)(W2S + rl*HID + kb + (lane<<2));
            v2f lo = __builtin_amdgcn_cvt_pk_f32_fp8((int)wb, false);
            v2f hi = __builtin_amdgcn_cvt_pk_f32_fp8((int)wb, true);
            a2[rl] = fmaf(lo.x, a.x, a2[rl]); a2[rl] = fmaf(lo.y, a.y, a2[rl]);
            a2[rl] = fmaf(hi.x, a.z, a2[rl]); a2[rl] = fmaf(hi.y, a.w, a2[rl]);
          }
        }
#pragma unroll
        for (int rl = 0; rl < 4; ++rl) a2[rl] *= INVWS;
      } else {
        for (int k = lane; k < HID; k += 64) {
          float a = HS[k];
#pragma unroll
          for (int rl = 0; rl < 4; ++rl) if (rl < rows2)
            a2[rl] = fmaf(p.W2[(size_t)(r2s+rl)*HID + k], a, a2[rl]);
        }
      }
#pragma unroll
      for (int m = 32; m >= 1; m >>= 1)
#pragma unroll
        for (int rl = 0; rl < 4; ++rl) a2[rl] += __shfl_xor(a2[rl], m, 64);
      if (lane == 0) {
        float l2v[4];
#pragma unroll
        for (int rl = 0; rl < 4; ++rl)
          l2v[rl] = (rl < rows2) ? fmaxf(a2[rl] + B2S[rl], 0.f) : 0.f;
        float* sd = (float*)p.slt + (((size_t)par*NBLK + bid) << 4);
#pragma unroll
        for (int i = 0; i < 4; ++i) {
          float cp = l2v[0]*TS[i*4+0] + l2v[1]*TS[i*4+1]
                   + l2v[2]*TS[i*4+2] + l2v[3]*TS[i*4+3];
          __hip_atomic_store(sd + i, cp, __ATOMIC_RELAXED, __HIP_MEMORY_SCOPE_AGENT);
        }
        __hip_atomic_store((uint32_t*)sd + 15, want, __ATOMIC_RELEASE,
                           __HIP_MEMORY_SCOPE_AGENT);
      }
    }

    // ---- E: ghh(t) for step t+1 (off critical path) ----
    ghh();

    // ---- F: slot reduce (waves 0-3) ----
    if (wv < 4) {
      int idx = (wv << 6) | lane;
      float s0 = 0, s1 = 0, s2 = 0, s3 = 0;
      if (idx < NBLK) {
        const float* sd = (const float*)p.slt + (((size_t)par*NBLK + idx) << 4);
        const uint32_t* st = (const uint32_t*)sd + 15;
        uint32_t spins = 0;
        while (!dead && __hip_atomic_load(st, __ATOMIC_RELAXED,
                                          __HIP_MEMORY_SCOPE_AGENT) != want) {
          __builtin_amdgcn_s_sleep(1);
          if (++spins > SPINCAP) dead = true;
        }
        s0 = __hip_atomic_load(sd+0, __ATOMIC_RELAXED, __HIP_MEMORY_SCOPE_AGENT);
        s1 = __hip_atomic_load(sd+1, __ATOMIC_RELAXED, __HIP_MEMORY_SCOPE_AGENT);
        s2 = __hip_atomic_load(sd+2, __ATOMIC_RELAXED, __HIP_MEMORY_SCOPE_AGENT);
        s3 = __hip_atomic_load(sd+3, __ATOMIC_RELAXED, __HIP_MEMORY_SCOPE_AGENT);
      }
#pragma unroll
      for (int m = 32; m >= 1; m >>= 1) {
        s0 += __shfl_xor(s0, m, 64); s1 += __shfl_xor(s1, m, 64);
        s2 += __shfl_xor(s2, m, 64); s3 += __shfl_xor(s3, m, 64);
      }
      if (lane == 0) {
        SLP[wv*4+0] = s0; SLP[wv*4+1] = s1; SLP[wv*4+2] = s2; SLP[wv*4+3] = s3;
      }
    }
    __syncthreads();

    // ---- G: posterior + next-step chain ----
    if (tid < 4) {
      float c = SLP[tid] + SLP[4 + tid] + SLP[8 + tid] + SLP[12 + tid];
      float xp = XPRI[tid] + (c + B4[tid]) * 1e-4f;
      XPO[tid] = xp;
      if (bid == 0) p.out[(size_t)tid*TSEQ + t] = xp;
    }
    __syncthreads();
    if (t + 1 < TSEQ) {
      if (tid < 4) {
        float xo = XPO[tid];
        DXS[tid] = xo - XPRI[tid];
        float s = 0;
#pragma unroll
        for (int j = 0; j < 4; ++j) s += AS[tid*4 + j] * XPO[j];
        XPRI[tid] = s;
      }
      __syncthreads();
      small_chain(t + 1);                        // ends with syncthreads
    }
  }
}

// f32 -> fp8 e4m3 (x128), 4 elements per thread (W_ih full).
extern "C" __global__ void knet_cvt_fp8(const float* __restrict__ src,
                                        uint8_t* __restrict__ dst, long n4) {
  long stride = (long)gridDim.x * blockDim.x;
  for (long i = (long)blockIdx.x*blockDim.x + threadIdx.x; i < n4; i += stride) {
    float4 v = ((const float4*)src)[i];
    float a0 = fminf(fmaxf(v.x * 128.f, -448.f), 448.f);
    float a1 = fminf(fmaxf(v.y * 128.f, -448.f), 448.f);
    float a2 = fminf(fmaxf(v.z * 128.f, -448.f), 448.f);
    float a3 = fminf(fmaxf(v.w * 128.f, -448.f), 448.f);
    int pk = __builtin_amdgcn_cvt_pk_fp8_f32(a0, a1, 0, false);
    pk = __builtin_amdgcn_cvt_pk_fp8_f32(a2, a3, pk, true);
    ((uint32_t*)dst)[i] = (uint32_t)pk;
  }
}

// Build W1ext fp8: row r = [W1[r,0:52], b1[r], 0 x11] * 128, 64 B/row.
extern "C" __global__ void knet_build_w1e(const float* __restrict__ W1,
                                          const float* __restrict__ b1,
                                          uint8_t* __restrict__ dst) {
  int r = blockIdx.x * blockDim.x + threadIdx.x;
  if (r >= KIH) return;
  float v[64];
#pragma unroll 13
  for (int q = 0; q < 13; ++q) {
    float4 w = ((const float4*)(W1 + (size_t)r*52))[q];
    v[q*4+0] = w.x; v[q*4+1] = w.y; v[q*4+2] = w.z; v[q*4+3] = w.w;
  }
  v[52] = b1[r];
  for (int i = 53; i < 64; ++i) v[i] = 0.f;
  uint32_t out[16];
#pragma unroll 16
  for (int d = 0; d < 16; ++d) {
    float a0 = fminf(fmaxf(v[d*4+0] * 128.f, -448.f), 448.f);
    float a1 = fminf(fmaxf(v[d*4+1] * 128.f, -448.f), 448.f);
    float a2 = fminf(fmaxf(v[d*4+2] * 128.f, -448.f), 448.f);
    float a3 = fminf(fmaxf(v[d*4+3] * 128.f, -448.f), 448.f);
    int pk = __builtin_amdgcn_cvt_pk_fp8_f32(a0, a1, 0, false);
    pk = __builtin_amdgcn_cvt_pk_fp8_f32(a2, a3, pk, true);
    out[d] = (uint32_t)pk;
  }
  uint4* dp = (uint4*)(dst + (size_t)r*64);
#pragma unroll 4
  for (int q = 0; q < 4; ++q)
    dp[q] = make_uint4(out[q*4+0], out[q*4+1], out[q*4+2], out[q*4+3]);
}

extern "C" void kernel_launch(void* const* d_in, const int* in_sizes, int n_in,
                              void* d_out, int out_size, void* d_ws, size_t ws_size,
                              hipStream_t stream)
{
  if (ws_size < (size_t)WS_END) return;   // 29.3 MB (proven available)
  uint8_t* ws = (uint8_t*)d_ws;

  knet_cvt_fp8<<<2048, 256, 0, stream>>>((const float*)d_in[7], ws + WS_WIH8,
                                         (long)G3*KIH/4);
  knet_build_w1e<<<(KIH + 255)/256, 256, 0, stream>>>(
      (const float*)d_in[5], (const float*)d_in[6], ws + WS_W1E);
  // no memset: packet tags are exact-match (t+1), 0xAA poison never matches

  int resident = 1;
  Offs o = mkoffs(resident);
  hipError_t e = hipFuncSetAttribute((const void*)knet_main,
                                     hipFuncAttributeMaxDynamicSharedMemorySize,
                                     o.total);
  if (e != hipSuccess) {
    resident = 0; o = mkoffs(resident);
    (void)hipFuncSetAttribute((const void*)knet_main,
                              hipFuncAttributeMaxDynamicSharedMemorySize, o.total);
  }

  Params p;
  p.A   = (const float*)d_in[0];  p.C   = (const float*)d_in[1];
  p.x0  = (const float*)d_in[2];  p.h0  = (const float*)d_in[3];
  p.y   = (const float*)d_in[4];
  p.W1  = (const float*)d_in[5];  p.b1  = (const float*)d_in[6];
  p.Wih = (const float*)d_in[7];  p.Whh = (const float*)d_in[8];
  p.bih = (const float*)d_in[9];  p.bhh = (const float*)d_in[10];
  p.W2  = (const float*)d_in[11]; p.b2  = (const float*)d_in[12];
  p.W3  = (const float*)d_in[13]; p.b3  = (const float*)d_in[14];
  p.wih8 = ws + WS_WIH8;
  p.w1e  = ws + WS_W1E;
  p.hbp  = ws + WS_HBP;
  p.slt  = ws + WS_SLT;
  p.out  = (float*)d_out;
  p.resident = resident;

  knet_main<<<NBLK, NTHR, (size_t)o.total, stream>>>(p);
}

// Round 6
// 8877.345 us; speedup vs baseline: 2.0721x; 1.2335x over previous
//
// KalmanNetNN persistent kernel, MI355X (gfx950).
// R6: NO cache-maintenance ops in the loop. Packet publishes use
//   relaxed agent atomic data stores + s_waitcnt vmcnt(0) + RELAXED tag
//   store (release-without-wbl2; legal because packet data is write-through
//   atomic, never dirty in L2). Consumers: relaxed tag polls (s_sleep(4))
//   + relaxed data loads. Grid shrunk to 232 blocks (all gates; l2 rows
//   72x4+160x3). Everything else = R5: W_ih on-chip (LDS+VGPR), W_hh/W2
//   LDS fp8, l1 redundant per block from fp8 W1ext (L2-resident).
// Predicted: ~9-11 us/step -> 4.5-6 ms.

#include <hip/hip_runtime.h>
#include <stdint.h>
#include <stddef.h>

typedef float v2f __attribute__((ext_vector_type(2)));

#define HID   2320
#define G3    6960
#define KIH   4160
#define KHH   2320
#define NBLK  232
#define NTHR  512
#define UPB   10
#define TSEQ  512
#define KRES  1600
#define INVWS (1.0f/128.0f)
#define SPINCAP (1u<<17)

// ---------------- workspace layout (bytes) ----------------
#define WS_WIH8 0L
#define WS_W1E  28953600L      // 6960*4160 fp8
#define WS_HBP  29219840L      // 4160*64 fp8 W1ext (52 w + b1 + pad)
#define WS_SLT  29249536L      // 2 x 232 x 64B h packets
#define WS_END  29280256L      // 2 x 240 x 64B slot packets

struct Offs {
  int l1s, hs, wih, whh, w2s, w3s, cs, as_, b3s, bih, bhh, b2s, gis, ghs,
      ts, inn, kn, dxs, xpri, xpo, b4, nrm, slp;
  int total;
};

__host__ __device__ inline Offs mkoffs(int res) {
  Offs o; int p = 0;
#define ALLOC(name, bytes) { p = (p + 15) & ~15; o.name = p; p += (bytes); }
  ALLOC(l1s, KIH*4) ALLOC(hs, HID*4)
  ALLOC(wih, res ? 30*KRES : 16) ALLOC(whh, res ? 30*KHH : 16)
  ALLOC(w2s, res ? 4*HID : 16)
  ALLOC(w3s, 16*48*4) ALLOC(cs, 240*4) ALLOC(as_, 64) ALLOC(b3s, 192*4)
  ALLOC(bih, 120) ALLOC(bhh, 120) ALLOC(b2s, 16)
  ALLOC(gis, 120) ALLOC(ghs, 120)
  ALLOC(ts, 64) ALLOC(inn, 192) ALLOC(kn, 256)
  ALLOC(dxs, 16) ALLOC(xpri, 16) ALLOC(xpo, 16) ALLOC(b4, 16) ALLOC(nrm, 16)
  ALLOC(slp, 64)
#undef ALLOC
  o.total = (p + 63) & ~63;
  return o;
}

struct Params {
  const float *A, *C, *x0, *h0, *y, *W1, *b1, *Wih, *Whh, *bih, *bhh, *W2, *b2, *W3, *b3;
  const uint8_t *wih8, *w1e;
  uint8_t *hbp, *slt;
  float *out;
  int resident;
};

__device__ __forceinline__ uint8_t f2fp8(float v) {
  v = fminf(fmaxf(v * 128.f, -448.f), 448.f);
  int pk = __builtin_amdgcn_cvt_pk_fp8_f32(v, v, 0, false);
  return (uint8_t)(pk & 0xff);
}

// fp8 row-dot, LDS weights, <=4 rows/wave, lanes split K.
__device__ __forceinline__ void dot8_lds(
    const float* __restrict__ acts, const uint8_t* __restrict__ w, int stride,
    int K, const int* lrows, int nr, int lane, float acc[4])
{
  int kb = 0;
  for (; kb + 256 <= K; kb += 256) {
    const float4 a = ((const float4*)(acts + kb))[lane];
#pragma unroll
    for (int j = 0; j < 4; ++j) if (j < nr) {
      uint32_t wb = *(const uint32_t*)(w + (size_t)lrows[j]*stride + kb + (lane<<2));
      v2f lo = __builtin_amdgcn_cvt_pk_f32_fp8((int)wb, false);
      v2f hi = __builtin_amdgcn_cvt_pk_f32_fp8((int)wb, true);
      acc[j] = fmaf(lo.x, a.x, acc[j]); acc[j] = fmaf(lo.y, a.y, acc[j]);
      acc[j] = fmaf(hi.x, a.z, acc[j]); acc[j] = fmaf(hi.y, a.w, acc[j]);
    }
  }
  int rem = K - kb;
  if ((lane << 2) < rem) {
    const float4 a = ((const float4*)(acts + kb))[lane];
#pragma unroll
    for (int j = 0; j < 4; ++j) if (j < nr) {
      uint32_t wb = *(const uint32_t*)(w + (size_t)lrows[j]*stride + kb + (lane<<2));
      v2f lo = __builtin_amdgcn_cvt_pk_f32_fp8((int)wb, false);
      v2f hi = __builtin_amdgcn_cvt_pk_f32_fp8((int)wb, true);
      acc[j] = fmaf(lo.x, a.x, acc[j]); acc[j] = fmaf(lo.y, a.y, acc[j]);
      acc[j] = fmaf(hi.x, a.z, acc[j]); acc[j] = fmaf(hi.y, a.w, acc[j]);
    }
  }
}

// fp8 row-dot, global weights, cols [K0,K).
__device__ __forceinline__ void dot8_glb(
    const float* __restrict__ acts, const uint8_t* __restrict__ gw, int gstride,
    int K0, int K, const int* grows, int nr, int lane, float acc[4])
{
  int kb = K0;
  for (; kb + 512 <= K; kb += 512) {
    const float4 a0 = ((const float4*)(acts + kb))[lane*2];
    const float4 a1 = ((const float4*)(acts + kb))[lane*2 + 1];
#pragma unroll
    for (int j = 0; j < 4; ++j) if (j < nr) {
      uint2 wb = *(const uint2*)(gw + (size_t)grows[j]*gstride + kb + (lane<<3));
      v2f l0 = __builtin_amdgcn_cvt_pk_f32_fp8((int)wb.x, false);
      v2f h0 = __builtin_amdgcn_cvt_pk_f32_fp8((int)wb.x, true);
      v2f l1 = __builtin_amdgcn_cvt_pk_f32_fp8((int)wb.y, false);
      v2f h1 = __builtin_amdgcn_cvt_pk_f32_fp8((int)wb.y, true);
      acc[j] = fmaf(l0.x, a0.x, acc[j]); acc[j] = fmaf(l0.y, a0.y, acc[j]);
      acc[j] = fmaf(h0.x, a0.z, acc[j]); acc[j] = fmaf(h0.y, a0.w, acc[j]);
      acc[j] = fmaf(l1.x, a1.x, acc[j]); acc[j] = fmaf(l1.y, a1.y, acc[j]);
      acc[j] = fmaf(h1.x, a1.z, acc[j]); acc[j] = fmaf(h1.y, a1.w, acc[j]);
    }
  }
  for (int e = kb + lane; e < K; e += 64) {
    float a = acts[e];
#pragma unroll
    for (int j = 0; j < 4; ++j) if (j < nr) {
      v2f lo = __builtin_amdgcn_cvt_pk_f32_fp8(
          (int)(uint32_t)gw[(size_t)grows[j]*gstride + e], false);
      acc[j] = fmaf(lo.x, a, acc[j]);
    }
  }
}

// f32 row-dot, global weights (fallback ghh).
__device__ __forceinline__ void dotf_glb(
    const float* __restrict__ acts, const float* __restrict__ gw, int gstride,
    int K, const int* grows, int nr, int lane, float acc[4])
{
  for (int k = lane; k < K; k += 64) {
    float a = acts[k];
#pragma unroll
    for (int j = 0; j < 4; ++j) if (j < nr)
      acc[j] = fmaf(gw[(size_t)grows[j]*gstride + k], a, acc[j]);
  }
}

extern "C" __global__ void __launch_bounds__(NTHR, 2) knet_main(Params p)
{
  extern __shared__ char smem[];
  const Offs o = mkoffs(p.resident);
  float*   L1S  = (float*)(smem + o.l1s);
  float*   HS   = (float*)(smem + o.hs);
  uint8_t* WIHR = (uint8_t*)(smem + o.wih);
  uint8_t* WHHR = (uint8_t*)(smem + o.whh);
  uint8_t* W2S  = (uint8_t*)(smem + o.w2s);
  float*   W3S  = (float*)(smem + o.w3s);
  float*   CS   = (float*)(smem + o.cs);
  float*   AS   = (float*)(smem + o.as_);
  float*   B3S  = (float*)(smem + o.b3s);
  float*   BIH  = (float*)(smem + o.bih);
  float*   BHH  = (float*)(smem + o.bhh);
  float*   B2S  = (float*)(smem + o.b2s);
  float*   GIS  = (float*)(smem + o.gis);
  float*   GHS  = (float*)(smem + o.ghs);
  float*   TS   = (float*)(smem + o.ts);
  float*   INNS = (float*)(smem + o.inn);
  float*   KN   = (float*)(smem + o.kn);
  float*   DXS  = (float*)(smem + o.dxs);
  float*   XPRI = (float*)(smem + o.xpri);
  float*   XPO  = (float*)(smem + o.xpo);
  float*   B4   = (float*)(smem + o.b4);
  float*   NRM  = (float*)(smem + o.nrm);
  float*   SLP  = (float*)(smem + o.slp);

  const int tid  = (int)threadIdx.x;
  const int bid  = (int)blockIdx.x;
  const int lane = tid & 63;
  const int wv   = tid >> 6;
  const int rows2 = (bid < 72) ? 4 : 3;               // l2 rows: 72*4+160*3=768
  const int r2s   = (bid < 72) ? bid*4 : 288 + (bid-72)*3;
  bool dead = false;

  int lrows[4] = {0,0,0,0}, grows[4] = {0,0,0,0};
  int nr = 0;
#pragma unroll
  for (int j = 0; j < 4; ++j) {
    int row = wv + 8*j;
    if (row < 30) { int u = row/3, g = row - 3*u;
      lrows[nr] = row; grows[nr] = g*HID + bid*UPB + u; ++nr; }
  }

  // ---------------- one-time staging ----------------
  for (int i = tid; i < rows2*192; i += NTHR) { int rl = i/192, rem = i - rl*192;
    W3S[i] = p.W3[(size_t)rem*768 + (r2s + rl)]; }
  for (int i = tid; i < 240; i += NTHR) CS[i] = p.C[i];
  if (tid < 16) AS[tid] = p.A[tid];
  for (int i = tid; i < 192; i += NTHR) B3S[i] = p.b3[i];
  if (tid < rows2) B2S[tid] = p.b2[r2s + tid];
  if (tid < 30) {
    int u = tid/3, g = tid - 3*u, ug = bid*UPB + u;
    BIH[tid] = p.bih[g*HID + ug];
    BHH[tid] = p.bhh[g*HID + ug];
  }
  for (int i = tid; i < HID; i += NTHR) HS[i] = p.h0[i];
  if (p.resident) {
    const int kd = KRES >> 2;                   // W_ih resident cols from fp8 ws
    uint32_t* W32 = (uint32_t*)WIHR;
    for (int i = tid; i < 30*kd; i += NTHR) {
      int row = i / kd, c = i - row*kd;
      int u = row/3, g = row - 3*u, gr = g*HID + bid*UPB + u;
      W32[i] = ((const uint32_t*)p.wih8)[(size_t)gr*(KIH/4) + c];
    }
    for (int i = tid; i < 30*KHH; i += NTHR) {  // W_hh rows f32->fp8
      int row = i / KHH, k = i - row*KHH;
      int u = row/3, g = row - 3*u, gr = g*HID + bid*UPB + u;
      WHHR[i] = f2fp8(p.Whh[(size_t)gr*KHH + k]);
    }
    for (int i = tid; i < rows2*HID; i += NTHR) { // W2 slice f32->fp8
      int rl = i / HID, k = i - rl*HID;
      W2S[i] = f2fp8(p.W2[(size_t)(r2s+rl)*HID + k]);
    }
  }
  // streamed W_ih cols [KRES,4160) hoisted into VGPRs (constant across steps)
  uint2 pf[4][5];
#pragma unroll
  for (int j = 0; j < 4; ++j)
#pragma unroll
    for (int i = 0; i < 5; ++i) pf[j][i] = make_uint2(0u, 0u);
#pragma unroll
  for (int j = 0; j < 4; ++j) if (j < nr)
#pragma unroll
    for (int i = 0; i < 5; ++i)
      pf[j][i] = *(const uint2*)(p.wih8 + (size_t)grows[j]*KIH + KRES + i*512 + (lane<<3));
  __syncthreads();

  // small chain producing step-`ycol` inputs: INNS, KN, B4, TS, full l1.
  auto small_chain = [&](int ycol) {
    if (tid < 48) {
      float s = CS[tid*5 + 4];
#pragma unroll
      for (int k = 0; k < 4; ++k) s += CS[tid*5 + k] * XPRI[k];
      INNS[tid] = p.y[(size_t)tid*TSEQ + ycol] - s;
    }
    __syncthreads();
    if (tid == 0) {
      float s = 0;
      for (int j = 0; j < 48; ++j) s += INNS[j]*INNS[j];
      NRM[0] = fmaxf(sqrtf(s), 1e-12f);
      float s2 = 0;
      for (int j = 0; j < 4; ++j) s2 += DXS[j]*DXS[j];
      NRM[1] = fmaxf(sqrtf(s2), 1e-12f);
    }
    __syncthreads();
    if (tid < 48) KN[tid] = INNS[tid] / NRM[0];
    else if (tid < 52) KN[tid] = DXS[tid-48] / NRM[1];
    else if (tid == 52) KN[tid] = 1.0f;
    else if (tid < 64) KN[tid] = 0.0f;
    else if (tid < 68) {
      int i = tid - 64; float s = 0;
      for (int j = 0; j < 48; ++j) s += B3S[i*48 + j] * INNS[j];
      B4[i] = s;
    }
    if (tid >= 128 && tid < 128 + rows2*4) {
      int idx = tid - 128, rl = idx >> 2, i = idx & 3;
      float s = 0;
      for (int j = 0; j < 48; ++j) s += W3S[rl*192 + i*48 + j] * INNS[j];
      TS[i*4 + rl] = s;
    }
    __syncthreads();
    {                                            // redundant full l1
      float4 kn[16];
#pragma unroll
      for (int c = 0; c < 16; ++c) kn[c] = ((const float4*)KN)[c];
      for (int r = tid; r < KIH; r += NTHR) {
        const uint4* wp = (const uint4*)(p.w1e + (size_t)r*64);
        float acc = 0.f;
#pragma unroll
        for (int q = 0; q < 4; ++q) {
          uint4 w = wp[q];
          v2f l0 = __builtin_amdgcn_cvt_pk_f32_fp8((int)w.x, false);
          v2f h0 = __builtin_amdgcn_cvt_pk_f32_fp8((int)w.x, true);
          v2f l1 = __builtin_amdgcn_cvt_pk_f32_fp8((int)w.y, false);
          v2f h1 = __builtin_amdgcn_cvt_pk_f32_fp8((int)w.y, true);
          v2f l2 = __builtin_amdgcn_cvt_pk_f32_fp8((int)w.z, false);
          v2f h2 = __builtin_amdgcn_cvt_pk_f32_fp8((int)w.z, true);
          v2f l3 = __builtin_amdgcn_cvt_pk_f32_fp8((int)w.w, false);
          v2f h3 = __builtin_amdgcn_cvt_pk_f32_fp8((int)w.w, true);
          float4 a0 = kn[q*4+0], a1 = kn[q*4+1], a2 = kn[q*4+2], a3 = kn[q*4+3];
          acc = fmaf(l0.x,a0.x,acc); acc = fmaf(l0.y,a0.y,acc);
          acc = fmaf(h0.x,a0.z,acc); acc = fmaf(h0.y,a0.w,acc);
          acc = fmaf(l1.x,a1.x,acc); acc = fmaf(l1.y,a1.y,acc);
          acc = fmaf(h1.x,a1.z,acc); acc = fmaf(h1.y,a1.w,acc);
          acc = fmaf(l2.x,a2.x,acc); acc = fmaf(l2.y,a2.y,acc);
          acc = fmaf(h2.x,a2.z,acc); acc = fmaf(h2.y,a2.w,acc);
          acc = fmaf(l3.x,a3.x,acc); acc = fmaf(l3.y,a3.y,acc);
          acc = fmaf(h3.x,a3.z,acc); acc = fmaf(h3.y,a3.w,acc);
        }
        L1S[r] = fmaxf(acc * INVWS, 0.f);
      }
    }
    __syncthreads();
  };

  auto ghh = [&]() {                             // W_hh @ HS -> GHS
    float acc[4] = {0,0,0,0};
    if (p.resident) dot8_lds(HS, WHHR, KHH, KHH, lrows, nr, lane, acc);
    else            dotf_glb(HS, p.Whh, KHH, KHH, grows, nr, lane, acc);
#pragma unroll
    for (int m = 32; m >= 1; m >>= 1)
#pragma unroll
      for (int j = 0; j < 4; ++j) acc[j] += __shfl_xor(acc[j], m, 64);
    if (lane == 0)
#pragma unroll
      for (int j = 0; j < 4; ++j) if (j < nr) GHS[lrows[j]] = acc[j];
  };

  // ---------------- pre-loop ----------------
  if (tid < 4) { XPO[tid] = p.x0[tid]; DXS[tid] = 0.f; }
  __syncthreads();
  if (tid < 4) {
    float s = 0;
#pragma unroll
    for (int j = 0; j < 4; ++j) s += AS[tid*4 + j] * XPO[j];
    XPRI[tid] = s;
  }
  __syncthreads();
  small_chain(0);
  ghh();
  __syncthreads();

  // ---------------- main sequence (no barriers, no cache-maintenance) ----
  for (int t = 0; t < TSEQ; ++t) {
    const int par = t & 1;
    const uint32_t want = (uint32_t)(t + 1);

    // ---- A: gate-dot gi = W_ih @ l1(t) ----
    {
      float acc[4] = {0,0,0,0};
      if (p.resident) dot8_lds(L1S, WIHR, KRES, KRES, lrows, nr, lane, acc);
      else            dot8_glb(L1S, p.wih8, KIH, 0, KRES, grows, nr, lane, acc);
#pragma unroll
      for (int i = 0; i < 5; ++i) {              // VGPR-held streamed cols
        const float4 a0 = ((const float4*)(L1S + KRES + i*512))[lane*2];
        const float4 a1 = ((const float4*)(L1S + KRES + i*512))[lane*2 + 1];
#pragma unroll
        for (int j = 0; j < 4; ++j) if (j < nr) {
          uint2 w = pf[j][i];
          v2f l0 = __builtin_amdgcn_cvt_pk_f32_fp8((int)w.x, false);
          v2f h0 = __builtin_amdgcn_cvt_pk_f32_fp8((int)w.x, true);
          v2f l1v = __builtin_amdgcn_cvt_pk_f32_fp8((int)w.y, false);
          v2f h1 = __builtin_amdgcn_cvt_pk_f32_fp8((int)w.y, true);
          acc[j] = fmaf(l0.x, a0.x, acc[j]); acc[j] = fmaf(l0.y, a0.y, acc[j]);
          acc[j] = fmaf(h0.x, a0.z, acc[j]); acc[j] = fmaf(h0.y, a0.w, acc[j]);
          acc[j] = fmaf(l1v.x, a1.x, acc[j]); acc[j] = fmaf(l1v.y, a1.y, acc[j]);
          acc[j] = fmaf(h1.x, a1.z, acc[j]); acc[j] = fmaf(h1.y, a1.w, acc[j]);
        }
      }
#pragma unroll
      for (int m = 32; m >= 1; m >>= 1)
#pragma unroll
        for (int j = 0; j < 4; ++j) acc[j] += __shfl_xor(acc[j], m, 64);
      if (lane == 0)
#pragma unroll
        for (int j = 0; j < 4; ++j) if (j < nr) GIS[lrows[j]] = acc[j];
    }
    __syncthreads();

    // ---- B: h(t) + packet publish (wave 0, lanes 0..9; vmcnt-ordered) ----
    if (tid < UPB) {
      int ug = bid*UPB + tid, r0 = tid*3;
      float gi0 = GIS[r0+0]*INVWS + BIH[r0+0], gh0 = GHS[r0+0]*INVWS + BHH[r0+0];
      float gi1 = GIS[r0+1]*INVWS + BIH[r0+1], gh1 = GHS[r0+1]*INVWS + BHH[r0+1];
      float gi2 = GIS[r0+2]*INVWS + BIH[r0+2], gh2 = GHS[r0+2]*INVWS + BHH[r0+2];
      float rg = 1.f/(1.f + expf(-(gi0+gh0)));
      float zg = 1.f/(1.f + expf(-(gi1+gh1)));
      float ng = tanhf(gi2 + rg*gh2);
      float hnew = (1.f - zg)*ng + zg*HS[ug];
      float* hd = (float*)p.hbp + (((size_t)par*NBLK + bid) << 4);
      __hip_atomic_store(hd + tid, hnew, __ATOMIC_RELAXED, __HIP_MEMORY_SCOPE_AGENT);
    }
    asm volatile("s_waitcnt vmcnt(0)" ::: "memory");   // data < tag, no wbl2
    if (tid == 0) {
      uint32_t* ht = (uint32_t*)p.hbp + (((size_t)par*NBLK + bid) << 4) + 15;
      __hip_atomic_store(ht, want, __ATOMIC_RELAXED, __HIP_MEMORY_SCOPE_AGENT);
    }
    __syncthreads();   // protect HS (old h) until B done before C overwrites

    // ---- C: h broadcast consume -> HS ----
    if (wv < 4) {
      int idx = (wv << 6) | lane;
      if (idx < NBLK) {
        const float* hd = (const float*)p.hbp + (((size_t)par*NBLK + idx) << 4);
        const uint32_t* ht = (const uint32_t*)hd + 15;
        uint32_t spins = 0;
        while (!dead && __hip_atomic_load(ht, __ATOMIC_RELAXED,
                                          __HIP_MEMORY_SCOPE_AGENT) != want) {
          __builtin_amdgcn_s_sleep(4);
          if (++spins > SPINCAP) dead = true;
        }
        float v[10];
#pragma unroll
        for (int k = 0; k < 10; ++k)
          v[k] = __hip_atomic_load(hd + k, __ATOMIC_RELAXED, __HIP_MEMORY_SCOPE_AGENT);
#pragma unroll
        for (int k = 0; k < 10; ++k) HS[idx*10 + k] = v[k];
      }
    }
    __syncthreads();

    // ---- D: l2 (wave 0 only) + slot publish (vmcnt-ordered) ----
    if (wv == 0) {
      float a2[4] = {0,0,0,0};
      if (p.resident) {
        int kb = 0;
        for (; kb + 256 <= HID; kb += 256) {
          const float4 a = ((const float4*)(HS + kb))[lane];
#pragma unroll
          for (int rl = 0; rl < 4; ++rl) if (rl < rows2) {
            uint32_t wb = *(const uint32_t*)(W2S + rl*HID + kb + (lane<<2));
            v2f lo = __builtin_amdgcn_cvt_pk_f32_fp8((int)wb, false);
            v2f hi = __builtin_amdgcn_cvt_pk_f32_fp8((int)wb, true);
            a2[rl] = fmaf(lo.x, a.x, a2[rl]); a2[rl] = fmaf(lo.y, a.y, a2[rl]);
            a2[rl] = fmaf(hi.x, a.z, a2[rl]); a2[rl] = fmaf(hi.y, a.w, a2[rl]);
          }
        }
        if ((lane << 2) < HID - kb) {
          const float4 a = ((const float4*)(HS + kb))[lane];
#pragma unroll
          for (int rl = 0; rl < 4; ++rl) if (rl < rows2) {
            uint32_t wb = *(const uint32_t*)(W2S + rl*HID + kb + (lane<<2));
            v2f lo = __builtin_amdgcn_cvt_pk_f32_fp8((int)wb, false);
            v2f hi = __builtin_amdgcn_cvt_pk_f32_fp8((int)wb, true);
            a2[rl] = fmaf(lo.x, a.x, a2[rl]); a2[rl] = fmaf(lo.y, a.y, a2[rl]);
            a2[rl] = fmaf(hi.x, a.z, a2[rl]); a2[rl] = fmaf(hi.y, a.w, a2[rl]);
          }
        }
#pragma unroll
        for (int rl = 0; rl < 4; ++rl) a2[rl] *= INVWS;
      } else {
        for (int k = lane; k < HID; k += 64) {
          float a = HS[k];
#pragma unroll
          for (int rl = 0; rl < 4; ++rl) if (rl < rows2)
            a2[rl] = fmaf(p.W2[(size_t)(r2s+rl)*HID + k], a, a2[rl]);
        }
      }
#pragma unroll
      for (int m = 32; m >= 1; m >>= 1)
#pragma unroll
        for (int rl = 0; rl < 4; ++rl) a2[rl] += __shfl_xor(a2[rl], m, 64);
      if (lane == 0) {
        float l2v[4];
#pragma unroll
        for (int rl = 0; rl < 4; ++rl)
          l2v[rl] = (rl < rows2) ? fmaxf(a2[rl] + B2S[rl], 0.f) : 0.f;
        float* sd = (float*)p.slt + (((size_t)par*NBLK + bid) << 4);
#pragma unroll
        for (int i = 0; i < 4; ++i) {
          float cp = l2v[0]*TS[i*4+0] + l2v[1]*TS[i*4+1]
                   + l2v[2]*TS[i*4+2] + l2v[3]*TS[i*4+3];
          __hip_atomic_store(sd + i, cp, __ATOMIC_RELAXED, __HIP_MEMORY_SCOPE_AGENT);
        }
      }
      asm volatile("s_waitcnt vmcnt(0)" ::: "memory");  // data < tag, no wbl2
      if (lane == 0) {
        float* sd = (float*)p.slt + (((size_t)par*NBLK + bid) << 4);
        __hip_atomic_store((uint32_t*)sd + 15, want, __ATOMIC_RELAXED,
                           __HIP_MEMORY_SCOPE_AGENT);
      }
    }

    // ---- E: ghh(t) for step t+1 (off critical path) ----
    ghh();

    // ---- F: slot reduce (waves 0-3) ----
    if (wv < 4) {
      int idx = (wv << 6) | lane;
      float s0 = 0, s1 = 0, s2 = 0, s3 = 0;
      if (idx < NBLK) {
        const float* sd = (const float*)p.slt + (((size_t)par*NBLK + idx) << 4);
        const uint32_t* st = (const uint32_t*)sd + 15;
        uint32_t spins = 0;
        while (!dead && __hip_atomic_load(st, __ATOMIC_RELAXED,
                                          __HIP_MEMORY_SCOPE_AGENT) != want) {
          __builtin_amdgcn_s_sleep(4);
          if (++spins > SPINCAP) dead = true;
        }
        s0 = __hip_atomic_load(sd+0, __ATOMIC_RELAXED, __HIP_MEMORY_SCOPE_AGENT);
        s1 = __hip_atomic_load(sd+1, __ATOMIC_RELAXED, __HIP_MEMORY_SCOPE_AGENT);
        s2 = __hip_atomic_load(sd+2, __ATOMIC_RELAXED, __HIP_MEMORY_SCOPE_AGENT);
        s3 = __hip_atomic_load(sd+3, __ATOMIC_RELAXED, __HIP_MEMORY_SCOPE_AGENT);
      }
#pragma unroll
      for (int m = 32; m >= 1; m >>= 1) {
        s0 += __shfl_xor(s0, m, 64); s1 += __shfl_xor(s1, m, 64);
        s2 += __shfl_xor(s2, m, 64); s3 += __shfl_xor(s3, m, 64);
      }
      if (lane == 0) {
        SLP[wv*4+0] = s0; SLP[wv*4+1] = s1; SLP[wv*4+2] = s2; SLP[wv*4+3] = s3;
      }
    }
    __syncthreads();

    // ---- G: posterior + next-step chain ----
    if (tid < 4) {
      float c = SLP[tid] + SLP[4 + tid] + SLP[8 + tid] + SLP[12 + tid];
      float xp = XPRI[tid] + (c + B4[tid]) * 1e-4f;
      XPO[tid] = xp;
      if (bid == 0) p.out[(size_t)tid*TSEQ + t] = xp;
    }
    __syncthreads();
    if (t + 1 < TSEQ) {
      if (tid < 4) {
        float xo = XPO[tid];
        DXS[tid] = xo - XPRI[tid];
        float s = 0;
#pragma unroll
        for (int j = 0; j < 4; ++j) s += AS[tid*4 + j] * XPO[j];
        XPRI[tid] = s;
      }
      __syncthreads();
      small_chain(t + 1);                        // ends with syncthreads
    }
  }
}

// f32 -> fp8 e4m3 (x128), 4 elements per thread (W_ih full).
extern "C" __global__ void knet_cvt_fp8(const float* __restrict__ src,
                                        uint8_t* __restrict__ dst, long n4) {
  long stride = (long)gridDim.x * blockDim.x;
  for (long i = (long)blockIdx.x*blockDim.x + threadIdx.x; i < n4; i += stride) {
    float4 v = ((const float4*)src)[i];
    float a0 = fminf(fmaxf(v.x * 128.f, -448.f), 448.f);
    float a1 = fminf(fmaxf(v.y * 128.f, -448.f), 448.f);
    float a2 = fminf(fmaxf(v.z * 128.f, -448.f), 448.f);
    float a3 = fminf(fmaxf(v.w * 128.f, -448.f), 448.f);
    int pk = __builtin_amdgcn_cvt_pk_fp8_f32(a0, a1, 0, false);
    pk = __builtin_amdgcn_cvt_pk_fp8_f32(a2, a3, pk, true);
    ((uint32_t*)dst)[i] = (uint32_t)pk;
  }
}

// Build W1ext fp8: row r = [W1[r,0:52], b1[r], 0 x11] * 128, 64 B/row.
extern "C" __global__ void knet_build_w1e(const float* __restrict__ W1,
                                          const float* __restrict__ b1,
                                          uint8_t* __restrict__ dst) {
  int r = blockIdx.x * blockDim.x + threadIdx.x;
  if (r >= KIH) return;
  float v[64];
#pragma unroll 13
  for (int q = 0; q < 13; ++q) {
    float4 w = ((const float4*)(W1 + (size_t)r*52))[q];
    v[q*4+0] = w.x; v[q*4+1] = w.y; v[q*4+2] = w.z; v[q*4+3] = w.w;
  }
  v[52] = b1[r];
  for (int i = 53; i < 64; ++i) v[i] = 0.f;
  uint32_t out[16];
#pragma unroll 16
  for (int d = 0; d < 16; ++d) {
    float a0 = fminf(fmaxf(v[d*4+0] * 128.f, -448.f), 448.f);
    float a1 = fminf(fmaxf(v[d*4+1] * 128.f, -448.f), 448.f);
    float a2 = fminf(fmaxf(v[d*4+2] * 128.f, -448.f), 448.f);
    float a3 = fminf(fmaxf(v[d*4+3] * 128.f, -448.f), 448.f);
    int pk = __builtin_amdgcn_cvt_pk_fp8_f32(a0, a1, 0, false);
    pk = __builtin_amdgcn_cvt_pk_fp8_f32(a2, a3, pk, true);
    out[d] = (uint32_t)pk;
  }
  uint4* dp = (uint4*)(dst + (size_t)r*64);
#pragma unroll 4
  for (int q = 0; q < 4; ++q)
    dp[q] = make_uint4(out[q*4+0], out[q*4+1], out[q*4+2], out[q*4+3]);
}

extern "C" void kernel_launch(void* const* d_in, const int* in_sizes, int n_in,
                              void* d_out, int out_size, void* d_ws, size_t ws_size,
                              hipStream_t stream)
{
  if (ws_size < (size_t)WS_END) return;   // 29.3 MB (proven available)
  uint8_t* ws = (uint8_t*)d_ws;

  knet_cvt_fp8<<<2048, 256, 0, stream>>>((const float*)d_in[7], ws + WS_WIH8,
                                         (long)G3*KIH/4);
  knet_build_w1e<<<(KIH + 255)/256, 256, 0, stream>>>(
      (const float*)d_in[5], (const float*)d_in[6], ws + WS_W1E);
  // no memset needed: tags are exact-match (t+1); 0xAA poison never matches

  int resident = 1;
  Offs o = mkoffs(resident);
  hipError_t e = hipFuncSetAttribute((const void*)knet_main,
                                     hipFuncAttributeMaxDynamicSharedMemorySize,
                                     o.total);
  if (e != hipSuccess) {
    resident = 0; o = mkoffs(resident);
    (void)hipFuncSetAttribute((const void*)knet_main,
                              hipFuncAttributeMaxDynamicSharedMemorySize, o.total);
  }

  Params p;
  p.A   = (const float*)d_in[0];  p.C   = (const float*)d_in[1];
  p.x0  = (const float*)d_in[2];  p.h0  = (const float*)d_in[3];
  p.y   = (const float*)d_in[4];
  p.W1  = (const float*)d_in[5];  p.b1  = (const float*)d_in[6];
  p.Wih = (const float*)d_in[7];  p.Whh = (const float*)d_in[8];
  p.bih = (const float*)d_in[9];  p.bhh = (const float*)d_in[10];
  p.W2  = (const float*)d_in[11]; p.b2  = (const float*)d_in[12];
  p.W3  = (const float*)d_in[13]; p.b3  = (const float*)d_in[14];
  p.wih8 = ws + WS_WIH8;
  p.w1e  = ws + WS_W1E;
  p.hbp  = ws + WS_HBP;
  p.slt  = ws + WS_SLT;
  p.out  = (float*)d_out;
  p.resident = resident;

  knet_main<<<NBLK, NTHR, (size_t)o.total, stream>>>(p);
}

// Round 7
// 8799.179 us; speedup vs baseline: 2.0905x; 1.0089x over previous
//
// KalmanNetNN persistent kernel, MI355X (gfx950).
// R7: ONE-round-trip exchanges — tag-in-data self-validating 8B words.
//   Every exchanged float is stored as ((step_tag<<32)|float_bits) with a
//   relaxed agent 8B atomic store (fire-and-forget: no vmcnt ack, no separate
//   tag store, no fences). Consumers poll the data words directly (all loads
//   of a packet in flight per poll round); tag match == data valid.
//   h packet: 10 words (128B stride); slot packet: 4 words (64B stride);
//   parity double-buffer (safety argument unchanged from R5/R6).
//   Rest = R6: 232 blocks, W_ih on-chip (LDS+VGPR), W_hh/W2 LDS fp8,
//   l1 redundant per block from fp8 W1ext (L2-resident).
// Predicted: step 17.3 -> 10-12 us => 5.2-6.5 ms.

#include <hip/hip_runtime.h>
#include <stdint.h>
#include <stddef.h>

typedef float v2f __attribute__((ext_vector_type(2)));

#define HID   2320
#define G3    6960
#define KIH   4160
#define KHH   2320
#define NBLK  232
#define NTHR  512
#define UPB   10
#define TSEQ  512
#define KRES  1600
#define INVWS (1.0f/128.0f)
#define SPINCAP (1u<<17)

// ---------------- workspace layout (bytes) ----------------
#define WS_WIH8 0L            // 6960*4160 fp8
#define WS_W1E  28953600L     // 4160*64 fp8 W1ext (52 w + b1 + pad)
#define WS_HBP  29219840L     // 2 x 232 x 128B h packets (10 tagged words)
#define WS_SLT  29279232L     // 2 x 232 x 64B slot packets (4 tagged words)
#define WS_END  29308928L

struct Offs {
  int l1s, hs, wih, whh, w2s, w3s, cs, as_, b3s, bih, bhh, b2s, gis, ghs,
      ts, inn, kn, dxs, xpri, xpo, b4, nrm, slp;
  int total;
};

__host__ __device__ inline Offs mkoffs(int res) {
  Offs o; int p = 0;
#define ALLOC(name, bytes) { p = (p + 15) & ~15; o.name = p; p += (bytes); }
  ALLOC(l1s, KIH*4) ALLOC(hs, HID*4)
  ALLOC(wih, res ? 30*KRES : 16) ALLOC(whh, res ? 30*KHH : 16)
  ALLOC(w2s, res ? 4*HID : 16)
  ALLOC(w3s, 16*48*4) ALLOC(cs, 240*4) ALLOC(as_, 64) ALLOC(b3s, 192*4)
  ALLOC(bih, 120) ALLOC(bhh, 120) ALLOC(b2s, 16)
  ALLOC(gis, 120) ALLOC(ghs, 120)
  ALLOC(ts, 64) ALLOC(inn, 192) ALLOC(kn, 256)
  ALLOC(dxs, 16) ALLOC(xpri, 16) ALLOC(xpo, 16) ALLOC(b4, 16) ALLOC(nrm, 16)
  ALLOC(slp, 64)
#undef ALLOC
  o.total = (p + 63) & ~63;
  return o;
}

struct Params {
  const float *A, *C, *x0, *h0, *y, *W1, *b1, *Wih, *Whh, *bih, *bhh, *W2, *b2, *W3, *b3;
  const uint8_t *wih8, *w1e;
  uint64_t *hbp, *slt;
  float *out;
  int resident;
};

__device__ __forceinline__ uint8_t f2fp8(float v) {
  v = fminf(fmaxf(v * 128.f, -448.f), 448.f);
  int pk = __builtin_amdgcn_cvt_pk_fp8_f32(v, v, 0, false);
  return (uint8_t)(pk & 0xff);
}

// fire-and-forget tagged publish: one self-validating 8B word.
__device__ __forceinline__ void pub64(uint64_t* a, uint32_t tag, float v) {
  uint64_t w = ((uint64_t)tag << 32) | (uint64_t)__float_as_uint(v);
  __hip_atomic_store(a, w, __ATOMIC_RELAXED, __HIP_MEMORY_SCOPE_AGENT);
}

// poll N tagged words (all loads in flight per round) until every hi32==want.
template<int N>
__device__ __forceinline__ void poll_pkt(const uint64_t* base, uint32_t want,
                                         float* out, bool& dead) {
  uint64_t v[N];
  uint32_t spins = 0;
  for (;;) {
    bool ok = true;
#pragma unroll
    for (int k = 0; k < N; ++k)
      v[k] = __hip_atomic_load(base + k, __ATOMIC_RELAXED, __HIP_MEMORY_SCOPE_AGENT);
#pragma unroll
    for (int k = 0; k < N; ++k) ok &= ((uint32_t)(v[k] >> 32) == want);
    if (ok || dead) break;
    __builtin_amdgcn_s_sleep(2);
    if (++spins > SPINCAP) dead = true;
  }
#pragma unroll
  for (int k = 0; k < N; ++k) out[k] = __uint_as_float((uint32_t)v[k]);
}

// fp8 row-dot, LDS weights, <=4 rows/wave, lanes split K.
__device__ __forceinline__ void dot8_lds(
    const float* __restrict__ acts, const uint8_t* __restrict__ w, int stride,
    int K, const int* lrows, int nr, int lane, float acc[4])
{
  int kb = 0;
  for (; kb + 256 <= K; kb += 256) {
    const float4 a = ((const float4*)(acts + kb))[lane];
#pragma unroll
    for (int j = 0; j < 4; ++j) if (j < nr) {
      uint32_t wb = *(const uint32_t*)(w + (size_t)lrows[j]*stride + kb + (lane<<2));
      v2f lo = __builtin_amdgcn_cvt_pk_f32_fp8((int)wb, false);
      v2f hi = __builtin_amdgcn_cvt_pk_f32_fp8((int)wb, true);
      acc[j] = fmaf(lo.x, a.x, acc[j]); acc[j] = fmaf(lo.y, a.y, acc[j]);
      acc[j] = fmaf(hi.x, a.z, acc[j]); acc[j] = fmaf(hi.y, a.w, acc[j]);
    }
  }
  int rem = K - kb;
  if ((lane << 2) < rem) {
    const float4 a = ((const float4*)(acts + kb))[lane];
#pragma unroll
    for (int j = 0; j < 4; ++j) if (j < nr) {
      uint32_t wb = *(const uint32_t*)(w + (size_t)lrows[j]*stride + kb + (lane<<2));
      v2f lo = __builtin_amdgcn_cvt_pk_f32_fp8((int)wb, false);
      v2f hi = __builtin_amdgcn_cvt_pk_f32_fp8((int)wb, true);
      acc[j] = fmaf(lo.x, a.x, acc[j]); acc[j] = fmaf(lo.y, a.y, acc[j]);
      acc[j] = fmaf(hi.x, a.z, acc[j]); acc[j] = fmaf(hi.y, a.w, acc[j]);
    }
  }
}

// fp8 row-dot, global weights, cols [K0,K).
__device__ __forceinline__ void dot8_glb(
    const float* __restrict__ acts, const uint8_t* __restrict__ gw, int gstride,
    int K0, int K, const int* grows, int nr, int lane, float acc[4])
{
  int kb = K0;
  for (; kb + 512 <= K; kb += 512) {
    const float4 a0 = ((const float4*)(acts + kb))[lane*2];
    const float4 a1 = ((const float4*)(acts + kb))[lane*2 + 1];
#pragma unroll
    for (int j = 0; j < 4; ++j) if (j < nr) {
      uint2 wb = *(const uint2*)(gw + (size_t)grows[j]*gstride + kb + (lane<<3));
      v2f l0 = __builtin_amdgcn_cvt_pk_f32_fp8((int)wb.x, false);
      v2f h0 = __builtin_amdgcn_cvt_pk_f32_fp8((int)wb.x, true);
      v2f l1 = __builtin_amdgcn_cvt_pk_f32_fp8((int)wb.y, false);
      v2f h1 = __builtin_amdgcn_cvt_pk_f32_fp8((int)wb.y, true);
      acc[j] = fmaf(l0.x, a0.x, acc[j]); acc[j] = fmaf(l0.y, a0.y, acc[j]);
      acc[j] = fmaf(h0.x, a0.z, acc[j]); acc[j] = fmaf(h0.y, a0.w, acc[j]);
      acc[j] = fmaf(l1.x, a1.x, acc[j]); acc[j] = fmaf(l1.y, a1.y, acc[j]);
      acc[j] = fmaf(h1.x, a1.z, acc[j]); acc[j] = fmaf(h1.y, a1.w, acc[j]);
    }
  }
  for (int e = kb + lane; e < K; e += 64) {
    float a = acts[e];
#pragma unroll
    for (int j = 0; j < 4; ++j) if (j < nr) {
      v2f lo = __builtin_amdgcn_cvt_pk_f32_fp8(
          (int)(uint32_t)gw[(size_t)grows[j]*gstride + e], false);
      acc[j] = fmaf(lo.x, a, acc[j]);
    }
  }
}

// f32 row-dot, global weights (fallback ghh).
__device__ __forceinline__ void dotf_glb(
    const float* __restrict__ acts, const float* __restrict__ gw, int gstride,
    int K, const int* grows, int nr, int lane, float acc[4])
{
  for (int k = lane; k < K; k += 64) {
    float a = acts[k];
#pragma unroll
    for (int j = 0; j < 4; ++j) if (j < nr)
      acc[j] = fmaf(gw[(size_t)grows[j]*gstride + k], a, acc[j]);
  }
}

extern "C" __global__ void __launch_bounds__(NTHR, 2) knet_main(Params p)
{
  extern __shared__ char smem[];
  const Offs o = mkoffs(p.resident);
  float*   L1S  = (float*)(smem + o.l1s);
  float*   HS   = (float*)(smem + o.hs);
  uint8_t* WIHR = (uint8_t*)(smem + o.wih);
  uint8_t* WHHR = (uint8_t*)(smem + o.whh);
  uint8_t* W2S  = (uint8_t*)(smem + o.w2s);
  float*   W3S  = (float*)(smem + o.w3s);
  float*   CS   = (float*)(smem + o.cs);
  float*   AS   = (float*)(smem + o.as_);
  float*   B3S  = (float*)(smem + o.b3s);
  float*   BIH  = (float*)(smem + o.bih);
  float*   BHH  = (float*)(smem + o.bhh);
  float*   B2S  = (float*)(smem + o.b2s);
  float*   GIS  = (float*)(smem + o.gis);
  float*   GHS  = (float*)(smem + o.ghs);
  float*   TS   = (float*)(smem + o.ts);
  float*   INNS = (float*)(smem + o.inn);
  float*   KN   = (float*)(smem + o.kn);
  float*   DXS  = (float*)(smem + o.dxs);
  float*   XPRI = (float*)(smem + o.xpri);
  float*   XPO  = (float*)(smem + o.xpo);
  float*   B4   = (float*)(smem + o.b4);
  float*   NRM  = (float*)(smem + o.nrm);
  float*   SLP  = (float*)(smem + o.slp);

  const int tid  = (int)threadIdx.x;
  const int bid  = (int)blockIdx.x;
  const int lane = tid & 63;
  const int wv   = tid >> 6;
  const int rows2 = (bid < 72) ? 4 : 3;               // l2 rows: 72*4+160*3=768
  const int r2s   = (bid < 72) ? bid*4 : 288 + (bid-72)*3;
  bool dead = false;

  int lrows[4] = {0,0,0,0}, grows[4] = {0,0,0,0};
  int nr = 0;
#pragma unroll
  for (int j = 0; j < 4; ++j) {
    int row = wv + 8*j;
    if (row < 30) { int u = row/3, g = row - 3*u;
      lrows[nr] = row; grows[nr] = g*HID + bid*UPB + u; ++nr; }
  }

  // ---------------- one-time staging ----------------
  for (int i = tid; i < rows2*192; i += NTHR) { int rl = i/192, rem = i - rl*192;
    W3S[i] = p.W3[(size_t)rem*768 + (r2s + rl)]; }
  for (int i = tid; i < 240; i += NTHR) CS[i] = p.C[i];
  if (tid < 16) AS[tid] = p.A[tid];
  for (int i = tid; i < 192; i += NTHR) B3S[i] = p.b3[i];
  if (tid < rows2) B2S[tid] = p.b2[r2s + tid];
  if (tid < 30) {
    int u = tid/3, g = tid - 3*u, ug = bid*UPB + u;
    BIH[tid] = p.bih[g*HID + ug];
    BHH[tid] = p.bhh[g*HID + ug];
  }
  for (int i = tid; i < HID; i += NTHR) HS[i] = p.h0[i];
  if (p.resident) {
    const int kd = KRES >> 2;                   // W_ih resident cols from fp8 ws
    uint32_t* W32 = (uint32_t*)WIHR;
    for (int i = tid; i < 30*kd; i += NTHR) {
      int row = i / kd, c = i - row*kd;
      int u = row/3, g = row - 3*u, gr = g*HID + bid*UPB + u;
      W32[i] = ((const uint32_t*)p.wih8)[(size_t)gr*(KIH/4) + c];
    }
    for (int i = tid; i < 30*KHH; i += NTHR) {  // W_hh rows f32->fp8
      int row = i / KHH, k = i - row*KHH;
      int u = row/3, g = row - 3*u, gr = g*HID + bid*UPB + u;
      WHHR[i] = f2fp8(p.Whh[(size_t)gr*KHH + k]);
    }
    for (int i = tid; i < rows2*HID; i += NTHR) { // W2 slice f32->fp8
      int rl = i / HID, k = i - rl*HID;
      W2S[i] = f2fp8(p.W2[(size_t)(r2s+rl)*HID + k]);
    }
  }
  // streamed W_ih cols [KRES,4160) hoisted into VGPRs (constant across steps)
  uint2 pf[4][5];
#pragma unroll
  for (int j = 0; j < 4; ++j)
#pragma unroll
    for (int i = 0; i < 5; ++i) pf[j][i] = make_uint2(0u, 0u);
#pragma unroll
  for (int j = 0; j < 4; ++j) if (j < nr)
#pragma unroll
    for (int i = 0; i < 5; ++i)
      pf[j][i] = *(const uint2*)(p.wih8 + (size_t)grows[j]*KIH + KRES + i*512 + (lane<<3));
  __syncthreads();

  // small chain producing step-`ycol` inputs: INNS, KN, B4, TS, full l1.
  auto small_chain = [&](int ycol) {
    if (tid < 48) {
      float s = CS[tid*5 + 4];
#pragma unroll
      for (int k = 0; k < 4; ++k) s += CS[tid*5 + k] * XPRI[k];
      INNS[tid] = p.y[(size_t)tid*TSEQ + ycol] - s;
    }
    __syncthreads();
    if (tid == 0) {
      float s = 0;
      for (int j = 0; j < 48; ++j) s += INNS[j]*INNS[j];
      NRM[0] = fmaxf(sqrtf(s), 1e-12f);
      float s2 = 0;
      for (int j = 0; j < 4; ++j) s2 += DXS[j]*DXS[j];
      NRM[1] = fmaxf(sqrtf(s2), 1e-12f);
    }
    __syncthreads();
    if (tid < 48) KN[tid] = INNS[tid] / NRM[0];
    else if (tid < 52) KN[tid] = DXS[tid-48] / NRM[1];
    else if (tid == 52) KN[tid] = 1.0f;
    else if (tid < 64) KN[tid] = 0.0f;
    else if (tid < 68) {
      int i = tid - 64; float s = 0;
      for (int j = 0; j < 48; ++j) s += B3S[i*48 + j] * INNS[j];
      B4[i] = s;
    }
    if (tid >= 128 && tid < 128 + rows2*4) {
      int idx = tid - 128, rl = idx >> 2, i = idx & 3;
      float s = 0;
      for (int j = 0; j < 48; ++j) s += W3S[rl*192 + i*48 + j] * INNS[j];
      TS[i*4 + rl] = s;
    }
    __syncthreads();
    {                                            // redundant full l1
      float4 kn[16];
#pragma unroll
      for (int c = 0; c < 16; ++c) kn[c] = ((const float4*)KN)[c];
      for (int r = tid; r < KIH; r += NTHR) {
        const uint4* wp = (const uint4*)(p.w1e + (size_t)r*64);
        float acc = 0.f;
#pragma unroll
        for (int q = 0; q < 4; ++q) {
          uint4 w = wp[q];
          v2f l0 = __builtin_amdgcn_cvt_pk_f32_fp8((int)w.x, false);
          v2f h0 = __builtin_amdgcn_cvt_pk_f32_fp8((int)w.x, true);
          v2f l1 = __builtin_amdgcn_cvt_pk_f32_fp8((int)w.y, false);
          v2f h1 = __builtin_amdgcn_cvt_pk_f32_fp8((int)w.y, true);
          v2f l2 = __builtin_amdgcn_cvt_pk_f32_fp8((int)w.z, false);
          v2f h2 = __builtin_amdgcn_cvt_pk_f32_fp8((int)w.z, true);
          v2f l3 = __builtin_amdgcn_cvt_pk_f32_fp8((int)w.w, false);
          v2f h3 = __builtin_amdgcn_cvt_pk_f32_fp8((int)w.w, true);
          float4 a0 = kn[q*4+0], a1 = kn[q*4+1], a2 = kn[q*4+2], a3 = kn[q*4+3];
          acc = fmaf(l0.x,a0.x,acc); acc = fmaf(l0.y,a0.y,acc);
          acc = fmaf(h0.x,a0.z,acc); acc = fmaf(h0.y,a0.w,acc);
          acc = fmaf(l1.x,a1.x,acc); acc = fmaf(l1.y,a1.y,acc);
          acc = fmaf(h1.x,a1.z,acc); acc = fmaf(h1.y,a1.w,acc);
          acc = fmaf(l2.x,a2.x,acc); acc = fmaf(l2.y,a2.y,acc);
          acc = fmaf(h2.x,a2.z,acc); acc = fmaf(h2.y,a2.w,acc);
          acc = fmaf(l3.x,a3.x,acc); acc = fmaf(l3.y,a3.y,acc);
          acc = fmaf(h3.x,a3.z,acc); acc = fmaf(h3.y,a3.w,acc);
        }
        L1S[r] = fmaxf(acc * INVWS, 0.f);
      }
    }
    __syncthreads();
  };

  auto ghh = [&]() {                             // W_hh @ HS -> GHS
    float acc[4] = {0,0,0,0};
    if (p.resident) dot8_lds(HS, WHHR, KHH, KHH, lrows, nr, lane, acc);
    else            dotf_glb(HS, p.Whh, KHH, KHH, grows, nr, lane, acc);
#pragma unroll
    for (int m = 32; m >= 1; m >>= 1)
#pragma unroll
      for (int j = 0; j < 4; ++j) acc[j] += __shfl_xor(acc[j], m, 64);
    if (lane == 0)
#pragma unroll
      for (int j = 0; j < 4; ++j) if (j < nr) GHS[lrows[j]] = acc[j];
  };

  // ---------------- pre-loop ----------------
  if (tid < 4) { XPO[tid] = p.x0[tid]; DXS[tid] = 0.f; }
  __syncthreads();
  if (tid < 4) {
    float s = 0;
#pragma unroll
    for (int j = 0; j < 4; ++j) s += AS[tid*4 + j] * XPO[j];
    XPRI[tid] = s;
  }
  __syncthreads();
  small_chain(0);
  ghh();
  __syncthreads();

  // ---------------- main sequence (1-round-trip exchanges) ----------------
  for (int t = 0; t < TSEQ; ++t) {
    const int par = t & 1;
    const uint32_t want = (uint32_t)(t + 1);

    // ---- A: gate-dot gi = W_ih @ l1(t) ----
    {
      float acc[4] = {0,0,0,0};
      if (p.resident) dot8_lds(L1S, WIHR, KRES, KRES, lrows, nr, lane, acc);
      else            dot8_glb(L1S, p.wih8, KIH, 0, KRES, grows, nr, lane, acc);
#pragma unroll
      for (int i = 0; i < 5; ++i) {              // VGPR-held streamed cols
        const float4 a0 = ((const float4*)(L1S + KRES + i*512))[lane*2];
        const float4 a1 = ((const float4*)(L1S + KRES + i*512))[lane*2 + 1];
#pragma unroll
        for (int j = 0; j < 4; ++j) if (j < nr) {
          uint2 w = pf[j][i];
          v2f l0 = __builtin_amdgcn_cvt_pk_f32_fp8((int)w.x, false);
          v2f h0 = __builtin_amdgcn_cvt_pk_f32_fp8((int)w.x, true);
          v2f l1v = __builtin_amdgcn_cvt_pk_f32_fp8((int)w.y, false);
          v2f h1 = __builtin_amdgcn_cvt_pk_f32_fp8((int)w.y, true);
          acc[j] = fmaf(l0.x, a0.x, acc[j]); acc[j] = fmaf(l0.y, a0.y, acc[j]);
          acc[j] = fmaf(h0.x, a0.z, acc[j]); acc[j] = fmaf(h0.y, a0.w, acc[j]);
          acc[j] = fmaf(l1v.x, a1.x, acc[j]); acc[j] = fmaf(l1v.y, a1.y, acc[j]);
          acc[j] = fmaf(h1.x, a1.z, acc[j]); acc[j] = fmaf(h1.y, a1.w, acc[j]);
        }
      }
#pragma unroll
      for (int m = 32; m >= 1; m >>= 1)
#pragma unroll
        for (int j = 0; j < 4; ++j) acc[j] += __shfl_xor(acc[j], m, 64);
      if (lane == 0)
#pragma unroll
        for (int j = 0; j < 4; ++j) if (j < nr) GIS[lrows[j]] = acc[j];
    }
    __syncthreads();

    // ---- B: h(t) + fire-and-forget tagged publish (lanes 0..9) ----
    if (tid < UPB) {
      int ug = bid*UPB + tid, r0 = tid*3;
      float gi0 = GIS[r0+0]*INVWS + BIH[r0+0], gh0 = GHS[r0+0]*INVWS + BHH[r0+0];
      float gi1 = GIS[r0+1]*INVWS + BIH[r0+1], gh1 = GHS[r0+1]*INVWS + BHH[r0+1];
      float gi2 = GIS[r0+2]*INVWS + BIH[r0+2], gh2 = GHS[r0+2]*INVWS + BHH[r0+2];
      float rg = 1.f/(1.f + expf(-(gi0+gh0)));
      float zg = 1.f/(1.f + expf(-(gi1+gh1)));
      float ng = tanhf(gi2 + rg*gh2);
      float hnew = (1.f - zg)*ng + zg*HS[ug];
      pub64(p.hbp + (((size_t)par*NBLK + bid) << 4) + tid, want, hnew);
    }
    __syncthreads();   // protect HS (old h) reads in B before C overwrites

    // ---- C: h broadcast consume -> HS (self-validating words) ----
    if (wv < 4) {
      int idx = (wv << 6) | lane;
      if (idx < NBLK) {
        float v[10];
        poll_pkt<10>(p.hbp + (((size_t)par*NBLK + idx) << 4), want, v, dead);
#pragma unroll
        for (int k = 0; k < 10; ++k) HS[idx*10 + k] = v[k];
      }
    }
    __syncthreads();

    // ---- D: l2 (wave 0 only) + tagged slot publish (lanes 0..3) ----
    if (wv == 0) {
      float a2[4] = {0,0,0,0};
      if (p.resident) {
        int kb = 0;
        for (; kb + 256 <= HID; kb += 256) {
          const float4 a = ((const float4*)(HS + kb))[lane];
#pragma unroll
          for (int rl = 0; rl < 4; ++rl) if (rl < rows2) {
            uint32_t wb = *(const uint32_t*)(W2S + rl*HID + kb + (lane<<2));
            v2f lo = __builtin_amdgcn_cvt_pk_f32_fp8((int)wb, false);
            v2f hi = __builtin_amdgcn_cvt_pk_f32_fp8((int)wb, true);
            a2[rl] = fmaf(lo.x, a.x, a2[rl]); a2[rl] = fmaf(lo.y, a.y, a2[rl]);
            a2[rl] = fmaf(hi.x, a.z, a2[rl]); a2[rl] = fmaf(hi.y, a.w, a2[rl]);
          }
        }
        if ((lane << 2) < HID - kb) {
          const float4 a = ((const float4*)(HS + kb))[lane];
#pragma unroll
          for (int rl = 0; rl < 4; ++rl) if (rl < rows2) {
            uint32_t wb = *(const uint32_t*)(W2S + rl*HID + kb + (lane<<2));
            v2f lo = __builtin_amdgcn_cvt_pk_f32_fp8((int)wb, false);
            v2f hi = __builtin_amdgcn_cvt_pk_f32_fp8((int)wb, true);
            a2[rl] = fmaf(lo.x, a.x, a2[rl]); a2[rl] = fmaf(lo.y, a.y, a2[rl]);
            a2[rl] = fmaf(hi.x, a.z, a2[rl]); a2[rl] = fmaf(hi.y, a.w, a2[rl]);
          }
        }
#pragma unroll
        for (int rl = 0; rl < 4; ++rl) a2[rl] *= INVWS;
      } else {
        for (int k = lane; k < HID; k += 64) {
          float a = HS[k];
#pragma unroll
          for (int rl = 0; rl < 4; ++rl) if (rl < rows2)
            a2[rl] = fmaf(p.W2[(size_t)(r2s+rl)*HID + k], a, a2[rl]);
        }
      }
#pragma unroll
      for (int m = 32; m >= 1; m >>= 1)
#pragma unroll
        for (int rl = 0; rl < 4; ++rl) a2[rl] += __shfl_xor(a2[rl], m, 64);
      if (lane < 4) {                            // each lane: one tagged word
        float l2v[4];
#pragma unroll
        for (int rl = 0; rl < 4; ++rl)
          l2v[rl] = (rl < rows2) ? fmaxf(a2[rl] + B2S[rl], 0.f) : 0.f;
        float cp = l2v[0]*TS[lane*4+0] + l2v[1]*TS[lane*4+1]
                 + l2v[2]*TS[lane*4+2] + l2v[3]*TS[lane*4+3];
        pub64(p.slt + (((size_t)par*NBLK + bid) << 3) + lane, want, cp);
      }
    }

    // ---- E: ghh(t) for step t+1 (off critical path, covers slot flight) ----
    ghh();

    // ---- F: slot reduce (waves 0-3, self-validating words) ----
    if (wv < 4) {
      int idx = (wv << 6) | lane;
      float s0 = 0, s1 = 0, s2 = 0, s3 = 0;
      if (idx < NBLK) {
        float v[4];
        poll_pkt<4>(p.slt + (((size_t)par*NBLK + idx) << 3), want, v, dead);
        s0 = v[0]; s1 = v[1]; s2 = v[2]; s3 = v[3];
      }
#pragma unroll
      for (int m = 32; m >= 1; m >>= 1) {
        s0 += __shfl_xor(s0, m, 64); s1 += __shfl_xor(s1, m, 64);
        s2 += __shfl_xor(s2, m, 64); s3 += __shfl_xor(s3, m, 64);
      }
      if (lane == 0) {
        SLP[wv*4+0] = s0; SLP[wv*4+1] = s1; SLP[wv*4+2] = s2; SLP[wv*4+3] = s3;
      }
    }
    __syncthreads();

    // ---- G: posterior + next-step chain ----
    if (tid < 4) {
      float c = SLP[tid] + SLP[4 + tid] + SLP[8 + tid] + SLP[12 + tid];
      float xp = XPRI[tid] + (c + B4[tid]) * 1e-4f;
      XPO[tid] = xp;
      if (bid == 0) p.out[(size_t)tid*TSEQ + t] = xp;
    }
    __syncthreads();
    if (t + 1 < TSEQ) {
      if (tid < 4) {
        float xo = XPO[tid];
        DXS[tid] = xo - XPRI[tid];
        float s = 0;
#pragma unroll
        for (int j = 0; j < 4; ++j) s += AS[tid*4 + j] * XPO[j];
        XPRI[tid] = s;
      }
      __syncthreads();
      small_chain(t + 1);                        // ends with syncthreads
    }
  }
}

// f32 -> fp8 e4m3 (x128), 4 elements per thread (W_ih full).
extern "C" __global__ void knet_cvt_fp8(const float* __restrict__ src,
                                        uint8_t* __restrict__ dst, long n4) {
  long stride = (long)gridDim.x * blockDim.x;
  for (long i = (long)blockIdx.x*blockDim.x + threadIdx.x; i < n4; i += stride) {
    float4 v = ((const float4*)src)[i];
    float a0 = fminf(fmaxf(v.x * 128.f, -448.f), 448.f);
    float a1 = fminf(fmaxf(v.y * 128.f, -448.f), 448.f);
    float a2 = fminf(fmaxf(v.z * 128.f, -448.f), 448.f);
    float a3 = fminf(fmaxf(v.w * 128.f, -448.f), 448.f);
    int pk = __builtin_amdgcn_cvt_pk_fp8_f32(a0, a1, 0, false);
    pk = __builtin_amdgcn_cvt_pk_fp8_f32(a2, a3, pk, true);
    ((uint32_t*)dst)[i] = (uint32_t)pk;
  }
}

// Build W1ext fp8: row r = [W1[r,0:52], b1[r], 0 x11] * 128, 64 B/row.
extern "C" __global__ void knet_build_w1e(const float* __restrict__ W1,
                                          const float* __restrict__ b1,
                                          uint8_t* __restrict__ dst) {
  int r = blockIdx.x * blockDim.x + threadIdx.x;
  if (r >= KIH) return;
  float v[64];
#pragma unroll 13
  for (int q = 0; q < 13; ++q) {
    float4 w = ((const float4*)(W1 + (size_t)r*52))[q];
    v[q*4+0] = w.x; v[q*4+1] = w.y; v[q*4+2] = w.z; v[q*4+3] = w.w;
  }
  v[52] = b1[r];
  for (int i = 53; i < 64; ++i) v[i] = 0.f;
  uint32_t out[16];
#pragma unroll 16
  for (int d = 0; d < 16; ++d) {
    float a0 = fminf(fmaxf(v[d*4+0] * 128.f, -448.f), 448.f);
    float a1 = fminf(fmaxf(v[d*4+1] * 128.f, -448.f), 448.f);
    float a2 = fminf(fmaxf(v[d*4+2] * 128.f, -448.f), 448.f);
    float a3 = fminf(fmaxf(v[d*4+3] * 128.f, -448.f), 448.f);
    int pk = __builtin_amdgcn_cvt_pk_fp8_f32(a0, a1, 0, false);
    pk = __builtin_amdgcn_cvt_pk_fp8_f32(a2, a3, pk, true);
    out[d] = (uint32_t)pk;
  }
  uint4* dp = (uint4*)(dst + (size_t)r*64);
#pragma unroll 4
  for (int q = 0; q < 4; ++q)
    dp[q] = make_uint4(out[q*4+0], out[q*4+1], out[q*4+2], out[q*4+3]);
}

extern "C" void kernel_launch(void* const* d_in, const int* in_sizes, int n_in,
                              void* d_out, int out_size, void* d_ws, size_t ws_size,
                              hipStream_t stream)
{
  if (ws_size < (size_t)WS_END) return;   // 29.3 MB (proven available)
  uint8_t* ws = (uint8_t*)d_ws;

  knet_cvt_fp8<<<2048, 256, 0, stream>>>((const float*)d_in[7], ws + WS_WIH8,
                                         (long)G3*KIH/4);
  knet_build_w1e<<<(KIH + 255)/256, 256, 0, stream>>>(
      (const float*)d_in[5], (const float*)d_in[6], ws + WS_W1E);
  // no memset needed: word tags are exact-match (t+1); 0xAA poison never matches

  int resident = 1;
  Offs o = mkoffs(resident);
  hipError_t e = hipFuncSetAttribute((const void*)knet_main,
                                     hipFuncAttributeMaxDynamicSharedMemorySize,
                                     o.total);
  if (e != hipSuccess) {
    resident = 0; o = mkoffs(resident);
    (void)hipFuncSetAttribute((const void*)knet_main,
                              hipFuncAttributeMaxDynamicSharedMemorySize, o.total);
  }

  Params p;
  p.A   = (const float*)d_in[0];  p.C   = (const float*)d_in[1];
  p.x0  = (const float*)d_in[2];  p.h0  = (const float*)d_in[3];
  p.y   = (const float*)d_in[4];
  p.W1  = (const float*)d_in[5];  p.b1  = (const float*)d_in[6];
  p.Wih = (const float*)d_in[7];  p.Whh = (const float*)d_in[8];
  p.bih = (const float*)d_in[9];  p.bhh = (const float*)d_in[10];
  p.W2  = (const float*)d_in[11]; p.b2  = (const float*)d_in[12];
  p.W3  = (const float*)d_in[13]; p.b3  = (const float*)d_in[14];
  p.wih8 = ws + WS_WIH8;
  p.w1e  = ws + WS_W1E;
  p.hbp  = (uint64_t*)(ws + WS_HBP);
  p.slt  = (uint64_t*)(ws + WS_SLT);
  p.out  = (float*)d_out;
  p.resident = resident;

  knet_main<<<NBLK, NTHR, (size_t)o.total, stream>>>(p);
}

// Round 8
// 8290.298 us; speedup vs baseline: 2.2188x; 1.0614x over previous
//
// KalmanNetNN persistent kernel, MI355X (gfx950).
// R8: de-serialize the post-h-exchange segment.
//   - l2: uniform 4 rows on blocks 0..191 (fan-in 192), 1 row per wave on
//     waves 4-7 (parallel, ~0.2us), block sync, publish, then ghh on ALL
//     waves covers slot flight; slot poll on waves 0-2.
//   - norms via wave shuffle reduce (was single-thread 48-iter loop).
//   - polls hot-start (sleep only after 8 misses).
//   Exchange mechanism unchanged from R7 (tag-in-data 8B words, relaxed
//   agent atomics, no fences/wbl2 — R7 proved mechanism cost is not the issue).
// Predicted: step 17.2 -> ~15 us => 7.4-8.1 ms.

#include <hip/hip_runtime.h>
#include <stdint.h>
#include <stddef.h>

typedef float v2f __attribute__((ext_vector_type(2)));

#define HID   2320
#define G3    6960
#define KIH   4160
#define KHH   2320
#define NBLK  232
#define NL2B  192              // blocks owning l2 rows (4 each = 768)
#define NTHR  512
#define UPB   10
#define TSEQ  512
#define KRES  1600
#define INVWS (1.0f/128.0f)
#define SPINCAP (1u<<17)

// ---------------- workspace layout (bytes) ----------------
#define WS_WIH8 0L            // 6960*4160 fp8
#define WS_W1E  28953600L     // 4160*64 fp8 W1ext (52 w + b1 + pad)
#define WS_HBP  29219840L     // 2 x 232 x 128B h packets (10 tagged words)
#define WS_SLT  29279232L     // 2 x 232 x 64B slot packets (4 tagged words)
#define WS_END  29308928L

struct Offs {
  int l1s, hs, wih, whh, w2s, w3s, cs, as_, b3s, bih, bhh, b2s, gis, ghs,
      ts, inn, kn, dxs, xpri, xpo, b4, nrm, l2r, slp;
  int total;
};

__host__ __device__ inline Offs mkoffs(int res) {
  Offs o; int p = 0;
#define ALLOC(name, bytes) { p = (p + 15) & ~15; o.name = p; p += (bytes); }
  ALLOC(l1s, KIH*4) ALLOC(hs, HID*4)
  ALLOC(wih, res ? 30*KRES : 16) ALLOC(whh, res ? 30*KHH : 16)
  ALLOC(w2s, res ? 4*HID : 16)
  ALLOC(w3s, 16*48*4) ALLOC(cs, 240*4) ALLOC(as_, 64) ALLOC(b3s, 192*4)
  ALLOC(bih, 120) ALLOC(bhh, 120) ALLOC(b2s, 16)
  ALLOC(gis, 120) ALLOC(ghs, 120)
  ALLOC(ts, 64) ALLOC(inn, 192) ALLOC(kn, 256)
  ALLOC(dxs, 16) ALLOC(xpri, 16) ALLOC(xpo, 16) ALLOC(b4, 16) ALLOC(nrm, 16)
  ALLOC(l2r, 16) ALLOC(slp, 64)
#undef ALLOC
  o.total = (p + 63) & ~63;
  return o;
}

struct Params {
  const float *A, *C, *x0, *h0, *y, *W1, *b1, *Wih, *Whh, *bih, *bhh, *W2, *b2, *W3, *b3;
  const uint8_t *wih8, *w1e;
  uint64_t *hbp, *slt;
  float *out;
  int resident;
};

__device__ __forceinline__ uint8_t f2fp8(float v) {
  v = fminf(fmaxf(v * 128.f, -448.f), 448.f);
  int pk = __builtin_amdgcn_cvt_pk_fp8_f32(v, v, 0, false);
  return (uint8_t)(pk & 0xff);
}

// fire-and-forget tagged publish: one self-validating 8B word.
__device__ __forceinline__ void pub64(uint64_t* a, uint32_t tag, float v) {
  uint64_t w = ((uint64_t)tag << 32) | (uint64_t)__float_as_uint(v);
  __hip_atomic_store(a, w, __ATOMIC_RELAXED, __HIP_MEMORY_SCOPE_AGENT);
}

// poll N tagged words; hot for first 8 rounds, then s_sleep(2) throttle.
template<int N>
__device__ __forceinline__ void poll_pkt(const uint64_t* base, uint32_t want,
                                         float* out, bool& dead) {
  uint64_t v[N];
  uint32_t spins = 0;
  for (;;) {
    bool ok = true;
#pragma unroll
    for (int k = 0; k < N; ++k)
      v[k] = __hip_atomic_load(base + k, __ATOMIC_RELAXED, __HIP_MEMORY_SCOPE_AGENT);
#pragma unroll
    for (int k = 0; k < N; ++k) ok &= ((uint32_t)(v[k] >> 32) == want);
    if (ok || dead) break;
    ++spins;
    if (spins > 8) __builtin_amdgcn_s_sleep(2);
    if (spins > SPINCAP) dead = true;
  }
#pragma unroll
  for (int k = 0; k < N; ++k) out[k] = __uint_as_float((uint32_t)v[k]);
}

// fp8 row-dot, LDS weights, <=4 rows/wave, lanes split K.
__device__ __forceinline__ void dot8_lds(
    const float* __restrict__ acts, const uint8_t* __restrict__ w, int stride,
    int K, const int* lrows, int nr, int lane, float acc[4])
{
  int kb = 0;
  for (; kb + 256 <= K; kb += 256) {
    const float4 a = ((const float4*)(acts + kb))[lane];
#pragma unroll
    for (int j = 0; j < 4; ++j) if (j < nr) {
      uint32_t wb = *(const uint32_t*)(w + (size_t)lrows[j]*stride + kb + (lane<<2));
      v2f lo = __builtin_amdgcn_cvt_pk_f32_fp8((int)wb, false);
      v2f hi = __builtin_amdgcn_cvt_pk_f32_fp8((int)wb, true);
      acc[j] = fmaf(lo.x, a.x, acc[j]); acc[j] = fmaf(lo.y, a.y, acc[j]);
      acc[j] = fmaf(hi.x, a.z, acc[j]); acc[j] = fmaf(hi.y, a.w, acc[j]);
    }
  }
  int rem = K - kb;
  if ((lane << 2) < rem) {
    const float4 a = ((const float4*)(acts + kb))[lane];
#pragma unroll
    for (int j = 0; j < 4; ++j) if (j < nr) {
      uint32_t wb = *(const uint32_t*)(w + (size_t)lrows[j]*stride + kb + (lane<<2));
      v2f lo = __builtin_amdgcn_cvt_pk_f32_fp8((int)wb, false);
      v2f hi = __builtin_amdgcn_cvt_pk_f32_fp8((int)wb, true);
      acc[j] = fmaf(lo.x, a.x, acc[j]); acc[j] = fmaf(lo.y, a.y, acc[j]);
      acc[j] = fmaf(hi.x, a.z, acc[j]); acc[j] = fmaf(hi.y, a.w, acc[j]);
    }
  }
}

// fp8 row-dot, global weights, cols [K0,K).
__device__ __forceinline__ void dot8_glb(
    const float* __restrict__ acts, const uint8_t* __restrict__ gw, int gstride,
    int K0, int K, const int* grows, int nr, int lane, float acc[4])
{
  int kb = K0;
  for (; kb + 512 <= K; kb += 512) {
    const float4 a0 = ((const float4*)(acts + kb))[lane*2];
    const float4 a1 = ((const float4*)(acts + kb))[lane*2 + 1];
#pragma unroll
    for (int j = 0; j < 4; ++j) if (j < nr) {
      uint2 wb = *(const uint2*)(gw + (size_t)grows[j]*gstride + kb + (lane<<3));
      v2f l0 = __builtin_amdgcn_cvt_pk_f32_fp8((int)wb.x, false);
      v2f h0 = __builtin_amdgcn_cvt_pk_f32_fp8((int)wb.x, true);
      v2f l1 = __builtin_amdgcn_cvt_pk_f32_fp8((int)wb.y, false);
      v2f h1 = __builtin_amdgcn_cvt_pk_f32_fp8((int)wb.y, true);
      acc[j] = fmaf(l0.x, a0.x, acc[j]); acc[j] = fmaf(l0.y, a0.y, acc[j]);
      acc[j] = fmaf(h0.x, a0.z, acc[j]); acc[j] = fmaf(h0.y, a0.w, acc[j]);
      acc[j] = fmaf(l1.x, a1.x, acc[j]); acc[j] = fmaf(l1.y, a1.y, acc[j]);
      acc[j] = fmaf(h1.x, a1.z, acc[j]); acc[j] = fmaf(h1.y, a1.w, acc[j]);
    }
  }
  for (int e = kb + lane; e < K; e += 64) {
    float a = acts[e];
#pragma unroll
    for (int j = 0; j < 4; ++j) if (j < nr) {
      v2f lo = __builtin_amdgcn_cvt_pk_f32_fp8(
          (int)(uint32_t)gw[(size_t)grows[j]*gstride + e], false);
      acc[j] = fmaf(lo.x, a, acc[j]);
    }
  }
}

// f32 row-dot, global weights (fallback ghh).
__device__ __forceinline__ void dotf_glb(
    const float* __restrict__ acts, const float* __restrict__ gw, int gstride,
    int K, const int* grows, int nr, int lane, float acc[4])
{
  for (int k = lane; k < K; k += 64) {
    float a = acts[k];
#pragma unroll
    for (int j = 0; j < 4; ++j) if (j < nr)
      acc[j] = fmaf(gw[(size_t)grows[j]*gstride + k], a, acc[j]);
  }
}

extern "C" __global__ void __launch_bounds__(NTHR, 2) knet_main(Params p)
{
  extern __shared__ char smem[];
  const Offs o = mkoffs(p.resident);
  float*   L1S  = (float*)(smem + o.l1s);
  float*   HS   = (float*)(smem + o.hs);
  uint8_t* WIHR = (uint8_t*)(smem + o.wih);
  uint8_t* WHHR = (uint8_t*)(smem + o.whh);
  uint8_t* W2S  = (uint8_t*)(smem + o.w2s);
  float*   W3S  = (float*)(smem + o.w3s);
  float*   CS   = (float*)(smem + o.cs);
  float*   AS   = (float*)(smem + o.as_);
  float*   B3S  = (float*)(smem + o.b3s);
  float*   BIH  = (float*)(smem + o.bih);
  float*   BHH  = (float*)(smem + o.bhh);
  float*   B2S  = (float*)(smem + o.b2s);
  float*   GIS  = (float*)(smem + o.gis);
  float*   GHS  = (float*)(smem + o.ghs);
  float*   TS   = (float*)(smem + o.ts);
  float*   INNS = (float*)(smem + o.inn);
  float*   KN   = (float*)(smem + o.kn);
  float*   DXS  = (float*)(smem + o.dxs);
  float*   XPRI = (float*)(smem + o.xpri);
  float*   XPO  = (float*)(smem + o.xpo);
  float*   B4   = (float*)(smem + o.b4);
  float*   NRM  = (float*)(smem + o.nrm);
  float*   L2R  = (float*)(smem + o.l2r);
  float*   SLP  = (float*)(smem + o.slp);

  const int tid  = (int)threadIdx.x;
  const int bid  = (int)blockIdx.x;
  const int lane = tid & 63;
  const int wv   = tid >> 6;
  const int rows2 = (bid < NL2B) ? 4 : 0;              // uniform l2 ownership
  const int r2s   = bid * 4;
  bool dead = false;

  int lrows[4] = {0,0,0,0}, grows[4] = {0,0,0,0};
  int nr = 0;
#pragma unroll
  for (int j = 0; j < 4; ++j) {
    int row = wv + 8*j;
    if (row < 30) { int u = row/3, g = row - 3*u;
      lrows[nr] = row; grows[nr] = g*HID + bid*UPB + u; ++nr; }
  }

  // ---------------- one-time staging ----------------
  for (int i = tid; i < rows2*192; i += NTHR) { int rl = i/192, rem = i - rl*192;
    W3S[i] = p.W3[(size_t)rem*768 + (r2s + rl)]; }
  for (int i = tid; i < 240; i += NTHR) CS[i] = p.C[i];
  if (tid < 16) AS[tid] = p.A[tid];
  for (int i = tid; i < 192; i += NTHR) B3S[i] = p.b3[i];
  if (tid < rows2) B2S[tid] = p.b2[r2s + tid];
  if (tid < 30) {
    int u = tid/3, g = tid - 3*u, ug = bid*UPB + u;
    BIH[tid] = p.bih[g*HID + ug];
    BHH[tid] = p.bhh[g*HID + ug];
  }
  for (int i = tid; i < HID; i += NTHR) HS[i] = p.h0[i];
  if (p.resident) {
    const int kd = KRES >> 2;                   // W_ih resident cols from fp8 ws
    uint32_t* W32 = (uint32_t*)WIHR;
    for (int i = tid; i < 30*kd; i += NTHR) {
      int row = i / kd, c = i - row*kd;
      int u = row/3, g = row - 3*u, gr = g*HID + bid*UPB + u;
      W32[i] = ((const uint32_t*)p.wih8)[(size_t)gr*(KIH/4) + c];
    }
    for (int i = tid; i < 30*KHH; i += NTHR) {  // W_hh rows f32->fp8
      int row = i / KHH, k = i - row*KHH;
      int u = row/3, g = row - 3*u, gr = g*HID + bid*UPB + u;
      WHHR[i] = f2fp8(p.Whh[(size_t)gr*KHH + k]);
    }
    for (int i = tid; i < rows2*HID; i += NTHR) { // W2 slice f32->fp8
      int rl = i / HID, k = i - rl*HID;
      W2S[i] = f2fp8(p.W2[(size_t)(r2s+rl)*HID + k]);
    }
  }
  // streamed W_ih cols [KRES,4160) hoisted into VGPRs (constant across steps)
  uint2 pf[4][5];
#pragma unroll
  for (int j = 0; j < 4; ++j)
#pragma unroll
    for (int i = 0; i < 5; ++i) pf[j][i] = make_uint2(0u, 0u);
#pragma unroll
  for (int j = 0; j < 4; ++j) if (j < nr)
#pragma unroll
    for (int i = 0; i < 5; ++i)
      pf[j][i] = *(const uint2*)(p.wih8 + (size_t)grows[j]*KIH + KRES + i*512 + (lane<<3));
  __syncthreads();

  // small chain producing step-`ycol` inputs: INNS, KN, B4, TS, full l1.
  auto small_chain = [&](int ycol) {
    if (tid < 48) {
      float s = CS[tid*5 + 4];
#pragma unroll
      for (int k = 0; k < 4; ++k) s += CS[tid*5 + k] * XPRI[k];
      INNS[tid] = p.y[(size_t)tid*TSEQ + ycol] - s;
    }
    __syncthreads();
    if (wv == 0) {                               // parallel ||inn||
      float q = (lane < 48) ? INNS[lane]*INNS[lane] : 0.f;
#pragma unroll
      for (int m = 32; m >= 1; m >>= 1) q += __shfl_xor(q, m, 64);
      if (lane == 0) NRM[0] = fmaxf(sqrtf(q), 1e-12f);
    } else if (wv == 1) {                        // parallel ||dx||
      float q = (lane < 4) ? DXS[lane]*DXS[lane] : 0.f;
#pragma unroll
      for (int m = 32; m >= 1; m >>= 1) q += __shfl_xor(q, m, 64);
      if (lane == 0) NRM[1] = fmaxf(sqrtf(q), 1e-12f);
    }
    __syncthreads();
    if (tid < 48) KN[tid] = INNS[tid] / NRM[0];
    else if (tid < 52) KN[tid] = DXS[tid-48] / NRM[1];
    else if (tid == 52) KN[tid] = 1.0f;
    else if (tid < 64) KN[tid] = 0.0f;
    else if (tid < 68) {
      int i = tid - 64; float s = 0;
      for (int j = 0; j < 48; ++j) s += B3S[i*48 + j] * INNS[j];
      B4[i] = s;
    }
    if (tid >= 128 && tid < 128 + rows2*4) {
      int idx = tid - 128, rl = idx >> 2, i = idx & 3;
      float s = 0;
      for (int j = 0; j < 48; ++j) s += W3S[rl*192 + i*48 + j] * INNS[j];
      TS[i*4 + rl] = s;
    }
    __syncthreads();
    {                                            // redundant full l1
      float4 kn[16];
#pragma unroll
      for (int c = 0; c < 16; ++c) kn[c] = ((const float4*)KN)[c];
      for (int r = tid; r < KIH; r += NTHR) {
        const uint4* wp = (const uint4*)(p.w1e + (size_t)r*64);
        float acc = 0.f;
#pragma unroll
        for (int q = 0; q < 4; ++q) {
          uint4 w = wp[q];
          v2f l0 = __builtin_amdgcn_cvt_pk_f32_fp8((int)w.x, false);
          v2f h0 = __builtin_amdgcn_cvt_pk_f32_fp8((int)w.x, true);
          v2f l1 = __builtin_amdgcn_cvt_pk_f32_fp8((int)w.y, false);
          v2f h1 = __builtin_amdgcn_cvt_pk_f32_fp8((int)w.y, true);
          v2f l2 = __builtin_amdgcn_cvt_pk_f32_fp8((int)w.z, false);
          v2f h2 = __builtin_amdgcn_cvt_pk_f32_fp8((int)w.z, true);
          v2f l3 = __builtin_amdgcn_cvt_pk_f32_fp8((int)w.w, false);
          v2f h3 = __builtin_amdgcn_cvt_pk_f32_fp8((int)w.w, true);
          float4 a0 = kn[q*4+0], a1 = kn[q*4+1], a2 = kn[q*4+2], a3 = kn[q*4+3];
          acc = fmaf(l0.x,a0.x,acc); acc = fmaf(l0.y,a0.y,acc);
          acc = fmaf(h0.x,a0.z,acc); acc = fmaf(h0.y,a0.w,acc);
          acc = fmaf(l1.x,a1.x,acc); acc = fmaf(l1.y,a1.y,acc);
          acc = fmaf(h1.x,a1.z,acc); acc = fmaf(h1.y,a1.w,acc);
          acc = fmaf(l2.x,a2.x,acc); acc = fmaf(l2.y,a2.y,acc);
          acc = fmaf(h2.x,a2.z,acc); acc = fmaf(h2.y,a2.w,acc);
          acc = fmaf(l3.x,a3.x,acc); acc = fmaf(l3.y,a3.y,acc);
          acc = fmaf(h3.x,a3.z,acc); acc = fmaf(h3.y,a3.w,acc);
        }
        L1S[r] = fmaxf(acc * INVWS, 0.f);
      }
    }
    __syncthreads();
  };

  auto ghh = [&]() {                             // W_hh @ HS -> GHS
    float acc[4] = {0,0,0,0};
    if (p.resident) dot8_lds(HS, WHHR, KHH, KHH, lrows, nr, lane, acc);
    else            dotf_glb(HS, p.Whh, KHH, KHH, grows, nr, lane, acc);
#pragma unroll
    for (int m = 32; m >= 1; m >>= 1)
#pragma unroll
      for (int j = 0; j < 4; ++j) acc[j] += __shfl_xor(acc[j], m, 64);
    if (lane == 0)
#pragma unroll
      for (int j = 0; j < 4; ++j) if (j < nr) GHS[lrows[j]] = acc[j];
  };

  // ---------------- pre-loop ----------------
  if (tid < 4) { XPO[tid] = p.x0[tid]; DXS[tid] = 0.f; }
  __syncthreads();
  if (tid < 4) {
    float s = 0;
#pragma unroll
    for (int j = 0; j < 4; ++j) s += AS[tid*4 + j] * XPO[j];
    XPRI[tid] = s;
  }
  __syncthreads();
  small_chain(0);
  ghh();
  __syncthreads();

  // ---------------- main sequence ----------------
  for (int t = 0; t < TSEQ; ++t) {
    const int par = t & 1;
    const uint32_t want = (uint32_t)(t + 1);

    // ---- A: gate-dot gi = W_ih @ l1(t) ----
    {
      float acc[4] = {0,0,0,0};
      if (p.resident) dot8_lds(L1S, WIHR, KRES, KRES, lrows, nr, lane, acc);
      else            dot8_glb(L1S, p.wih8, KIH, 0, KRES, grows, nr, lane, acc);
#pragma unroll
      for (int i = 0; i < 5; ++i) {              // VGPR-held streamed cols
        const float4 a0 = ((const float4*)(L1S + KRES + i*512))[lane*2];
        const float4 a1 = ((const float4*)(L1S + KRES + i*512))[lane*2 + 1];
#pragma unroll
        for (int j = 0; j < 4; ++j) if (j < nr) {
          uint2 w = pf[j][i];
          v2f l0 = __builtin_amdgcn_cvt_pk_f32_fp8((int)w.x, false);
          v2f h0 = __builtin_amdgcn_cvt_pk_f32_fp8((int)w.x, true);
          v2f l1v = __builtin_amdgcn_cvt_pk_f32_fp8((int)w.y, false);
          v2f h1 = __builtin_amdgcn_cvt_pk_f32_fp8((int)w.y, true);
          acc[j] = fmaf(l0.x, a0.x, acc[j]); acc[j] = fmaf(l0.y, a0.y, acc[j]);
          acc[j] = fmaf(h0.x, a0.z, acc[j]); acc[j] = fmaf(h0.y, a0.w, acc[j]);
          acc[j] = fmaf(l1v.x, a1.x, acc[j]); acc[j] = fmaf(l1v.y, a1.y, acc[j]);
          acc[j] = fmaf(h1.x, a1.z, acc[j]); acc[j] = fmaf(h1.y, a1.w, acc[j]);
        }
      }
#pragma unroll
      for (int m = 32; m >= 1; m >>= 1)
#pragma unroll
        for (int j = 0; j < 4; ++j) acc[j] += __shfl_xor(acc[j], m, 64);
      if (lane == 0)
#pragma unroll
        for (int j = 0; j < 4; ++j) if (j < nr) GIS[lrows[j]] = acc[j];
    }
    __syncthreads();

    // ---- B: h(t) + fire-and-forget tagged publish (lanes 0..9) ----
    if (tid < UPB) {
      int ug = bid*UPB + tid, r0 = tid*3;
      float gi0 = GIS[r0+0]*INVWS + BIH[r0+0], gh0 = GHS[r0+0]*INVWS + BHH[r0+0];
      float gi1 = GIS[r0+1]*INVWS + BIH[r0+1], gh1 = GHS[r0+1]*INVWS + BHH[r0+1];
      float gi2 = GIS[r0+2]*INVWS + BIH[r0+2], gh2 = GHS[r0+2]*INVWS + BHH[r0+2];
      float rg = 1.f/(1.f + expf(-(gi0+gh0)));
      float zg = 1.f/(1.f + expf(-(gi1+gh1)));
      float ng = tanhf(gi2 + rg*gh2);
      float hnew = (1.f - zg)*ng + zg*HS[ug];
      pub64(p.hbp + (((size_t)par*NBLK + bid) << 4) + tid, want, hnew);
    }
    __syncthreads();   // protect HS (old h) reads in B before C overwrites

    // ---- C: h broadcast consume -> HS (waves 0-3) ----
    if (wv < 4) {
      int idx = (wv << 6) | lane;
      if (idx < NBLK) {
        float v[10];
        poll_pkt<10>(p.hbp + (((size_t)par*NBLK + idx) << 4), want, v, dead);
#pragma unroll
        for (int k = 0; k < 10; ++k) HS[idx*10 + k] = v[k];
      }
    }
    __syncthreads();

    // ---- D: l2 rows, one per wave on waves 4-7 (blocks < NL2B) ----
    if (rows2 && wv >= 4) {
      const int rl = wv - 4;
      float a2 = 0.f;
      if (p.resident) {
        int kb = 0;
        for (; kb + 256 <= HID; kb += 256) {
          const float4 a = ((const float4*)(HS + kb))[lane];
          uint32_t wb = *(const uint32_t*)(W2S + rl*HID + kb + (lane<<2));
          v2f lo = __builtin_amdgcn_cvt_pk_f32_fp8((int)wb, false);
          v2f hi = __builtin_amdgcn_cvt_pk_f32_fp8((int)wb, true);
          a2 = fmaf(lo.x, a.x, a2); a2 = fmaf(lo.y, a.y, a2);
          a2 = fmaf(hi.x, a.z, a2); a2 = fmaf(hi.y, a.w, a2);
        }
        if ((lane << 2) < HID - kb) {
          const float4 a = ((const float4*)(HS + kb))[lane];
          uint32_t wb = *(const uint32_t*)(W2S + rl*HID + kb + (lane<<2));
          v2f lo = __builtin_amdgcn_cvt_pk_f32_fp8((int)wb, false);
          v2f hi = __builtin_amdgcn_cvt_pk_f32_fp8((int)wb, true);
          a2 = fmaf(lo.x, a.x, a2); a2 = fmaf(lo.y, a.y, a2);
          a2 = fmaf(hi.x, a.z, a2); a2 = fmaf(hi.y, a.w, a2);
        }
        a2 *= INVWS;
      } else {
        for (int k = lane; k < HID; k += 64)
          a2 = fmaf(p.W2[(size_t)(r2s+rl)*HID + k], HS[k], a2);
      }
#pragma unroll
      for (int m = 32; m >= 1; m >>= 1) a2 += __shfl_xor(a2, m, 64);
      if (lane == 0) L2R[rl] = fmaxf(a2 + B2S[rl], 0.f);
    }
    __syncthreads();
    if (rows2 && tid < 4) {                      // publish 4 slot words
      float cp = L2R[0]*TS[tid*4+0] + L2R[1]*TS[tid*4+1]
               + L2R[2]*TS[tid*4+2] + L2R[3]*TS[tid*4+3];
      pub64(p.slt + (((size_t)par*NBLK + bid) << 3) + tid, want, cp);
    }

    // ---- E: ghh(t) for step t+1 (all waves; covers slot flight) ----
    ghh();

    // ---- F: slot reduce (waves 0-2: 192 packets) ----
    if (wv < 3) {
      int idx = (wv << 6) | lane;
      float v[4];
      poll_pkt<4>(p.slt + (((size_t)par*NBLK + idx) << 3), want, v, dead);
      float s0 = v[0], s1 = v[1], s2 = v[2], s3 = v[3];
#pragma unroll
      for (int m = 32; m >= 1; m >>= 1) {
        s0 += __shfl_xor(s0, m, 64); s1 += __shfl_xor(s1, m, 64);
        s2 += __shfl_xor(s2, m, 64); s3 += __shfl_xor(s3, m, 64);
      }
      if (lane == 0) {
        SLP[wv*4+0] = s0; SLP[wv*4+1] = s1; SLP[wv*4+2] = s2; SLP[wv*4+3] = s3;
      }
    }
    __syncthreads();

    // ---- G: posterior + next-step chain ----
    if (tid < 4) {
      float c = SLP[tid] + SLP[4 + tid] + SLP[8 + tid];
      float xp = XPRI[tid] + (c + B4[tid]) * 1e-4f;
      XPO[tid] = xp;
      if (bid == 0) p.out[(size_t)tid*TSEQ + t] = xp;
    }
    __syncthreads();
    if (t + 1 < TSEQ) {
      if (tid < 4) {
        float xo = XPO[tid];
        DXS[tid] = xo - XPRI[tid];
        float s = 0;
#pragma unroll
        for (int j = 0; j < 4; ++j) s += AS[tid*4 + j] * XPO[j];
        XPRI[tid] = s;
      }
      __syncthreads();
      small_chain(t + 1);                        // ends with syncthreads
    }
  }
}

// f32 -> fp8 e4m3 (x128), 4 elements per thread (W_ih full).
extern "C" __global__ void knet_cvt_fp8(const float* __restrict__ src,
                                        uint8_t* __restrict__ dst, long n4) {
  long stride = (long)gridDim.x * blockDim.x;
  for (long i = (long)blockIdx.x*blockDim.x + threadIdx.x; i < n4; i += stride) {
    float4 v = ((const float4*)src)[i];
    float a0 = fminf(fmaxf(v.x * 128.f, -448.f), 448.f);
    float a1 = fminf(fmaxf(v.y * 128.f, -448.f), 448.f);
    float a2 = fminf(fmaxf(v.z * 128.f, -448.f), 448.f);
    float a3 = fminf(fmaxf(v.w * 128.f, -448.f), 448.f);
    int pk = __builtin_amdgcn_cvt_pk_fp8_f32(a0, a1, 0, false);
    pk = __builtin_amdgcn_cvt_pk_fp8_f32(a2, a3, pk, true);
    ((uint32_t*)dst)[i] = (uint32_t)pk;
  }
}

// Build W1ext fp8: row r = [W1[r,0:52], b1[r], 0 x11] * 128, 64 B/row.
extern "C" __global__ void knet_build_w1e(const float* __restrict__ W1,
                                          const float* __restrict__ b1,
                                          uint8_t* __restrict__ dst) {
  int r = blockIdx.x * blockDim.x + threadIdx.x;
  if (r >= KIH) return;
  float v[64];
#pragma unroll 13
  for (int q = 0; q < 13; ++q) {
    float4 w = ((const float4*)(W1 + (size_t)r*52))[q];
    v[q*4+0] = w.x; v[q*4+1] = w.y; v[q*4+2] = w.z; v[q*4+3] = w.w;
  }
  v[52] = b1[r];
  for (int i = 53; i < 64; ++i) v[i] = 0.f;
  uint32_t out[16];
#pragma unroll 16
  for (int d = 0; d < 16; ++d) {
    float a0 = fminf(fmaxf(v[d*4+0] * 128.f, -448.f), 448.f);
    float a1 = fminf(fmaxf(v[d*4+1] * 128.f, -448.f), 448.f);
    float a2 = fminf(fmaxf(v[d*4+2] * 128.f, -448.f), 448.f);
    float a3 = fminf(fmaxf(v[d*4+3] * 128.f, -448.f), 448.f);
    int pk = __builtin_amdgcn_cvt_pk_fp8_f32(a0, a1, 0, false);
    pk = __builtin_amdgcn_cvt_pk_fp8_f32(a2, a3, pk, true);
    out[d] = (uint32_t)pk;
  }
  uint4* dp = (uint4*)(dst + (size_t)r*64);
#pragma unroll 4
  for (int q = 0; q < 4; ++q)
    dp[q] = make_uint4(out[q*4+0], out[q*4+1], out[q*4+2], out[q*4+3]);
}

extern "C" void kernel_launch(void* const* d_in, const int* in_sizes, int n_in,
                              void* d_out, int out_size, void* d_ws, size_t ws_size,
                              hipStream_t stream)
{
  if (ws_size < (size_t)WS_END) return;   // 29.3 MB (proven available)
  uint8_t* ws = (uint8_t*)d_ws;

  knet_cvt_fp8<<<2048, 256, 0, stream>>>((const float*)d_in[7], ws + WS_WIH8,
                                         (long)G3*KIH/4);
  knet_build_w1e<<<(KIH + 255)/256, 256, 0, stream>>>(
      (const float*)d_in[5], (const float*)d_in[6], ws + WS_W1E);
  // no memset needed: word tags are exact-match (t+1); 0xAA poison never matches

  int resident = 1;
  Offs o = mkoffs(resident);
  hipError_t e = hipFuncSetAttribute((const void*)knet_main,
                                     hipFuncAttributeMaxDynamicSharedMemorySize,
                                     o.total);
  if (e != hipSuccess) {
    resident = 0; o = mkoffs(resident);
    (void)hipFuncSetAttribute((const void*)knet_main,
                              hipFuncAttributeMaxDynamicSharedMemorySize, o.total);
  }

  Params p;
  p.A   = (const float*)d_in[0];  p.C   = (const float*)d_in[1];
  p.x0  = (const float*)d_in[2];  p.h0  = (const float*)d_in[3];
  p.y   = (const float*)d_in[4];
  p.W1  = (const float*)d_in[5];  p.b1  = (const float*)d_in[6];
  p.Wih = (const float*)d_in[7];  p.Whh = (const float*)d_in[8];
  p.bih = (const float*)d_in[9];  p.bhh = (const float*)d_in[10];
  p.W2  = (const float*)d_in[11]; p.b2  = (const float*)d_in[12];
  p.W3  = (const float*)d_in[13]; p.b3  = (const float*)d_in[14];
  p.wih8 = ws + WS_WIH8;
  p.w1e  = ws + WS_W1E;
  p.hbp  = (uint64_t*)(ws + WS_HBP);
  p.slt  = (uint64_t*)(ws + WS_SLT);
  p.out  = (float*)d_out;
  p.resident = resident;

  knet_main<<<NBLK, NTHR, (size_t)o.total, stream>>>(p);
}